// Round 3
// baseline (723.835 us; speedup 1.0000x reference)
//
#include <hip/hip_runtime.h>

#define B_ 32
#define S_ 512
#define D_ 512
#define H_ 8
#define DK_ 64
#define FF_ 2048

typedef float f32x4 __attribute__((ext_vector_type(4)));
typedef __bf16 bf16x8 __attribute__((ext_vector_type(8)));
typedef __bf16 bf16x4 __attribute__((ext_vector_type(4)));

// ---- async global->LDS, 16B per lane (dest must be wave-uniform base + lane*16) ----
__device__ __forceinline__ void gld_lds16(const void* gptr, void* lptr) {
    auto g = (__attribute__((address_space(1))) void*)(unsigned long long)gptr;
    auto l = (__attribute__((address_space(3))) void*)(unsigned)(unsigned long long)lptr;
    __builtin_amdgcn_global_load_lds(g, l, 16, 0, 0);
}

// ---- x = q+pe (fp32 + bf16), y = qa+pe (bf16) ----
__global__ __launch_bounds__(256) void prep_kernel(
    const float* __restrict__ q, const float* __restrict__ qa,
    const float* __restrict__ pe, float* __restrict__ xf,
    __bf16* __restrict__ xbf, __bf16* __restrict__ ybf)
{
    const int n4 = B_ * S_ * D_ / 4;
    for (int i = blockIdx.x * blockDim.x + threadIdx.x; i < n4;
         i += gridDim.x * blockDim.x) {
        float4 pv = ((const float4*)pe)[i & (S_ * D_ / 4 - 1)];
        float4 qv = ((const float4*)q)[i];
        float4 av = ((const float4*)qa)[i];
        float4 xv = make_float4(qv.x + pv.x, qv.y + pv.y, qv.z + pv.z, qv.w + pv.w);
        ((float4*)xf)[i] = xv;
        bf16x4 xb = {(__bf16)xv.x, (__bf16)xv.y, (__bf16)xv.z, (__bf16)xv.w};
        ((bf16x4*)xbf)[i] = xb;
        bf16x4 yb = {(__bf16)(av.x + pv.x), (__bf16)(av.y + pv.y),
                     (__bf16)(av.z + pv.z), (__bf16)(av.w + pv.w)};
        ((bf16x4*)ybf)[i] = yb;
    }
}

// ---- fp32 [R][C] -> bf16 [C][R] (weights to B^T layout) ----
__global__ __launch_bounds__(256) void transpose_cvt(
    const float* __restrict__ in, __bf16* __restrict__ out, int R, int C)
{
    __shared__ float tile[32][33];
    const int tc = blockIdx.x * 32, tr = blockIdx.y * 32;
    const int lx = threadIdx.x & 31, ly = threadIdx.x >> 5;
    #pragma unroll
    for (int yy = ly; yy < 32; yy += 8)
        tile[yy][lx] = in[(long)(tr + yy) * C + tc + lx];
    __syncthreads();
    #pragma unroll
    for (int yy = ly; yy < 32; yy += 8)
        out[(long)(tc + yy) * R + tr + lx] = (__bf16)tile[lx][yy];
}

// ---- V [B,S,H,DK] -> Vt [B,H,DK,S] ----
__global__ __launch_bounds__(256) void vtrans_kernel(
    const __bf16* __restrict__ V, __bf16* __restrict__ Vt)
{
    __shared__ __bf16 tile[64][72];
    const int sb = blockIdx.x, h = blockIdx.y, b = blockIdx.z;
    const int t = threadIdx.x;
    #pragma unroll
    for (int it = 0; it < 16; ++it) {
        int idx = it * 256 + t;
        int rr = idx >> 6, cc = idx & 63;
        tile[cc][rr] = V[((long)(b * S_ + sb * 64 + rr)) * D_ + h * DK_ + cc];
    }
    __syncthreads();
    #pragma unroll
    for (int it = 0; it < 16; ++it) {
        int idx = it * 256 + t;
        int dd = idx >> 6, so = idx & 63;
        Vt[((long)(b * H_ + h) * DK_ + dd) * S_ + sb * 64 + so] = tile[dd][so];
    }
}

// ---- GEMM: C[M,N] = A[M,K](bf16) @ Bt[N,K](bf16)^T + bias; m97-structure 128x128 ----
// MODE 0: bf16 out (+optional RELU). MODE 1: fp32 out = acc + bias + res.
template <int RELU, int MODE>
__global__ __launch_bounds__(256) void gemm_kernel(
    const __bf16* __restrict__ A, const __bf16* __restrict__ Bt,
    const float* __restrict__ bias, const float* __restrict__ res,
    void* __restrict__ outv, int M, int N, int K)
{
    __shared__ __bf16 As[128 * 32];
    __shared__ __bf16 Bs[128 * 32];
    const int t = threadIdx.x;
    const int lane = t & 63;
    const int wv = t >> 6, wr = wv >> 1, wc = wv & 1;
    const int lr = lane & 15, lk = lane >> 4;
    const int m0 = blockIdx.y * 128, n0 = blockIdx.x * 128;

    const int srow = t >> 2, scol = (t & 3) * 8;
    const __bf16* gA = A + (long)(m0 + srow) * K + scol;
    const __bf16* gB = Bt + (long)(n0 + srow) * K + scol;
    char* ldsA = (char*)As + t * 16;
    char* ldsB = (char*)Bs + t * 16;
    const long rstep = (long)64 * K;

    f32x4 acc[4][4] = {};
    for (int k0 = 0; k0 < K; k0 += 32) {
        gld_lds16(gA + k0, ldsA);
        gld_lds16(gA + k0 + rstep, ldsA + 4096);
        gld_lds16(gB + k0, ldsB);
        gld_lds16(gB + k0 + rstep, ldsB + 4096);
        __syncthreads();
        bf16x8 af[4], bfr[4];
        #pragma unroll
        for (int i = 0; i < 4; ++i)
            af[i] = *(const bf16x8*)&As[(wr * 64 + i * 16 + lr) * 32 + lk * 8];
        #pragma unroll
        for (int j = 0; j < 4; ++j)
            bfr[j] = *(const bf16x8*)&Bs[(wc * 64 + j * 16 + lr) * 32 + lk * 8];
        #pragma unroll
        for (int i = 0; i < 4; ++i)
            #pragma unroll
            for (int j = 0; j < 4; ++j)
                acc[i][j] = __builtin_amdgcn_mfma_f32_16x16x32_bf16(
                    af[i], bfr[j], acc[i][j], 0, 0, 0);
        __syncthreads();
    }

    #pragma unroll
    for (int i = 0; i < 4; ++i) {
        #pragma unroll
        for (int j = 0; j < 4; ++j) {
            const int n = n0 + wc * 64 + j * 16 + lr;
            const float bv = bias[n];
            #pragma unroll
            for (int r = 0; r < 4; ++r) {
                const int m = m0 + wr * 64 + i * 16 + lk * 4 + r;
                float v = acc[i][j][r] + bv;
                if (RELU) v = v > 0.f ? v : 0.f;
                const long off = (long)m * N + n;
                if (MODE == 0) ((__bf16*)outv)[off] = (__bf16)v;
                else           ((float*)outv)[off] = v + res[off];
            }
        }
    }
}

// ---- attention v3: v2 minus causal pairing (bisect). One 16-row q-tile per wave,
// KVBLK=64, direct exp (no online max), end-only denominator reduction,
// XOR-swizzled P LDS. Grid (8, H, B). ----
__global__ __launch_bounds__(256) void attn_kernel(
    const __bf16* __restrict__ Q, const __bf16* __restrict__ Vt,
    const float* __restrict__ fr, __bf16* __restrict__ Out)
{
    __shared__ __bf16 Plds[4][16 * 64];
    const int t = threadIdx.x;
    const int lane = t & 63, wv = t >> 6;
    const int lr = lane & 15, lk = lane >> 4;
    const int qb = blockIdx.x, h = blockIdx.y, b = blockIdx.z;
    const int qT = qb * 64 + wv * 16;

    const __bf16* qp = Q + (long)(b * S_ + qT + lr) * D_ + h * DK_ + lk * 8;
    const bf16x8 qf0 = *(const bf16x8*)qp;
    const bf16x8 qf1 = *(const bf16x8*)(qp + 32);

    float frv[4], ls[4];
    #pragma unroll
    for (int r = 0; r < 4; ++r) {
        frv[r] = fr[b * S_ + qT + lk * 4 + r] * 0.125f;  // fold 1/sqrt(64)
        ls[r] = 0.f;
    }
    f32x4 o[4] = {};

    const __bf16* kbase = Q + (long)b * S_ * D_ + h * DK_;
    const __bf16* vbase = Vt + (long)(b * H_ + h) * DK_ * S_;
    __bf16* pl = &Plds[wv][0];

    for (int ks = 0; ks < qT + 16; ks += 64) {
        bf16x8 kf[4][2];
        #pragma unroll
        for (int j = 0; j < 4; ++j) {
            const __bf16* kp = kbase + (long)(ks + j * 16 + lr) * D_ + lk * 8;
            kf[j][0] = *(const bf16x8*)kp;
            kf[j][1] = *(const bf16x8*)(kp + 32);
        }
        f32x4 s[4] = {};
        #pragma unroll
        for (int j = 0; j < 4; ++j) {
            s[j] = __builtin_amdgcn_mfma_f32_16x16x32_bf16(qf0, kf[j][0], s[j], 0, 0, 0);
            s[j] = __builtin_amdgcn_mfma_f32_16x16x32_bf16(qf1, kf[j][1], s[j], 0, 0, 0);
        }
        // p = allowed ? exp(s*fr) : 0 ; per-lane partial sums; swizzled LDS store
        #pragma unroll
        for (int j = 0; j < 4; ++j) {
            const int col = ks + j * 16 + lr;
            const int c8 = j * 2 + (lr >> 3), cb = lr & 7;
            #pragma unroll
            for (int r = 0; r < 4; ++r) {
                const int row = lk * 4 + r;
                const int sidx = row * 64 + ((c8 ^ (row & 7)) << 3) + cb;
                const float e = __expf(s[j][r] * frv[r]);
                const float p = (col < qT + row) ? e : 0.f;
                ls[r] += p;
                pl[sidx] = (__bf16)p;
            }
        }
        // PV: A-frag from swizzled LDS
        bf16x8 pf[2];
        #pragma unroll
        for (int kk = 0; kk < 2; ++kk) {
            const int ridx = lr * 64 + (((kk * 4 + lk) ^ (lr & 7)) << 3);
            pf[kk] = *(const bf16x8*)&pl[ridx];
        }
        #pragma unroll
        for (int dt = 0; dt < 4; ++dt) {
            #pragma unroll
            for (int kk = 0; kk < 2; ++kk) {
                const __bf16* vp = vbase + (long)(dt * 16 + lr) * S_ + ks + kk * 32 + lk * 8;
                const bf16x8 vf = *(const bf16x8*)vp;
                o[dt] = __builtin_amdgcn_mfma_f32_16x16x32_bf16(pf[kk], vf, o[dt], 0, 0, 0);
            }
        }
    }

    // one-time cross-lane reduction of the denominators (16-lane groups)
    #pragma unroll
    for (int r = 0; r < 4; ++r) {
        #pragma unroll
        for (int d = 1; d < 16; d <<= 1)
            ls[r] += __shfl_xor(ls[r], d);
        const float inv = ls[r] > 0.f ? 1.f / ls[r] : 0.f;  // row 0 -> zeros
        #pragma unroll
        for (int dt = 0; dt < 4; ++dt)
            Out[(long)(b * S_ + qT + lk * 4 + r) * D_ + h * DK_ + dt * 16 + lr] =
                (__bf16)(o[dt][r] * inv);
    }
}

// ---- LayerNorm, wave per row; writes fp32 master + bf16 copy ----
__global__ __launch_bounds__(256) void ln_kernel(
    const float* __restrict__ pre, const float* __restrict__ g,
    const float* __restrict__ be, float* __restrict__ xout,
    __bf16* __restrict__ xbf)
{
    const int lane = threadIdx.x & 63, wv = threadIdx.x >> 6;
    const long row = (long)blockIdx.x * 4 + wv;
    const float* p = pre + row * D_ + lane * 8;
    const float4 a = ((const float4*)p)[0];
    const float4 c = ((const float4*)p)[1];
    float s  = a.x + a.y + a.z + a.w + c.x + c.y + c.z + c.w;
    float ss = a.x * a.x + a.y * a.y + a.z * a.z + a.w * a.w +
               c.x * c.x + c.y * c.y + c.z * c.z + c.w * c.w;
    #pragma unroll
    for (int d = 1; d < 64; d <<= 1) {
        s  += __shfl_xor(s, d);
        ss += __shfl_xor(ss, d);
    }
    const float mean = s * (1.f / 512.f);
    const float rstd = rsqrtf(ss * (1.f / 512.f) - mean * mean + 1e-5f);
    const float4 ga = ((const float4*)(g + lane * 8))[0];
    const float4 gc = ((const float4*)(g + lane * 8))[1];
    const float4 ba = ((const float4*)(be + lane * 8))[0];
    const float4 bc = ((const float4*)(be + lane * 8))[1];
    const float o0 = (a.x - mean) * rstd * ga.x + ba.x;
    const float o1 = (a.y - mean) * rstd * ga.y + ba.y;
    const float o2 = (a.z - mean) * rstd * ga.z + ba.z;
    const float o3 = (a.w - mean) * rstd * ga.w + ba.w;
    const float o4 = (c.x - mean) * rstd * gc.x + bc.x;
    const float o5 = (c.y - mean) * rstd * gc.y + bc.y;
    const float o6 = (c.z - mean) * rstd * gc.z + bc.z;
    const float o7 = (c.w - mean) * rstd * gc.w + bc.w;
    float* xo = xout + row * D_ + lane * 8;
    ((float4*)xo)[0] = make_float4(o0, o1, o2, o3);
    ((float4*)xo)[1] = make_float4(o4, o5, o6, o7);
    bf16x8 xb = {(__bf16)o0, (__bf16)o1, (__bf16)o2, (__bf16)o3,
                 (__bf16)o4, (__bf16)o5, (__bf16)o6, (__bf16)o7};
    *(bf16x8*)(xbf + row * D_ + lane * 8) = xb;
}

extern "C" void kernel_launch(void* const* d_in, const int* in_sizes, int n_in,
                              void* d_out, int out_size, void* d_ws, size_t ws_size,
                              hipStream_t stream) {
    const float* q_embed = (const float*)d_in[0];
    const float* qa_embed = (const float*)d_in[1];
    const float* fr  = (const float*)d_in[2];
    const float* pe  = (const float*)d_in[3];
    const float* Wk  = (const float*)d_in[4];
    const float* bk  = (const float*)d_in[5];
    const float* Wv  = (const float*)d_in[6];
    const float* bv  = (const float*)d_in[7];
    const float* Wo  = (const float*)d_in[8];
    const float* bo  = (const float*)d_in[9];
    const float* g1  = (const float*)d_in[10];
    const float* be1 = (const float*)d_in[11];
    const float* W1  = (const float*)d_in[12];
    const float* bf1 = (const float*)d_in[13];
    const float* W2  = (const float*)d_in[14];
    const float* bf2 = (const float*)d_in[15];
    const float* g2  = (const float*)d_in[16];
    const float* be2 = (const float*)d_in[17];

    // workspace layout (~174 MB)
    char* ws = (char*)d_ws;
    float*  xf    = (float*)(ws + 0);            // 32 MB fp32 residual master
    __bf16* xbf   = (__bf16*)(ws + 33554432);    // 16 MB
    __bf16* ybf   = (__bf16*)(ws + 50331648);    // 16 MB (persists both blocks)
    __bf16* pool  = (__bf16*)(ws + 67108864);    // 64 MB: k/v/vt/attn OR f1
    float*  preln = (float*)(ws + 134217728);    // 32 MB
    __bf16* wts   = (__bf16*)(ws + 167772160);   // 11 MB bf16 transposed weights

    __bf16* kbuf  = pool;
    __bf16* vbuf  = pool + 8388608;
    __bf16* vtbuf = pool + 2 * 8388608;
    __bf16* abuf  = pool + 3 * 8388608;
    __bf16* f1buf = pool;  // 64 MB, aliases k/v/vt/attn (all dead by FFN1)

    __bf16* wkt = wts;
    __bf16* wvt = wts + 524288;
    __bf16* wot = wts + 1048576;
    __bf16* w1t = wts + 1572864;
    __bf16* w2t = wts + 3670016;

    for (int i = 0; i < 2; ++i) {
        transpose_cvt<<<dim3(16, 16), 256, 0, stream>>>(Wk + i * 262144, wkt + i * 262144, 512, 512);
        transpose_cvt<<<dim3(16, 16), 256, 0, stream>>>(Wv + i * 262144, wvt + i * 262144, 512, 512);
        transpose_cvt<<<dim3(16, 16), 256, 0, stream>>>(Wo + i * 262144, wot + i * 262144, 512, 512);
        transpose_cvt<<<dim3(64, 16), 256, 0, stream>>>(W1 + i * 1048576, w1t + i * 1048576, 512, 2048);
        transpose_cvt<<<dim3(16, 64), 256, 0, stream>>>(W2 + i * 1048576, w2t + i * 1048576, 2048, 512);
    }
    prep_kernel<<<2048, 256, 0, stream>>>(q_embed, qa_embed, pe, xf, xbf, ybf);

    for (int i = 0; i < 2; ++i) {
        gemm_kernel<0, 0><<<dim3(4, 128), 256, 0, stream>>>(
            xbf, wkt + i * 262144, bk + i * 512, nullptr, kbuf, 16384, 512, 512);
        gemm_kernel<0, 0><<<dim3(4, 128), 256, 0, stream>>>(
            ybf, wvt + i * 262144, bv + i * 512, nullptr, vbuf, 16384, 512, 512);
        vtrans_kernel<<<dim3(8, 8, 32), 256, 0, stream>>>(vbuf, vtbuf);
        attn_kernel<<<dim3(8, 8, 32), 256, 0, stream>>>(kbuf, vtbuf, fr, abuf);
        gemm_kernel<0, 1><<<dim3(4, 128), 256, 0, stream>>>(
            abuf, wot + i * 262144, bo + i * 512, xf, preln, 16384, 512, 512);
        ln_kernel<<<4096, 256, 0, stream>>>(preln, g1 + i * 512, be1 + i * 512, xf, xbf);
        gemm_kernel<1, 0><<<dim3(16, 128), 256, 0, stream>>>(
            xbf, w1t + i * 1048576, bf1 + i * 2048, nullptr, f1buf, 16384, 2048, 512);
        gemm_kernel<0, 1><<<dim3(4, 128), 256, 0, stream>>>(
            f1buf, w2t + i * 1048576, bf2 + i * 512, xf, preln, 16384, 512, 2048);
        float* xdst = (i == 1) ? (float*)d_out : xf;
        ln_kernel<<<4096, 256, 0, stream>>>(preln, g2 + i * 512, be2 + i * 512, xdst, xbf);
    }
}

// Round 4
// 581.374 us; speedup vs baseline: 1.2450x; 1.2450x over previous
//
#include <hip/hip_runtime.h>

#define B_ 32
#define S_ 512
#define D_ 512
#define H_ 8
#define DK_ 64
#define FF_ 2048

typedef float f32x4 __attribute__((ext_vector_type(4)));
typedef __bf16 bf16x8 __attribute__((ext_vector_type(8)));
typedef __bf16 bf16x4 __attribute__((ext_vector_type(4)));

// ---- async global->LDS, 16B per lane (dest must be wave-uniform base + lane*16) ----
__device__ __forceinline__ void gld_lds16(const void* gptr, void* lptr) {
    auto g = (__attribute__((address_space(1))) void*)(unsigned long long)gptr;
    auto l = (__attribute__((address_space(3))) void*)(unsigned)(unsigned long long)lptr;
    __builtin_amdgcn_global_load_lds(g, l, 16, 0, 0);
}

// ---- x = q+pe (fp32 + bf16), y = qa+pe (bf16) ----
__global__ __launch_bounds__(256) void prep_kernel(
    const float* __restrict__ q, const float* __restrict__ qa,
    const float* __restrict__ pe, float* __restrict__ xf,
    __bf16* __restrict__ xbf, __bf16* __restrict__ ybf)
{
    const int n4 = B_ * S_ * D_ / 4;
    for (int i = blockIdx.x * blockDim.x + threadIdx.x; i < n4;
         i += gridDim.x * blockDim.x) {
        float4 pv = ((const float4*)pe)[i & (S_ * D_ / 4 - 1)];
        float4 qv = ((const float4*)q)[i];
        float4 av = ((const float4*)qa)[i];
        float4 xv = make_float4(qv.x + pv.x, qv.y + pv.y, qv.z + pv.z, qv.w + pv.w);
        ((float4*)xf)[i] = xv;
        bf16x4 xb = {(__bf16)xv.x, (__bf16)xv.y, (__bf16)xv.z, (__bf16)xv.w};
        ((bf16x4*)xbf)[i] = xb;
        bf16x4 yb = {(__bf16)(av.x + pv.x), (__bf16)(av.y + pv.y),
                     (__bf16)(av.z + pv.z), (__bf16)(av.w + pv.w)};
        ((bf16x4*)ybf)[i] = yb;
    }
}

// ---- fp32 [R][C] -> bf16 [C][R] (weights to B^T layout) ----
__global__ __launch_bounds__(256) void transpose_cvt(
    const float* __restrict__ in, __bf16* __restrict__ out, int R, int C)
{
    __shared__ float tile[32][33];
    const int tc = blockIdx.x * 32, tr = blockIdx.y * 32;
    const int lx = threadIdx.x & 31, ly = threadIdx.x >> 5;
    #pragma unroll
    for (int yy = ly; yy < 32; yy += 8)
        tile[yy][lx] = in[(long)(tr + yy) * C + tc + lx];
    __syncthreads();
    #pragma unroll
    for (int yy = ly; yy < 32; yy += 8)
        out[(long)(tc + yy) * R + tr + lx] = (__bf16)tile[lx][yy];
}

// ---- V [B,S,H,DK] -> Vt [B,H,DK,S] ----
__global__ __launch_bounds__(256) void vtrans_kernel(
    const __bf16* __restrict__ V, __bf16* __restrict__ Vt)
{
    __shared__ __bf16 tile[64][72];
    const int sb = blockIdx.x, h = blockIdx.y, b = blockIdx.z;
    const int t = threadIdx.x;
    #pragma unroll
    for (int it = 0; it < 16; ++it) {
        int idx = it * 256 + t;
        int rr = idx >> 6, cc = idx & 63;
        tile[cc][rr] = V[((long)(b * S_ + sb * 64 + rr)) * D_ + h * DK_ + cc];
    }
    __syncthreads();
    #pragma unroll
    for (int it = 0; it < 16; ++it) {
        int idx = it * 256 + t;
        int dd = idx >> 6, so = idx & 63;
        Vt[((long)(b * H_ + h) * DK_ + dd) * S_ + sb * 64 + so] = tile[dd][so];
    }
}

// ---- GEMM: C[M,N] = A[M,K](bf16) @ Bt[N,K](bf16)^T + bias; m97-structure 128x128 ----
// MODE 0: bf16 out (+optional RELU). MODE 1: fp32 out = acc + bias + res.
template <int RELU, int MODE>
__global__ __launch_bounds__(256) void gemm_kernel(
    const __bf16* __restrict__ A, const __bf16* __restrict__ Bt,
    const float* __restrict__ bias, const float* __restrict__ res,
    void* __restrict__ outv, int M, int N, int K)
{
    __shared__ __bf16 As[128 * 32];
    __shared__ __bf16 Bs[128 * 32];
    const int t = threadIdx.x;
    const int lane = t & 63;
    const int wv = t >> 6, wr = wv >> 1, wc = wv & 1;
    const int lr = lane & 15, lk = lane >> 4;
    const int m0 = blockIdx.y * 128, n0 = blockIdx.x * 128;

    const int srow = t >> 2, scol = (t & 3) * 8;
    const __bf16* gA = A + (long)(m0 + srow) * K + scol;
    const __bf16* gB = Bt + (long)(n0 + srow) * K + scol;
    char* ldsA = (char*)As + t * 16;
    char* ldsB = (char*)Bs + t * 16;
    const long rstep = (long)64 * K;

    f32x4 acc[4][4] = {};
    for (int k0 = 0; k0 < K; k0 += 32) {
        gld_lds16(gA + k0, ldsA);
        gld_lds16(gA + k0 + rstep, ldsA + 4096);
        gld_lds16(gB + k0, ldsB);
        gld_lds16(gB + k0 + rstep, ldsB + 4096);
        __syncthreads();
        bf16x8 af[4], bfr[4];
        #pragma unroll
        for (int i = 0; i < 4; ++i)
            af[i] = *(const bf16x8*)&As[(wr * 64 + i * 16 + lr) * 32 + lk * 8];
        #pragma unroll
        for (int j = 0; j < 4; ++j)
            bfr[j] = *(const bf16x8*)&Bs[(wc * 64 + j * 16 + lr) * 32 + lk * 8];
        #pragma unroll
        for (int i = 0; i < 4; ++i)
            #pragma unroll
            for (int j = 0; j < 4; ++j)
                acc[i][j] = __builtin_amdgcn_mfma_f32_16x16x32_bf16(
                    af[i], bfr[j], acc[i][j], 0, 0, 0);
        __syncthreads();
    }

    #pragma unroll
    for (int i = 0; i < 4; ++i) {
        #pragma unroll
        for (int j = 0; j < 4; ++j) {
            const int n = n0 + wc * 64 + j * 16 + lr;
            const float bv = bias[n];
            #pragma unroll
            for (int r = 0; r < 4; ++r) {
                const int m = m0 + wr * 64 + i * 16 + lk * 4 + r;
                float v = acc[i][j][r] + bv;
                if (RELU) v = v > 0.f ? v : 0.f;
                const long off = (long)m * N + n;
                if (MODE == 0) ((__bf16*)outv)[off] = (__bf16)v;
                else           ((float*)outv)[off] = v + res[off];
            }
        }
    }
}

// ---- attention v4: v3 + block-cooperative LDS staging of K and V tiles ----
// K/V staged once per block per KV-chunk via global_load_lds (pre-swizzled
// global source, linear LDS dest); fragments via swizzled ds_read_b128.
// Compute path (exp, masking, P-LDS, reductions) identical to passing v3.
__global__ __launch_bounds__(256) void attn_kernel(
    const __bf16* __restrict__ Q, const __bf16* __restrict__ Vt,
    const float* __restrict__ fr, __bf16* __restrict__ Out)
{
    __shared__ __bf16 Ks[64 * 64];
    __shared__ __bf16 Vs[64 * 64];
    __shared__ __bf16 Plds[4][16 * 64];
    const int t = threadIdx.x;
    const int lane = t & 63, wv = t >> 6;
    const int lr = lane & 15, lk = lane >> 4;
    const int qb = blockIdx.x, h = blockIdx.y, b = blockIdx.z;
    const int qT = qb * 64 + wv * 16;

    const __bf16* qp = Q + (long)(b * S_ + qT + lr) * D_ + h * DK_ + lk * 8;
    const bf16x8 qf0 = *(const bf16x8*)qp;
    const bf16x8 qf1 = *(const bf16x8*)(qp + 32);

    float frv[4], ls[4];
    #pragma unroll
    for (int r = 0; r < 4; ++r) {
        frv[r] = fr[b * S_ + qT + lk * 4 + r] * 0.125f;  // fold 1/sqrt(64)
        ls[r] = 0.f;
    }
    f32x4 o[4] = {};

    // staging source (pre-swizzled slot so linear LDS dest ends up swizzled)
    const int srow = t >> 3;                       // 0..31
    const int sslot = (t & 7) ^ (srow & 7);        // XOR-swizzled 16B slot
    const __bf16* kstage = Q + (long)(b * S_ + srow) * D_ + h * DK_ + sslot * 8;
    const __bf16* vstage = Vt + ((long)(b * H_ + h) * DK_ + srow) * S_ + sslot * 8;
    char* kd = (char*)Ks + t * 16;
    char* vd = (char*)Vs + t * 16;
    __bf16* pl = &Plds[wv][0];
    const int sw = (lr & 7);                       // read-side swizzle key

    for (int ks = 0; ks <= qb * 64; ks += 64) {
        gld_lds16(kstage + (long)ks * D_, kd);
        gld_lds16(kstage + (long)(ks + 32) * D_, kd + 4096);
        gld_lds16(vstage + ks, vd);
        gld_lds16(vstage + ks + 32 * S_, vd + 4096);
        __syncthreads();

        f32x4 s[4] = {};
        #pragma unroll
        for (int j = 0; j < 4; ++j) {
            const char* kb = (const char*)Ks + ((j * 16 + lr) << 7);
            const bf16x8 kf0 = *(const bf16x8*)(kb + ((lk ^ sw) << 4));
            const bf16x8 kf1 = *(const bf16x8*)(kb + (((lk + 4) ^ sw) << 4));
            s[j] = __builtin_amdgcn_mfma_f32_16x16x32_bf16(qf0, kf0, s[j], 0, 0, 0);
            s[j] = __builtin_amdgcn_mfma_f32_16x16x32_bf16(qf1, kf1, s[j], 0, 0, 0);
        }
        // p = allowed ? exp(s*fr) : 0 ; per-lane partial sums; swizzled P store
        #pragma unroll
        for (int j = 0; j < 4; ++j) {
            const int col = ks + j * 16 + lr;
            const int c8 = j * 2 + (lr >> 3), cb = lr & 7;
            #pragma unroll
            for (int r = 0; r < 4; ++r) {
                const int row = lk * 4 + r;
                const int sidx = row * 64 + ((c8 ^ (row & 7)) << 3) + cb;
                const float e = __expf(s[j][r] * frv[r]);
                const float p = (col < qT + row) ? e : 0.f;
                ls[r] += p;
                pl[sidx] = (__bf16)p;
            }
        }
        // PV: A-frag from swizzled P-LDS, B-frag from swizzled V-LDS
        bf16x8 pf[2];
        #pragma unroll
        for (int kk = 0; kk < 2; ++kk) {
            const int ridx = lr * 64 + (((kk * 4 + lk) ^ sw) << 3);
            pf[kk] = *(const bf16x8*)&pl[ridx];
        }
        #pragma unroll
        for (int dt = 0; dt < 4; ++dt) {
            const char* vb = (const char*)Vs + ((dt * 16 + lr) << 7);
            #pragma unroll
            for (int kk = 0; kk < 2; ++kk) {
                const bf16x8 vf = *(const bf16x8*)(vb + (((kk * 4 + lk) ^ sw) << 4));
                o[dt] = __builtin_amdgcn_mfma_f32_16x16x32_bf16(pf[kk], vf, o[dt], 0, 0, 0);
            }
        }
        __syncthreads();  // protect K/V tiles before next stage
    }

    // one-time cross-lane reduction of the denominators (16-lane groups)
    #pragma unroll
    for (int r = 0; r < 4; ++r) {
        #pragma unroll
        for (int d = 1; d < 16; d <<= 1)
            ls[r] += __shfl_xor(ls[r], d);
        const float inv = ls[r] > 0.f ? 1.f / ls[r] : 0.f;  // row 0 -> zeros
        #pragma unroll
        for (int dt = 0; dt < 4; ++dt)
            Out[(long)(b * S_ + qT + lk * 4 + r) * D_ + h * DK_ + dt * 16 + lr] =
                (__bf16)(o[dt][r] * inv);
    }
}

// ---- LayerNorm, wave per row; writes fp32 master + bf16 copy ----
__global__ __launch_bounds__(256) void ln_kernel(
    const float* __restrict__ pre, const float* __restrict__ g,
    const float* __restrict__ be, float* __restrict__ xout,
    __bf16* __restrict__ xbf)
{
    const int lane = threadIdx.x & 63, wv = threadIdx.x >> 6;
    const long row = (long)blockIdx.x * 4 + wv;
    const float* p = pre + row * D_ + lane * 8;
    const float4 a = ((const float4*)p)[0];
    const float4 c = ((const float4*)p)[1];
    float s  = a.x + a.y + a.z + a.w + c.x + c.y + c.z + c.w;
    float ss = a.x * a.x + a.y * a.y + a.z * a.z + a.w * a.w +
               c.x * c.x + c.y * c.y + c.z * c.z + c.w * c.w;
    #pragma unroll
    for (int d = 1; d < 64; d <<= 1) {
        s  += __shfl_xor(s, d);
        ss += __shfl_xor(ss, d);
    }
    const float mean = s * (1.f / 512.f);
    const float rstd = rsqrtf(ss * (1.f / 512.f) - mean * mean + 1e-5f);
    const float4 ga = ((const float4*)(g + lane * 8))[0];
    const float4 gc = ((const float4*)(g + lane * 8))[1];
    const float4 ba = ((const float4*)(be + lane * 8))[0];
    const float4 bc = ((const float4*)(be + lane * 8))[1];
    const float o0 = (a.x - mean) * rstd * ga.x + ba.x;
    const float o1 = (a.y - mean) * rstd * ga.y + ba.y;
    const float o2 = (a.z - mean) * rstd * ga.z + ba.z;
    const float o3 = (a.w - mean) * rstd * ga.w + ba.w;
    const float o4 = (c.x - mean) * rstd * gc.x + bc.x;
    const float o5 = (c.y - mean) * rstd * gc.y + bc.y;
    const float o6 = (c.z - mean) * rstd * gc.z + bc.z;
    const float o7 = (c.w - mean) * rstd * gc.w + bc.w;
    float* xo = xout + row * D_ + lane * 8;
    ((float4*)xo)[0] = make_float4(o0, o1, o2, o3);
    ((float4*)xo)[1] = make_float4(o4, o5, o6, o7);
    bf16x8 xb = {(__bf16)o0, (__bf16)o1, (__bf16)o2, (__bf16)o3,
                 (__bf16)o4, (__bf16)o5, (__bf16)o6, (__bf16)o7};
    *(bf16x8*)(xbf + row * D_ + lane * 8) = xb;
}

extern "C" void kernel_launch(void* const* d_in, const int* in_sizes, int n_in,
                              void* d_out, int out_size, void* d_ws, size_t ws_size,
                              hipStream_t stream) {
    const float* q_embed = (const float*)d_in[0];
    const float* qa_embed = (const float*)d_in[1];
    const float* fr  = (const float*)d_in[2];
    const float* pe  = (const float*)d_in[3];
    const float* Wk  = (const float*)d_in[4];
    const float* bk  = (const float*)d_in[5];
    const float* Wv  = (const float*)d_in[6];
    const float* bv  = (const float*)d_in[7];
    const float* Wo  = (const float*)d_in[8];
    const float* bo  = (const float*)d_in[9];
    const float* g1  = (const float*)d_in[10];
    const float* be1 = (const float*)d_in[11];
    const float* W1  = (const float*)d_in[12];
    const float* bf1 = (const float*)d_in[13];
    const float* W2  = (const float*)d_in[14];
    const float* bf2 = (const float*)d_in[15];
    const float* g2  = (const float*)d_in[16];
    const float* be2 = (const float*)d_in[17];

    // workspace layout (~174 MB)
    char* ws = (char*)d_ws;
    float*  xf    = (float*)(ws + 0);            // 32 MB fp32 residual master
    __bf16* xbf   = (__bf16*)(ws + 33554432);    // 16 MB
    __bf16* ybf   = (__bf16*)(ws + 50331648);    // 16 MB (persists both blocks)
    __bf16* pool  = (__bf16*)(ws + 67108864);    // 64 MB: k/v/vt/attn OR f1
    float*  preln = (float*)(ws + 134217728);    // 32 MB
    __bf16* wts   = (__bf16*)(ws + 167772160);   // 11 MB bf16 transposed weights

    __bf16* kbuf  = pool;
    __bf16* vbuf  = pool + 8388608;
    __bf16* vtbuf = pool + 2 * 8388608;
    __bf16* abuf  = pool + 3 * 8388608;
    __bf16* f1buf = pool;  // 64 MB, aliases k/v/vt/attn (all dead by FFN1)

    __bf16* wkt = wts;
    __bf16* wvt = wts + 524288;
    __bf16* wot = wts + 1048576;
    __bf16* w1t = wts + 1572864;
    __bf16* w2t = wts + 3670016;

    for (int i = 0; i < 2; ++i) {
        transpose_cvt<<<dim3(16, 16), 256, 0, stream>>>(Wk + i * 262144, wkt + i * 262144, 512, 512);
        transpose_cvt<<<dim3(16, 16), 256, 0, stream>>>(Wv + i * 262144, wvt + i * 262144, 512, 512);
        transpose_cvt<<<dim3(16, 16), 256, 0, stream>>>(Wo + i * 262144, wot + i * 262144, 512, 512);
        transpose_cvt<<<dim3(64, 16), 256, 0, stream>>>(W1 + i * 1048576, w1t + i * 1048576, 512, 2048);
        transpose_cvt<<<dim3(16, 64), 256, 0, stream>>>(W2 + i * 1048576, w2t + i * 1048576, 2048, 512);
    }
    prep_kernel<<<2048, 256, 0, stream>>>(q_embed, qa_embed, pe, xf, xbf, ybf);

    for (int i = 0; i < 2; ++i) {
        gemm_kernel<0, 0><<<dim3(4, 128), 256, 0, stream>>>(
            xbf, wkt + i * 262144, bk + i * 512, nullptr, kbuf, 16384, 512, 512);
        gemm_kernel<0, 0><<<dim3(4, 128), 256, 0, stream>>>(
            ybf, wvt + i * 262144, bv + i * 512, nullptr, vbuf, 16384, 512, 512);
        vtrans_kernel<<<dim3(8, 8, 32), 256, 0, stream>>>(vbuf, vtbuf);
        attn_kernel<<<dim3(8, 8, 32), 256, 0, stream>>>(kbuf, vtbuf, fr, abuf);
        gemm_kernel<0, 1><<<dim3(4, 128), 256, 0, stream>>>(
            abuf, wot + i * 262144, bo + i * 512, xf, preln, 16384, 512, 512);
        ln_kernel<<<4096, 256, 0, stream>>>(preln, g1 + i * 512, be1 + i * 512, xf, xbf);
        gemm_kernel<1, 0><<<dim3(16, 128), 256, 0, stream>>>(
            xbf, w1t + i * 1048576, bf1 + i * 2048, nullptr, f1buf, 16384, 2048, 512);
        gemm_kernel<0, 1><<<dim3(4, 128), 256, 0, stream>>>(
            f1buf, w2t + i * 1048576, bf2 + i * 512, xf, preln, 16384, 512, 2048);
        float* xdst = (i == 1) ? (float*)d_out : xf;
        ln_kernel<<<4096, 256, 0, stream>>>(preln, g2 + i * 512, be2 + i * 512, xdst, xbf);
    }
}

// Round 5
// 532.497 us; speedup vs baseline: 1.3593x; 1.0918x over previous
//
#include <hip/hip_runtime.h>

#define B_ 32
#define S_ 512
#define D_ 512
#define H_ 8
#define DK_ 64
#define FF_ 2048

typedef float f32x4 __attribute__((ext_vector_type(4)));
typedef __bf16 bf16x8 __attribute__((ext_vector_type(8)));
typedef __bf16 bf16x4 __attribute__((ext_vector_type(4)));

// ---- async global->LDS, 16B per lane (dest must be wave-uniform base + lane*16) ----
__device__ __forceinline__ void gld_lds16(const void* gptr, void* lptr) {
    auto g = (__attribute__((address_space(1))) void*)(unsigned long long)gptr;
    auto l = (__attribute__((address_space(3))) void*)(unsigned)(unsigned long long)lptr;
    __builtin_amdgcn_global_load_lds(g, l, 16, 0, 0);
}

// ---- x = q+pe (fp32 + bf16), y = qa+pe (bf16) ----
__global__ __launch_bounds__(256) void prep_kernel(
    const float* __restrict__ q, const float* __restrict__ qa,
    const float* __restrict__ pe, float* __restrict__ xf,
    __bf16* __restrict__ xbf, __bf16* __restrict__ ybf)
{
    const int n4 = B_ * S_ * D_ / 4;
    for (int i = blockIdx.x * blockDim.x + threadIdx.x; i < n4;
         i += gridDim.x * blockDim.x) {
        float4 pv = ((const float4*)pe)[i & (S_ * D_ / 4 - 1)];
        float4 qv = ((const float4*)q)[i];
        float4 av = ((const float4*)qa)[i];
        float4 xv = make_float4(qv.x + pv.x, qv.y + pv.y, qv.z + pv.z, qv.w + pv.w);
        ((float4*)xf)[i] = xv;
        bf16x4 xb = {(__bf16)xv.x, (__bf16)xv.y, (__bf16)xv.z, (__bf16)xv.w};
        ((bf16x4*)xbf)[i] = xb;
        bf16x4 yb = {(__bf16)(av.x + pv.x), (__bf16)(av.y + pv.y),
                     (__bf16)(av.z + pv.z), (__bf16)(av.w + pv.w)};
        ((bf16x4*)ybf)[i] = yb;
    }
}

// ---- fp32 [R][C] -> bf16 [C][R] (weights to B^T layout) ----
__global__ __launch_bounds__(256) void transpose_cvt(
    const float* __restrict__ in, __bf16* __restrict__ out, int R, int C)
{
    __shared__ float tile[32][33];
    const int tc = blockIdx.x * 32, tr = blockIdx.y * 32;
    const int lx = threadIdx.x & 31, ly = threadIdx.x >> 5;
    #pragma unroll
    for (int yy = ly; yy < 32; yy += 8)
        tile[yy][lx] = in[(long)(tr + yy) * C + tc + lx];
    __syncthreads();
    #pragma unroll
    for (int yy = ly; yy < 32; yy += 8)
        out[(long)(tc + yy) * R + tr + lx] = (__bf16)tile[lx][yy];
}

// ---- V [B,S,H,DK] -> Vt [B,H,DK,S] ----
__global__ __launch_bounds__(256) void vtrans_kernel(
    const __bf16* __restrict__ V, __bf16* __restrict__ Vt)
{
    __shared__ __bf16 tile[64][72];
    const int sb = blockIdx.x, h = blockIdx.y, b = blockIdx.z;
    const int t = threadIdx.x;
    #pragma unroll
    for (int it = 0; it < 16; ++it) {
        int idx = it * 256 + t;
        int rr = idx >> 6, cc = idx & 63;
        tile[cc][rr] = V[((long)(b * S_ + sb * 64 + rr)) * D_ + h * DK_ + cc];
    }
    __syncthreads();
    #pragma unroll
    for (int it = 0; it < 16; ++it) {
        int idx = it * 256 + t;
        int dd = idx >> 6, so = idx & 63;
        Vt[((long)(b * H_ + h) * DK_ + dd) * S_ + sb * 64 + so] = tile[dd][so];
    }
}

// ---- GEMM v2: 128x128 tile, BK=64, XOR-swizzled LDS (T2), XCD block swizzle (T1) ----
// C[M,N] = A[M,K](bf16) @ Bt[N,K](bf16)^T + bias.
// MODE 0: bf16 out (+optional RELU). MODE 1: fp32 out = acc + bias + res.
// LDS[r][slot s] = G[r][s ^ (r&7)] via pre-swizzled global source; read with same XOR.
template <int RELU, int MODE>
__global__ __launch_bounds__(256) void gemm_kernel(
    const __bf16* __restrict__ A, const __bf16* __restrict__ Bt,
    const float* __restrict__ bias, const float* __restrict__ res,
    void* __restrict__ outv, int M, int N, int K)
{
    __shared__ __bf16 As[128 * 64];
    __shared__ __bf16 Bs[128 * 64];
    const int t = threadIdx.x;
    const int lane = t & 63;
    const int wv = t >> 6, wr = wv >> 1, wc = wv & 1;
    const int lr = lane & 15, lk = lane >> 4;

    // XCD-aware bijective block swizzle: contiguous work chunk per XCD.
    const int nwg = gridDim.x * gridDim.y;          // multiple of 8 for all our grids
    const int lin = blockIdx.y * gridDim.x + blockIdx.x;
    const int swz = (lin & 7) * (nwg >> 3) + (lin >> 3);
    const int m0 = (swz / gridDim.x) * 128, n0 = (swz % gridDim.x) * 128;

    // staging: row = issue*32 + (t>>3), slot = t&7, global col-chunk = slot^(row&7)
    const int srow = t >> 3;
    const int sslot = (t & 7) ^ (srow & 7);
    const __bf16* gA = A + (long)(m0 + srow) * K + sslot * 8;
    const __bf16* gB = Bt + (long)(n0 + srow) * K + sslot * 8;
    char* ldsA = (char*)As + t * 16;
    char* ldsB = (char*)Bs + t * 16;
    const long rstep = (long)32 * K;

    f32x4 acc[4][4] = {};
    for (int k0 = 0; k0 < K; k0 += 64) {
        #pragma unroll
        for (int u = 0; u < 4; ++u) {
            gld_lds16(gA + u * rstep + k0, ldsA + u * 4096);
            gld_lds16(gB + u * rstep + k0, ldsB + u * 4096);
        }
        __syncthreads();
        #pragma unroll
        for (int kk = 0; kk < 2; ++kk) {
            bf16x8 af[4], bfr[4];
            #pragma unroll
            for (int i = 0; i < 4; ++i) {
                const int rr = wr * 64 + i * 16 + lr;
                af[i] = *(const bf16x8*)((const char*)As +
                        (rr << 7) + (((kk * 4 + lk) ^ (rr & 7)) << 4));
            }
            #pragma unroll
            for (int j = 0; j < 4; ++j) {
                const int rr = wc * 64 + j * 16 + lr;
                bfr[j] = *(const bf16x8*)((const char*)Bs +
                         (rr << 7) + (((kk * 4 + lk) ^ (rr & 7)) << 4));
            }
            #pragma unroll
            for (int i = 0; i < 4; ++i)
                #pragma unroll
                for (int j = 0; j < 4; ++j)
                    acc[i][j] = __builtin_amdgcn_mfma_f32_16x16x32_bf16(
                        af[i], bfr[j], acc[i][j], 0, 0, 0);
        }
        __syncthreads();
    }

    #pragma unroll
    for (int i = 0; i < 4; ++i) {
        #pragma unroll
        for (int j = 0; j < 4; ++j) {
            const int n = n0 + wc * 64 + j * 16 + lr;
            const float bv = bias[n];
            #pragma unroll
            for (int r = 0; r < 4; ++r) {
                const int m = m0 + wr * 64 + i * 16 + lk * 4 + r;
                float v = acc[i][j][r] + bv;
                if (RELU) v = v > 0.f ? v : 0.f;
                const long off = (long)m * N + n;
                if (MODE == 0) ((__bf16*)outv)[off] = (__bf16)v;
                else           ((float*)outv)[off] = v + res[off];
            }
        }
    }
}

// ---- attention v4: block-cooperative LDS staging of K and V tiles ----
__global__ __launch_bounds__(256) void attn_kernel(
    const __bf16* __restrict__ Q, const __bf16* __restrict__ Vt,
    const float* __restrict__ fr, __bf16* __restrict__ Out)
{
    __shared__ __bf16 Ks[64 * 64];
    __shared__ __bf16 Vs[64 * 64];
    __shared__ __bf16 Plds[4][16 * 64];
    const int t = threadIdx.x;
    const int lane = t & 63, wv = t >> 6;
    const int lr = lane & 15, lk = lane >> 4;
    const int qb = blockIdx.x, h = blockIdx.y, b = blockIdx.z;
    const int qT = qb * 64 + wv * 16;

    const __bf16* qp = Q + (long)(b * S_ + qT + lr) * D_ + h * DK_ + lk * 8;
    const bf16x8 qf0 = *(const bf16x8*)qp;
    const bf16x8 qf1 = *(const bf16x8*)(qp + 32);

    float frv[4], ls[4];
    #pragma unroll
    for (int r = 0; r < 4; ++r) {
        frv[r] = fr[b * S_ + qT + lk * 4 + r] * 0.125f;  // fold 1/sqrt(64)
        ls[r] = 0.f;
    }
    f32x4 o[4] = {};

    const int srow = t >> 3;                       // 0..31
    const int sslot = (t & 7) ^ (srow & 7);        // XOR-swizzled 16B slot
    const __bf16* kstage = Q + (long)(b * S_ + srow) * D_ + h * DK_ + sslot * 8;
    const __bf16* vstage = Vt + ((long)(b * H_ + h) * DK_ + srow) * S_ + sslot * 8;
    char* kd = (char*)Ks + t * 16;
    char* vd = (char*)Vs + t * 16;
    __bf16* pl = &Plds[wv][0];
    const int sw = (lr & 7);                       // read-side swizzle key

    for (int ks = 0; ks <= qb * 64; ks += 64) {
        gld_lds16(kstage + (long)ks * D_, kd);
        gld_lds16(kstage + (long)(ks + 32) * D_, kd + 4096);
        gld_lds16(vstage + ks, vd);
        gld_lds16(vstage + ks + 32 * S_, vd + 4096);
        __syncthreads();

        f32x4 s[4] = {};
        #pragma unroll
        for (int j = 0; j < 4; ++j) {
            const char* kb = (const char*)Ks + ((j * 16 + lr) << 7);
            const bf16x8 kf0 = *(const bf16x8*)(kb + ((lk ^ sw) << 4));
            const bf16x8 kf1 = *(const bf16x8*)(kb + (((lk + 4) ^ sw) << 4));
            s[j] = __builtin_amdgcn_mfma_f32_16x16x32_bf16(qf0, kf0, s[j], 0, 0, 0);
            s[j] = __builtin_amdgcn_mfma_f32_16x16x32_bf16(qf1, kf1, s[j], 0, 0, 0);
        }
        #pragma unroll
        for (int j = 0; j < 4; ++j) {
            const int col = ks + j * 16 + lr;
            const int c8 = j * 2 + (lr >> 3), cb = lr & 7;
            #pragma unroll
            for (int r = 0; r < 4; ++r) {
                const int row = lk * 4 + r;
                const int sidx = row * 64 + ((c8 ^ (row & 7)) << 3) + cb;
                const float e = __expf(s[j][r] * frv[r]);
                const float p = (col < qT + row) ? e : 0.f;
                ls[r] += p;
                pl[sidx] = (__bf16)p;
            }
        }
        bf16x8 pf[2];
        #pragma unroll
        for (int kk = 0; kk < 2; ++kk) {
            const int ridx = lr * 64 + (((kk * 4 + lk) ^ sw) << 3);
            pf[kk] = *(const bf16x8*)&pl[ridx];
        }
        #pragma unroll
        for (int dt = 0; dt < 4; ++dt) {
            const char* vb = (const char*)Vs + ((dt * 16 + lr) << 7);
            #pragma unroll
            for (int kk = 0; kk < 2; ++kk) {
                const bf16x8 vf = *(const bf16x8*)(vb + (((kk * 4 + lk) ^ sw) << 4));
                o[dt] = __builtin_amdgcn_mfma_f32_16x16x32_bf16(pf[kk], vf, o[dt], 0, 0, 0);
            }
        }
        __syncthreads();
    }

    #pragma unroll
    for (int r = 0; r < 4; ++r) {
        #pragma unroll
        for (int d = 1; d < 16; d <<= 1)
            ls[r] += __shfl_xor(ls[r], d);
        const float inv = ls[r] > 0.f ? 1.f / ls[r] : 0.f;  // row 0 -> zeros
        #pragma unroll
        for (int dt = 0; dt < 4; ++dt)
            Out[(long)(b * S_ + qT + lk * 4 + r) * D_ + h * DK_ + dt * 16 + lr] =
                (__bf16)(o[dt][r] * inv);
    }
}

// ---- LayerNorm, wave per row; writes fp32 master + bf16 copy ----
__global__ __launch_bounds__(256) void ln_kernel(
    const float* __restrict__ pre, const float* __restrict__ g,
    const float* __restrict__ be, float* __restrict__ xout,
    __bf16* __restrict__ xbf)
{
    const int lane = threadIdx.x & 63, wv = threadIdx.x >> 6;
    const long row = (long)blockIdx.x * 4 + wv;
    const float* p = pre + row * D_ + lane * 8;
    const float4 a = ((const float4*)p)[0];
    const float4 c = ((const float4*)p)[1];
    float s  = a.x + a.y + a.z + a.w + c.x + c.y + c.z + c.w;
    float ss = a.x * a.x + a.y * a.y + a.z * a.z + a.w * a.w +
               c.x * c.x + c.y * c.y + c.z * c.z + c.w * c.w;
    #pragma unroll
    for (int d = 1; d < 64; d <<= 1) {
        s  += __shfl_xor(s, d);
        ss += __shfl_xor(ss, d);
    }
    const float mean = s * (1.f / 512.f);
    const float rstd = rsqrtf(ss * (1.f / 512.f) - mean * mean + 1e-5f);
    const float4 ga = ((const float4*)(g + lane * 8))[0];
    const float4 gc = ((const float4*)(g + lane * 8))[1];
    const float4 ba = ((const float4*)(be + lane * 8))[0];
    const float4 bc = ((const float4*)(be + lane * 8))[1];
    const float o0 = (a.x - mean) * rstd * ga.x + ba.x;
    const float o1 = (a.y - mean) * rstd * ga.y + ba.y;
    const float o2 = (a.z - mean) * rstd * ga.z + ba.z;
    const float o3 = (a.w - mean) * rstd * ga.w + ba.w;
    const float o4 = (c.x - mean) * rstd * gc.x + bc.x;
    const float o5 = (c.y - mean) * rstd * gc.y + bc.y;
    const float o6 = (c.z - mean) * rstd * gc.z + bc.z;
    const float o7 = (c.w - mean) * rstd * gc.w + bc.w;
    float* xo = xout + row * D_ + lane * 8;
    ((float4*)xo)[0] = make_float4(o0, o1, o2, o3);
    ((float4*)xo)[1] = make_float4(o4, o5, o6, o7);
    bf16x8 xb = {(__bf16)o0, (__bf16)o1, (__bf16)o2, (__bf16)o3,
                 (__bf16)o4, (__bf16)o5, (__bf16)o6, (__bf16)o7};
    *(bf16x8*)(xbf + row * D_ + lane * 8) = xb;
}

extern "C" void kernel_launch(void* const* d_in, const int* in_sizes, int n_in,
                              void* d_out, int out_size, void* d_ws, size_t ws_size,
                              hipStream_t stream) {
    const float* q_embed = (const float*)d_in[0];
    const float* qa_embed = (const float*)d_in[1];
    const float* fr  = (const float*)d_in[2];
    const float* pe  = (const float*)d_in[3];
    const float* Wk  = (const float*)d_in[4];
    const float* bk  = (const float*)d_in[5];
    const float* Wv  = (const float*)d_in[6];
    const float* bv  = (const float*)d_in[7];
    const float* Wo  = (const float*)d_in[8];
    const float* bo  = (const float*)d_in[9];
    const float* g1  = (const float*)d_in[10];
    const float* be1 = (const float*)d_in[11];
    const float* W1  = (const float*)d_in[12];
    const float* bf1 = (const float*)d_in[13];
    const float* W2  = (const float*)d_in[14];
    const float* bf2 = (const float*)d_in[15];
    const float* g2  = (const float*)d_in[16];
    const float* be2 = (const float*)d_in[17];

    // workspace layout (~174 MB)
    char* ws = (char*)d_ws;
    float*  xf    = (float*)(ws + 0);            // 32 MB fp32 residual master
    __bf16* xbf   = (__bf16*)(ws + 33554432);    // 16 MB
    __bf16* ybf   = (__bf16*)(ws + 50331648);    // 16 MB (persists both blocks)
    __bf16* pool  = (__bf16*)(ws + 67108864);    // 64 MB: k/v/vt/attn OR f1
    float*  preln = (float*)(ws + 134217728);    // 32 MB
    __bf16* wts   = (__bf16*)(ws + 167772160);   // 11 MB bf16 transposed weights

    __bf16* kbuf  = pool;
    __bf16* vbuf  = pool + 8388608;
    __bf16* vtbuf = pool + 2 * 8388608;
    __bf16* abuf  = pool + 3 * 8388608;
    __bf16* f1buf = pool;  // 64 MB, aliases k/v/vt/attn (all dead by FFN1)

    __bf16* wkt = wts;
    __bf16* wvt = wts + 524288;
    __bf16* wot = wts + 1048576;
    __bf16* w1t = wts + 1572864;
    __bf16* w2t = wts + 3670016;

    for (int i = 0; i < 2; ++i) {
        transpose_cvt<<<dim3(16, 16), 256, 0, stream>>>(Wk + i * 262144, wkt + i * 262144, 512, 512);
        transpose_cvt<<<dim3(16, 16), 256, 0, stream>>>(Wv + i * 262144, wvt + i * 262144, 512, 512);
        transpose_cvt<<<dim3(16, 16), 256, 0, stream>>>(Wo + i * 262144, wot + i * 262144, 512, 512);
        transpose_cvt<<<dim3(64, 16), 256, 0, stream>>>(W1 + i * 1048576, w1t + i * 1048576, 512, 2048);
        transpose_cvt<<<dim3(16, 64), 256, 0, stream>>>(W2 + i * 1048576, w2t + i * 1048576, 2048, 512);
    }
    prep_kernel<<<2048, 256, 0, stream>>>(q_embed, qa_embed, pe, xf, xbf, ybf);

    for (int i = 0; i < 2; ++i) {
        gemm_kernel<0, 0><<<dim3(4, 128), 256, 0, stream>>>(
            xbf, wkt + i * 262144, bk + i * 512, nullptr, kbuf, 16384, 512, 512);
        gemm_kernel<0, 0><<<dim3(4, 128), 256, 0, stream>>>(
            ybf, wvt + i * 262144, bv + i * 512, nullptr, vbuf, 16384, 512, 512);
        vtrans_kernel<<<dim3(8, 8, 32), 256, 0, stream>>>(vbuf, vtbuf);
        attn_kernel<<<dim3(8, 8, 32), 256, 0, stream>>>(kbuf, vtbuf, fr, abuf);
        gemm_kernel<0, 1><<<dim3(4, 128), 256, 0, stream>>>(
            abuf, wot + i * 262144, bo + i * 512, xf, preln, 16384, 512, 512);
        ln_kernel<<<4096, 256, 0, stream>>>(preln, g1 + i * 512, be1 + i * 512, xf, xbf);
        gemm_kernel<1, 0><<<dim3(16, 128), 256, 0, stream>>>(
            xbf, w1t + i * 1048576, bf1 + i * 2048, nullptr, f1buf, 16384, 2048, 512);
        gemm_kernel<0, 1><<<dim3(4, 128), 256, 0, stream>>>(
            f1buf, w2t + i * 1048576, bf2 + i * 512, xf, preln, 16384, 512, 2048);
        float* xdst = (i == 1) ? (float*)d_out : xf;
        ln_kernel<<<4096, 256, 0, stream>>>(preln, g2 + i * 512, be2 + i * 512, xdst, xbf);
    }
}

// Round 6
// 511.387 us; speedup vs baseline: 1.4154x; 1.0413x over previous
//
#include <hip/hip_runtime.h>

#define B_ 32
#define S_ 512
#define D_ 512
#define H_ 8
#define DK_ 64
#define FF_ 2048

typedef float f32x4 __attribute__((ext_vector_type(4)));
typedef __bf16 bf16x8 __attribute__((ext_vector_type(8)));
typedef __bf16 bf16x4 __attribute__((ext_vector_type(4)));

// ---- async global->LDS, 16B per lane (dest must be wave-uniform base + lane*16) ----
__device__ __forceinline__ void gld_lds16(const void* gptr, void* lptr) {
    auto g = (__attribute__((address_space(1))) void*)(unsigned long long)gptr;
    auto l = (__attribute__((address_space(3))) void*)(unsigned)(unsigned long long)lptr;
    __builtin_amdgcn_global_load_lds(g, l, 16, 0, 0);
}

// ---- x = q+pe (fp32 + bf16), y = qa+pe (bf16) ----
__global__ __launch_bounds__(256) void prep_kernel(
    const float* __restrict__ q, const float* __restrict__ qa,
    const float* __restrict__ pe, float* __restrict__ xf,
    __bf16* __restrict__ xbf, __bf16* __restrict__ ybf)
{
    const int n4 = B_ * S_ * D_ / 4;
    for (int i = blockIdx.x * blockDim.x + threadIdx.x; i < n4;
         i += gridDim.x * blockDim.x) {
        float4 pv = ((const float4*)pe)[i & (S_ * D_ / 4 - 1)];
        float4 qv = ((const float4*)q)[i];
        float4 av = ((const float4*)qa)[i];
        float4 xv = make_float4(qv.x + pv.x, qv.y + pv.y, qv.z + pv.z, qv.w + pv.w);
        ((float4*)xf)[i] = xv;
        bf16x4 xb = {(__bf16)xv.x, (__bf16)xv.y, (__bf16)xv.z, (__bf16)xv.w};
        ((bf16x4*)xbf)[i] = xb;
        bf16x4 yb = {(__bf16)(av.x + pv.x), (__bf16)(av.y + pv.y),
                     (__bf16)(av.z + pv.z), (__bf16)(av.w + pv.w)};
        ((bf16x4*)ybf)[i] = yb;
    }
}

// ---- fp32 [R][C] -> bf16 [C][R] (weights to B^T layout) ----
__global__ __launch_bounds__(256) void transpose_cvt(
    const float* __restrict__ in, __bf16* __restrict__ out, int R, int C)
{
    __shared__ float tile[32][33];
    const int tc = blockIdx.x * 32, tr = blockIdx.y * 32;
    const int lx = threadIdx.x & 31, ly = threadIdx.x >> 5;
    #pragma unroll
    for (int yy = ly; yy < 32; yy += 8)
        tile[yy][lx] = in[(long)(tr + yy) * C + tc + lx];
    __syncthreads();
    #pragma unroll
    for (int yy = ly; yy < 32; yy += 8)
        out[(long)(tc + yy) * R + tr + lx] = (__bf16)tile[lx][yy];
}

// ---- V [B,S,H,DK] -> Vt [B,H,DK,S] ----
__global__ __launch_bounds__(256) void vtrans_kernel(
    const __bf16* __restrict__ V, __bf16* __restrict__ Vt)
{
    __shared__ __bf16 tile[64][72];
    const int sb = blockIdx.x, h = blockIdx.y, b = blockIdx.z;
    const int t = threadIdx.x;
    #pragma unroll
    for (int it = 0; it < 16; ++it) {
        int idx = it * 256 + t;
        int rr = idx >> 6, cc = idx & 63;
        tile[cc][rr] = V[((long)(b * S_ + sb * 64 + rr)) * D_ + h * DK_ + cc];
    }
    __syncthreads();
    #pragma unroll
    for (int it = 0; it < 16; ++it) {
        int idx = it * 256 + t;
        int dd = idx >> 6, so = idx & 63;
        Vt[((long)(b * H_ + h) * DK_ + dd) * S_ + sb * 64 + so] = tile[dd][so];
    }
}

// ---- GEMM v3: 128x128, BK=64, T2 LDS swizzle, T1 XCD swizzle,
// 2-deep double-buffered pipeline with counted vmcnt (T3/T4-minimal).
// Main loop never drains vmcnt to 0: vmcnt(8) waits only the current tile's
// 8 loads; next tile's 8 stay in flight across both raw barriers.
template <int RELU, int MODE>
__global__ __launch_bounds__(256) void gemm_kernel(
    const __bf16* __restrict__ A, const __bf16* __restrict__ Bt,
    const float* __restrict__ bias, const float* __restrict__ res,
    void* __restrict__ outv, int M, int N, int K)
{
    __shared__ __bf16 As[2][128 * 64];
    __shared__ __bf16 Bs[2][128 * 64];
    const int t = threadIdx.x;
    const int lane = t & 63;
    const int wv = t >> 6, wr = wv >> 1, wc = wv & 1;
    const int lr = lane & 15, lk = lane >> 4;

    // XCD-aware bijective block swizzle
    const int nwg = gridDim.x * gridDim.y;
    const int lin = blockIdx.y * gridDim.x + blockIdx.x;
    const int swz = (lin & 7) * (nwg >> 3) + (lin >> 3);
    const int m0 = (swz / gridDim.x) * 128, n0 = (swz % gridDim.x) * 128;

    const int srow = t >> 3;
    const int sslot = (t & 7) ^ (srow & 7);
    const __bf16* gA = A + (long)(m0 + srow) * K + sslot * 8;
    const __bf16* gB = Bt + (long)(n0 + srow) * K + sslot * 8;
    const long rstep = (long)32 * K;

    auto STAGE = [&](int bsel, int k0) {
        char* ldsA = (char*)As[bsel] + t * 16;
        char* ldsB = (char*)Bs[bsel] + t * 16;
        #pragma unroll
        for (int u = 0; u < 4; ++u) {
            gld_lds16(gA + u * rstep + k0, ldsA + u * 4096);
            gld_lds16(gB + u * rstep + k0, ldsB + u * 4096);
        }
    };

    f32x4 acc[4][4] = {};
    auto COMPUTE = [&](int bsel) {
        #pragma unroll
        for (int kk = 0; kk < 2; ++kk) {
            bf16x8 af[4], bfr[4];
            #pragma unroll
            for (int i = 0; i < 4; ++i) {
                const int rr = wr * 64 + i * 16 + lr;
                af[i] = *(const bf16x8*)((const char*)As[bsel] +
                        (rr << 7) + (((kk * 4 + lk) ^ (rr & 7)) << 4));
            }
            #pragma unroll
            for (int j = 0; j < 4; ++j) {
                const int rr = wc * 64 + j * 16 + lr;
                bfr[j] = *(const bf16x8*)((const char*)Bs[bsel] +
                         (rr << 7) + (((kk * 4 + lk) ^ (rr & 7)) << 4));
            }
            #pragma unroll
            for (int i = 0; i < 4; ++i)
                #pragma unroll
                for (int j = 0; j < 4; ++j)
                    acc[i][j] = __builtin_amdgcn_mfma_f32_16x16x32_bf16(
                        af[i], bfr[j], acc[i][j], 0, 0, 0);
        }
    };

    const int NT = K >> 6;
    STAGE(0, 0);
    STAGE(1, 64);
    for (int kt = 0; kt < NT - 1; ++kt) {
        asm volatile("s_waitcnt vmcnt(8)" ::: "memory");  // current tile done; next stays in flight
        __builtin_amdgcn_s_barrier();
        COMPUTE(kt & 1);
        __builtin_amdgcn_s_barrier();                     // all waves done reading buf[kt&1]
        if (kt + 2 < NT) STAGE(kt & 1, (kt + 2) << 6);
    }
    asm volatile("s_waitcnt vmcnt(0)" ::: "memory");
    __builtin_amdgcn_s_barrier();
    COMPUTE((NT - 1) & 1);

    #pragma unroll
    for (int i = 0; i < 4; ++i) {
        #pragma unroll
        for (int j = 0; j < 4; ++j) {
            const int n = n0 + wc * 64 + j * 16 + lr;
            const float bv = bias[n];
            #pragma unroll
            for (int r = 0; r < 4; ++r) {
                const int m = m0 + wr * 64 + i * 16 + lk * 4 + r;
                float v = acc[i][j][r] + bv;
                if (RELU) v = v > 0.f ? v : 0.f;
                const long off = (long)m * N + n;
                if (MODE == 0) ((__bf16*)outv)[off] = (__bf16)v;
                else           ((float*)outv)[off] = v + res[off];
            }
        }
    }
}

// ---- attention v4: block-cooperative LDS staging of K and V tiles ----
__global__ __launch_bounds__(256) void attn_kernel(
    const __bf16* __restrict__ Q, const __bf16* __restrict__ Vt,
    const float* __restrict__ fr, __bf16* __restrict__ Out)
{
    __shared__ __bf16 Ks[64 * 64];
    __shared__ __bf16 Vs[64 * 64];
    __shared__ __bf16 Plds[4][16 * 64];
    const int t = threadIdx.x;
    const int lane = t & 63, wv = t >> 6;
    const int lr = lane & 15, lk = lane >> 4;
    const int qb = blockIdx.x, h = blockIdx.y, b = blockIdx.z;
    const int qT = qb * 64 + wv * 16;

    const __bf16* qp = Q + (long)(b * S_ + qT + lr) * D_ + h * DK_ + lk * 8;
    const bf16x8 qf0 = *(const bf16x8*)qp;
    const bf16x8 qf1 = *(const bf16x8*)(qp + 32);

    float frv[4], ls[4];
    #pragma unroll
    for (int r = 0; r < 4; ++r) {
        frv[r] = fr[b * S_ + qT + lk * 4 + r] * 0.125f;  // fold 1/sqrt(64)
        ls[r] = 0.f;
    }
    f32x4 o[4] = {};

    const int srow = t >> 3;                       // 0..31
    const int sslot = (t & 7) ^ (srow & 7);        // XOR-swizzled 16B slot
    const __bf16* kstage = Q + (long)(b * S_ + srow) * D_ + h * DK_ + sslot * 8;
    const __bf16* vstage = Vt + ((long)(b * H_ + h) * DK_ + srow) * S_ + sslot * 8;
    char* kd = (char*)Ks + t * 16;
    char* vd = (char*)Vs + t * 16;
    __bf16* pl = &Plds[wv][0];
    const int sw = (lr & 7);                       // read-side swizzle key

    for (int ks = 0; ks <= qb * 64; ks += 64) {
        gld_lds16(kstage + (long)ks * D_, kd);
        gld_lds16(kstage + (long)(ks + 32) * D_, kd + 4096);
        gld_lds16(vstage + ks, vd);
        gld_lds16(vstage + ks + 32 * S_, vd + 4096);
        __syncthreads();

        f32x4 s[4] = {};
        #pragma unroll
        for (int j = 0; j < 4; ++j) {
            const char* kb = (const char*)Ks + ((j * 16 + lr) << 7);
            const bf16x8 kf0 = *(const bf16x8*)(kb + ((lk ^ sw) << 4));
            const bf16x8 kf1 = *(const bf16x8*)(kb + (((lk + 4) ^ sw) << 4));
            s[j] = __builtin_amdgcn_mfma_f32_16x16x32_bf16(qf0, kf0, s[j], 0, 0, 0);
            s[j] = __builtin_amdgcn_mfma_f32_16x16x32_bf16(qf1, kf1, s[j], 0, 0, 0);
        }
        #pragma unroll
        for (int j = 0; j < 4; ++j) {
            const int col = ks + j * 16 + lr;
            const int c8 = j * 2 + (lr >> 3), cb = lr & 7;
            #pragma unroll
            for (int r = 0; r < 4; ++r) {
                const int row = lk * 4 + r;
                const int sidx = row * 64 + ((c8 ^ (row & 7)) << 3) + cb;
                const float e = __expf(s[j][r] * frv[r]);
                const float p = (col < qT + row) ? e : 0.f;
                ls[r] += p;
                pl[sidx] = (__bf16)p;
            }
        }
        bf16x8 pf[2];
        #pragma unroll
        for (int kk = 0; kk < 2; ++kk) {
            const int ridx = lr * 64 + (((kk * 4 + lk) ^ sw) << 3);
            pf[kk] = *(const bf16x8*)&pl[ridx];
        }
        #pragma unroll
        for (int dt = 0; dt < 4; ++dt) {
            const char* vb = (const char*)Vs + ((dt * 16 + lr) << 7);
            #pragma unroll
            for (int kk = 0; kk < 2; ++kk) {
                const bf16x8 vf = *(const bf16x8*)(vb + (((kk * 4 + lk) ^ sw) << 4));
                o[dt] = __builtin_amdgcn_mfma_f32_16x16x32_bf16(pf[kk], vf, o[dt], 0, 0, 0);
            }
        }
        __syncthreads();
    }

    #pragma unroll
    for (int r = 0; r < 4; ++r) {
        #pragma unroll
        for (int d = 1; d < 16; d <<= 1)
            ls[r] += __shfl_xor(ls[r], d);
        const float inv = ls[r] > 0.f ? 1.f / ls[r] : 0.f;  // row 0 -> zeros
        #pragma unroll
        for (int dt = 0; dt < 4; ++dt)
            Out[(long)(b * S_ + qT + lk * 4 + r) * D_ + h * DK_ + dt * 16 + lr] =
                (__bf16)(o[dt][r] * inv);
    }
}

// ---- LayerNorm, wave per row; writes fp32 master + bf16 copy ----
__global__ __launch_bounds__(256) void ln_kernel(
    const float* __restrict__ pre, const float* __restrict__ g,
    const float* __restrict__ be, float* __restrict__ xout,
    __bf16* __restrict__ xbf)
{
    const int lane = threadIdx.x & 63, wv = threadIdx.x >> 6;
    const long row = (long)blockIdx.x * 4 + wv;
    const float* p = pre + row * D_ + lane * 8;
    const float4 a = ((const float4*)p)[0];
    const float4 c = ((const float4*)p)[1];
    float s  = a.x + a.y + a.z + a.w + c.x + c.y + c.z + c.w;
    float ss = a.x * a.x + a.y * a.y + a.z * a.z + a.w * a.w +
               c.x * c.x + c.y * c.y + c.z * c.z + c.w * c.w;
    #pragma unroll
    for (int d = 1; d < 64; d <<= 1) {
        s  += __shfl_xor(s, d);
        ss += __shfl_xor(ss, d);
    }
    const float mean = s * (1.f / 512.f);
    const float rstd = rsqrtf(ss * (1.f / 512.f) - mean * mean + 1e-5f);
    const float4 ga = ((const float4*)(g + lane * 8))[0];
    const float4 gc = ((const float4*)(g + lane * 8))[1];
    const float4 ba = ((const float4*)(be + lane * 8))[0];
    const float4 bc = ((const float4*)(be + lane * 8))[1];
    const float o0 = (a.x - mean) * rstd * ga.x + ba.x;
    const float o1 = (a.y - mean) * rstd * ga.y + ba.y;
    const float o2 = (a.z - mean) * rstd * ga.z + ba.z;
    const float o3 = (a.w - mean) * rstd * ga.w + ba.w;
    const float o4 = (c.x - mean) * rstd * gc.x + bc.x;
    const float o5 = (c.y - mean) * rstd * gc.y + bc.y;
    const float o6 = (c.z - mean) * rstd * gc.z + bc.z;
    const float o7 = (c.w - mean) * rstd * gc.w + bc.w;
    float* xo = xout + row * D_ + lane * 8;
    ((float4*)xo)[0] = make_float4(o0, o1, o2, o3);
    ((float4*)xo)[1] = make_float4(o4, o5, o6, o7);
    bf16x8 xb = {(__bf16)o0, (__bf16)o1, (__bf16)o2, (__bf16)o3,
                 (__bf16)o4, (__bf16)o5, (__bf16)o6, (__bf16)o7};
    *(bf16x8*)(xbf + row * D_ + lane * 8) = xb;
}

extern "C" void kernel_launch(void* const* d_in, const int* in_sizes, int n_in,
                              void* d_out, int out_size, void* d_ws, size_t ws_size,
                              hipStream_t stream) {
    const float* q_embed = (const float*)d_in[0];
    const float* qa_embed = (const float*)d_in[1];
    const float* fr  = (const float*)d_in[2];
    const float* pe  = (const float*)d_in[3];
    const float* Wk  = (const float*)d_in[4];
    const float* bk  = (const float*)d_in[5];
    const float* Wv  = (const float*)d_in[6];
    const float* bv  = (const float*)d_in[7];
    const float* Wo  = (const float*)d_in[8];
    const float* bo  = (const float*)d_in[9];
    const float* g1  = (const float*)d_in[10];
    const float* be1 = (const float*)d_in[11];
    const float* W1  = (const float*)d_in[12];
    const float* bf1 = (const float*)d_in[13];
    const float* W2  = (const float*)d_in[14];
    const float* bf2 = (const float*)d_in[15];
    const float* g2  = (const float*)d_in[16];
    const float* be2 = (const float*)d_in[17];

    // workspace layout (~174 MB)
    char* ws = (char*)d_ws;
    float*  xf    = (float*)(ws + 0);            // 32 MB fp32 residual master
    __bf16* xbf   = (__bf16*)(ws + 33554432);    // 16 MB
    __bf16* ybf   = (__bf16*)(ws + 50331648);    // 16 MB (persists both blocks)
    __bf16* pool  = (__bf16*)(ws + 67108864);    // 64 MB: k/v/vt/attn OR f1
    float*  preln = (float*)(ws + 134217728);    // 32 MB
    __bf16* wts   = (__bf16*)(ws + 167772160);   // 11 MB bf16 transposed weights

    __bf16* kbuf  = pool;
    __bf16* vbuf  = pool + 8388608;
    __bf16* vtbuf = pool + 2 * 8388608;
    __bf16* abuf  = pool + 3 * 8388608;
    __bf16* f1buf = pool;  // 64 MB, aliases k/v/vt/attn (all dead by FFN1)

    __bf16* wkt = wts;
    __bf16* wvt = wts + 524288;
    __bf16* wot = wts + 1048576;
    __bf16* w1t = wts + 1572864;
    __bf16* w2t = wts + 3670016;

    for (int i = 0; i < 2; ++i) {
        transpose_cvt<<<dim3(16, 16), 256, 0, stream>>>(Wk + i * 262144, wkt + i * 262144, 512, 512);
        transpose_cvt<<<dim3(16, 16), 256, 0, stream>>>(Wv + i * 262144, wvt + i * 262144, 512, 512);
        transpose_cvt<<<dim3(16, 16), 256, 0, stream>>>(Wo + i * 262144, wot + i * 262144, 512, 512);
        transpose_cvt<<<dim3(64, 16), 256, 0, stream>>>(W1 + i * 1048576, w1t + i * 1048576, 512, 2048);
        transpose_cvt<<<dim3(16, 64), 256, 0, stream>>>(W2 + i * 1048576, w2t + i * 1048576, 2048, 512);
    }
    prep_kernel<<<2048, 256, 0, stream>>>(q_embed, qa_embed, pe, xf, xbf, ybf);

    for (int i = 0; i < 2; ++i) {
        gemm_kernel<0, 0><<<dim3(4, 128), 256, 0, stream>>>(
            xbf, wkt + i * 262144, bk + i * 512, nullptr, kbuf, 16384, 512, 512);
        gemm_kernel<0, 0><<<dim3(4, 128), 256, 0, stream>>>(
            ybf, wvt + i * 262144, bv + i * 512, nullptr, vbuf, 16384, 512, 512);
        vtrans_kernel<<<dim3(8, 8, 32), 256, 0, stream>>>(vbuf, vtbuf);
        attn_kernel<<<dim3(8, 8, 32), 256, 0, stream>>>(kbuf, vtbuf, fr, abuf);
        gemm_kernel<0, 1><<<dim3(4, 128), 256, 0, stream>>>(
            abuf, wot + i * 262144, bo + i * 512, xf, preln, 16384, 512, 512);
        ln_kernel<<<4096, 256, 0, stream>>>(preln, g1 + i * 512, be1 + i * 512, xf, xbf);
        gemm_kernel<1, 0><<<dim3(16, 128), 256, 0, stream>>>(
            xbf, w1t + i * 1048576, bf1 + i * 2048, nullptr, f1buf, 16384, 2048, 512);
        gemm_kernel<0, 1><<<dim3(4, 128), 256, 0, stream>>>(
            f1buf, w2t + i * 1048576, bf2 + i * 512, xf, preln, 16384, 512, 2048);
        float* xdst = (i == 1) ? (float*)d_out : xf;
        ln_kernel<<<4096, 256, 0, stream>>>(preln, g2 + i * 512, be2 + i * 512, xdst, xbf);
    }
}

// Round 7
// 491.171 us; speedup vs baseline: 1.4737x; 1.0412x over previous
//
#include <hip/hip_runtime.h>

#define B_ 32
#define S_ 512
#define D_ 512
#define H_ 8
#define DK_ 64
#define FF_ 2048

typedef float f32x4 __attribute__((ext_vector_type(4)));
typedef __bf16 bf16x8 __attribute__((ext_vector_type(8)));
typedef __bf16 bf16x4 __attribute__((ext_vector_type(4)));

// ---- async global->LDS, 16B per lane (dest must be wave-uniform base + lane*16) ----
__device__ __forceinline__ void gld_lds16(const void* gptr, void* lptr) {
    auto g = (__attribute__((address_space(1))) void*)(unsigned long long)gptr;
    auto l = (__attribute__((address_space(3))) void*)(unsigned)(unsigned long long)lptr;
    __builtin_amdgcn_global_load_lds(g, l, 16, 0, 0);
}

// ---- x = q+pe (bf16), y = qa+pe (bf16); bf16 master stream ----
__global__ __launch_bounds__(256) void prep_kernel(
    const float* __restrict__ q, const float* __restrict__ qa,
    const float* __restrict__ pe, __bf16* __restrict__ xbf,
    __bf16* __restrict__ ybf)
{
    const int n4 = B_ * S_ * D_ / 4;
    for (int i = blockIdx.x * blockDim.x + threadIdx.x; i < n4;
         i += gridDim.x * blockDim.x) {
        float4 pv = ((const float4*)pe)[i & (S_ * D_ / 4 - 1)];
        float4 qv = ((const float4*)q)[i];
        float4 av = ((const float4*)qa)[i];
        bf16x4 xb = {(__bf16)(qv.x + pv.x), (__bf16)(qv.y + pv.y),
                     (__bf16)(qv.z + pv.z), (__bf16)(qv.w + pv.w)};
        ((bf16x4*)xbf)[i] = xb;
        bf16x4 yb = {(__bf16)(av.x + pv.x), (__bf16)(av.y + pv.y),
                     (__bf16)(av.z + pv.z), (__bf16)(av.w + pv.w)};
        ((bf16x4*)ybf)[i] = yb;
    }
}

// ---- shared 32x32 transpose tile body: fp32 [R][C] -> bf16 [C][R] ----
__device__ __forceinline__ void ttile(
    const float* __restrict__ in, __bf16* __restrict__ out,
    int R, int C, int bx, int by, int t)
{
    __shared__ float tile[32][33];
    const int tc = bx * 32, tr = by * 32;
    const int lx = t & 31, ly = t >> 5;
    #pragma unroll
    for (int yy = ly; yy < 32; yy += 8)
        tile[yy][lx] = in[(long)(tr + yy) * C + tc + lx];
    __syncthreads();
    #pragma unroll
    for (int yy = ly; yy < 32; yy += 8)
        out[(long)(tc + yy) * R + tr + lx] = (__bf16)tile[lx][yy];
}

// six 512x512 weights (Wk,Wv,Wo x 2 blocks), z = mat*2 + i
__global__ __launch_bounds__(256) void transpose6(
    const float* __restrict__ Wk, const float* __restrict__ Wv,
    const float* __restrict__ Wo, __bf16* __restrict__ ok,
    __bf16* __restrict__ ov, __bf16* __restrict__ oo)
{
    const int z = blockIdx.z, sel = z >> 1, i = z & 1;
    const float* src = sel == 0 ? Wk : (sel == 1 ? Wv : Wo);
    __bf16* dst = sel == 0 ? ok : (sel == 1 ? ov : oo);
    ttile(src + (long)i * 262144, dst + (long)i * 262144, 512, 512,
          blockIdx.x, blockIdx.y, threadIdx.x);
}

// W1 [512,2048] x2, z = i
__global__ __launch_bounds__(256) void transposeW1(
    const float* __restrict__ W1, __bf16* __restrict__ o1)
{
    const int i = blockIdx.z;
    ttile(W1 + (long)i * 1048576, o1 + (long)i * 1048576, 512, 2048,
          blockIdx.x, blockIdx.y, threadIdx.x);
}

// W2 [2048,512] x2, z = i
__global__ __launch_bounds__(256) void transposeW2(
    const float* __restrict__ W2, __bf16* __restrict__ o2)
{
    const int i = blockIdx.z;
    ttile(W2 + (long)i * 1048576, o2 + (long)i * 1048576, 2048, 512,
          blockIdx.x, blockIdx.y, threadIdx.x);
}

// ---- V [B,S,H,DK] -> Vt [B,H,DK,S] ----
__global__ __launch_bounds__(256) void vtrans_kernel(
    const __bf16* __restrict__ V, __bf16* __restrict__ Vt)
{
    __shared__ __bf16 tile[64][72];
    const int sb = blockIdx.x, h = blockIdx.y, b = blockIdx.z;
    const int t = threadIdx.x;
    #pragma unroll
    for (int it = 0; it < 16; ++it) {
        int idx = it * 256 + t;
        int rr = idx >> 6, cc = idx & 63;
        tile[cc][rr] = V[((long)(b * S_ + sb * 64 + rr)) * D_ + h * DK_ + cc];
    }
    __syncthreads();
    #pragma unroll
    for (int it = 0; it < 16; ++it) {
        int idx = it * 256 + t;
        int dd = idx >> 6, so = idx & 63;
        Vt[((long)(b * H_ + h) * DK_ + dd) * S_ + sb * 64 + so] = tile[dd][so];
    }
}

// ---- GEMM v4: 128x128, BK=64, T2 LDS swizzle, T1 XCD swizzle, 2-deep counted-vmcnt
// pipeline; SWAPPED-OPERAND MFMA so each thread holds 4 consecutive n at fixed m
// -> packed bf16x4 epilogue stores (16 insts instead of 64 scalars).
// C (bf16) = A[M,K] @ Bt[N,K]^T + bias (+ res bf16 if MODE 1, RELU if RELU=1).
template <int RELU, int MODE>
__global__ __launch_bounds__(256) void gemm_kernel(
    const __bf16* __restrict__ A, const __bf16* __restrict__ Bt,
    const float* __restrict__ bias, const __bf16* __restrict__ res,
    __bf16* __restrict__ out, int M, int N, int K)
{
    __shared__ __bf16 As[2][128 * 64];
    __shared__ __bf16 Bs[2][128 * 64];
    const int t = threadIdx.x;
    const int lane = t & 63;
    const int wv = t >> 6, wr = wv >> 1, wc = wv & 1;
    const int lr = lane & 15, lk = lane >> 4;

    // XCD-aware bijective block swizzle
    const int nwg = gridDim.x * gridDim.y;
    const int lin = blockIdx.y * gridDim.x + blockIdx.x;
    const int swz = (lin & 7) * (nwg >> 3) + (lin >> 3);
    const int m0 = (swz / gridDim.x) * 128, n0 = (swz % gridDim.x) * 128;

    const int srow = t >> 3;
    const int sslot = (t & 7) ^ (srow & 7);
    const __bf16* gA = A + (long)(m0 + srow) * K + sslot * 8;
    const __bf16* gB = Bt + (long)(n0 + srow) * K + sslot * 8;
    const long rstep = (long)32 * K;

    auto STAGE = [&](int bsel, int k0) {
        char* ldsA = (char*)As[bsel] + t * 16;
        char* ldsB = (char*)Bs[bsel] + t * 16;
        #pragma unroll
        for (int u = 0; u < 4; ++u) {
            gld_lds16(gA + u * rstep + k0, ldsA + u * 4096);
            gld_lds16(gB + u * rstep + k0, ldsB + u * 4096);
        }
    };

    f32x4 acc[4][4] = {};
    auto COMPUTE = [&](int bsel) {
        #pragma unroll
        for (int kk = 0; kk < 2; ++kk) {
            bf16x8 af[4], bfr[4];
            #pragma unroll
            for (int i = 0; i < 4; ++i) {
                const int rr = wr * 64 + i * 16 + lr;
                af[i] = *(const bf16x8*)((const char*)As[bsel] +
                        (rr << 7) + (((kk * 4 + lk) ^ (rr & 7)) << 4));
            }
            #pragma unroll
            for (int j = 0; j < 4; ++j) {
                const int rr = wc * 64 + j * 16 + lr;
                bfr[j] = *(const bf16x8*)((const char*)Bs[bsel] +
                         (rr << 7) + (((kk * 4 + lk) ^ (rr & 7)) << 4));
            }
            #pragma unroll
            for (int i = 0; i < 4; ++i)
                #pragma unroll
                for (int j = 0; j < 4; ++j)
                    acc[i][j] = __builtin_amdgcn_mfma_f32_16x16x32_bf16(
                        bfr[j], af[i], acc[i][j], 0, 0, 0);  // swapped: row<->n, col<->m
        }
    };

    const int NT = K >> 6;
    STAGE(0, 0);
    STAGE(1, 64);
    for (int kt = 0; kt < NT - 1; ++kt) {
        asm volatile("s_waitcnt vmcnt(8)" ::: "memory");
        __builtin_amdgcn_s_barrier();
        COMPUTE(kt & 1);
        __builtin_amdgcn_s_barrier();
        if (kt + 2 < NT) STAGE(kt & 1, (kt + 2) << 6);
    }
    asm volatile("s_waitcnt vmcnt(0)" ::: "memory");
    __builtin_amdgcn_s_barrier();
    COMPUTE((NT - 1) & 1);

    // epilogue: thread holds m = ...+lr (col), n = ...+lk*4+r (row) -> pack 4 n
    #pragma unroll
    for (int i = 0; i < 4; ++i) {
        const int m = m0 + wr * 64 + i * 16 + lr;
        #pragma unroll
        for (int j = 0; j < 4; ++j) {
            const int nb = n0 + wc * 64 + j * 16 + lk * 4;
            const float4 bv = *(const float4*)(bias + nb);
            float v0 = acc[i][j][0] + bv.x;
            float v1 = acc[i][j][1] + bv.y;
            float v2 = acc[i][j][2] + bv.z;
            float v3 = acc[i][j][3] + bv.w;
            if (MODE == 1) {
                const bf16x4 rv = *(const bf16x4*)(res + (long)m * N + nb);
                v0 += (float)rv[0]; v1 += (float)rv[1];
                v2 += (float)rv[2]; v3 += (float)rv[3];
            }
            if (RELU) {
                v0 = v0 > 0.f ? v0 : 0.f; v1 = v1 > 0.f ? v1 : 0.f;
                v2 = v2 > 0.f ? v2 : 0.f; v3 = v3 > 0.f ? v3 : 0.f;
            }
            bf16x4 ov = {(__bf16)v0, (__bf16)v1, (__bf16)v2, (__bf16)v3};
            *(bf16x4*)(out + (long)m * N + nb) = ov;
        }
    }
}

// ---- attention v4: block-cooperative LDS staging of K and V tiles ----
__global__ __launch_bounds__(256) void attn_kernel(
    const __bf16* __restrict__ Q, const __bf16* __restrict__ Vt,
    const float* __restrict__ fr, __bf16* __restrict__ Out)
{
    __shared__ __bf16 Ks[64 * 64];
    __shared__ __bf16 Vs[64 * 64];
    __shared__ __bf16 Plds[4][16 * 64];
    const int t = threadIdx.x;
    const int lane = t & 63, wv = t >> 6;
    const int lr = lane & 15, lk = lane >> 4;
    const int qb = blockIdx.x, h = blockIdx.y, b = blockIdx.z;
    const int qT = qb * 64 + wv * 16;

    const __bf16* qp = Q + (long)(b * S_ + qT + lr) * D_ + h * DK_ + lk * 8;
    const bf16x8 qf0 = *(const bf16x8*)qp;
    const bf16x8 qf1 = *(const bf16x8*)(qp + 32);

    float frv[4], ls[4];
    #pragma unroll
    for (int r = 0; r < 4; ++r) {
        frv[r] = fr[b * S_ + qT + lk * 4 + r] * 0.125f;
        ls[r] = 0.f;
    }
    f32x4 o[4] = {};

    const int srow = t >> 3;
    const int sslot = (t & 7) ^ (srow & 7);
    const __bf16* kstage = Q + (long)(b * S_ + srow) * D_ + h * DK_ + sslot * 8;
    const __bf16* vstage = Vt + ((long)(b * H_ + h) * DK_ + srow) * S_ + sslot * 8;
    char* kd = (char*)Ks + t * 16;
    char* vd = (char*)Vs + t * 16;
    __bf16* pl = &Plds[wv][0];
    const int sw = (lr & 7);

    for (int ks = 0; ks <= qb * 64; ks += 64) {
        gld_lds16(kstage + (long)ks * D_, kd);
        gld_lds16(kstage + (long)(ks + 32) * D_, kd + 4096);
        gld_lds16(vstage + ks, vd);
        gld_lds16(vstage + ks + 32 * S_, vd + 4096);
        __syncthreads();

        f32x4 s[4] = {};
        #pragma unroll
        for (int j = 0; j < 4; ++j) {
            const char* kb = (const char*)Ks + ((j * 16 + lr) << 7);
            const bf16x8 kf0 = *(const bf16x8*)(kb + ((lk ^ sw) << 4));
            const bf16x8 kf1 = *(const bf16x8*)(kb + (((lk + 4) ^ sw) << 4));
            s[j] = __builtin_amdgcn_mfma_f32_16x16x32_bf16(qf0, kf0, s[j], 0, 0, 0);
            s[j] = __builtin_amdgcn_mfma_f32_16x16x32_bf16(qf1, kf1, s[j], 0, 0, 0);
        }
        #pragma unroll
        for (int j = 0; j < 4; ++j) {
            const int col = ks + j * 16 + lr;
            const int c8 = j * 2 + (lr >> 3), cb = lr & 7;
            #pragma unroll
            for (int r = 0; r < 4; ++r) {
                const int row = lk * 4 + r;
                const int sidx = row * 64 + ((c8 ^ (row & 7)) << 3) + cb;
                const float e = __expf(s[j][r] * frv[r]);
                const float p = (col < qT + row) ? e : 0.f;
                ls[r] += p;
                pl[sidx] = (__bf16)p;
            }
        }
        bf16x8 pf[2];
        #pragma unroll
        for (int kk = 0; kk < 2; ++kk) {
            const int ridx = lr * 64 + (((kk * 4 + lk) ^ sw) << 3);
            pf[kk] = *(const bf16x8*)&pl[ridx];
        }
        #pragma unroll
        for (int dt = 0; dt < 4; ++dt) {
            const char* vb = (const char*)Vs + ((dt * 16 + lr) << 7);
            #pragma unroll
            for (int kk = 0; kk < 2; ++kk) {
                const bf16x8 vf = *(const bf16x8*)(vb + (((kk * 4 + lk) ^ sw) << 4));
                o[dt] = __builtin_amdgcn_mfma_f32_16x16x32_bf16(pf[kk], vf, o[dt], 0, 0, 0);
            }
        }
        __syncthreads();
    }

    #pragma unroll
    for (int r = 0; r < 4; ++r) {
        #pragma unroll
        for (int d = 1; d < 16; d <<= 1)
            ls[r] += __shfl_xor(ls[r], d);
        const float inv = ls[r] > 0.f ? 1.f / ls[r] : 0.f;
        #pragma unroll
        for (int dt = 0; dt < 4; ++dt)
            Out[(long)(b * S_ + qT + lk * 4 + r) * D_ + h * DK_ + dt * 16 + lr] =
                (__bf16)(o[dt][r] * inv);
    }
}

// ---- LayerNorm: bf16 in, bf16 out (+fp32 out only when wf32 != 0) ----
__global__ __launch_bounds__(256) void ln_kernel(
    const __bf16* __restrict__ pre, const float* __restrict__ g,
    const float* __restrict__ be, float* __restrict__ xout,
    __bf16* __restrict__ xbf, int wf32)
{
    const int lane = threadIdx.x & 63, wv = threadIdx.x >> 6;
    const long row = (long)blockIdx.x * 4 + wv;
    const bf16x8 v = *(const bf16x8*)(pre + row * D_ + lane * 8);
    float f[8];
    #pragma unroll
    for (int k = 0; k < 8; ++k) f[k] = (float)v[k];
    float s = 0.f, ss = 0.f;
    #pragma unroll
    for (int k = 0; k < 8; ++k) { s += f[k]; ss += f[k] * f[k]; }
    #pragma unroll
    for (int d = 1; d < 64; d <<= 1) {
        s  += __shfl_xor(s, d);
        ss += __shfl_xor(ss, d);
    }
    const float mean = s * (1.f / 512.f);
    const float rstd = rsqrtf(ss * (1.f / 512.f) - mean * mean + 1e-5f);
    const float4 ga = ((const float4*)(g + lane * 8))[0];
    const float4 gc = ((const float4*)(g + lane * 8))[1];
    const float4 ba = ((const float4*)(be + lane * 8))[0];
    const float4 bc = ((const float4*)(be + lane * 8))[1];
    float o[8];
    o[0] = (f[0] - mean) * rstd * ga.x + ba.x;
    o[1] = (f[1] - mean) * rstd * ga.y + ba.y;
    o[2] = (f[2] - mean) * rstd * ga.z + ba.z;
    o[3] = (f[3] - mean) * rstd * ga.w + ba.w;
    o[4] = (f[4] - mean) * rstd * gc.x + bc.x;
    o[5] = (f[5] - mean) * rstd * gc.y + bc.y;
    o[6] = (f[6] - mean) * rstd * gc.z + bc.z;
    o[7] = (f[7] - mean) * rstd * gc.w + bc.w;
    bf16x8 xb = {(__bf16)o[0], (__bf16)o[1], (__bf16)o[2], (__bf16)o[3],
                 (__bf16)o[4], (__bf16)o[5], (__bf16)o[6], (__bf16)o[7]};
    *(bf16x8*)(xbf + row * D_ + lane * 8) = xb;
    if (wf32) {
        float* xo = xout + row * D_ + lane * 8;
        ((float4*)xo)[0] = make_float4(o[0], o[1], o[2], o[3]);
        ((float4*)xo)[1] = make_float4(o[4], o[5], o[6], o[7]);
    }
}

extern "C" void kernel_launch(void* const* d_in, const int* in_sizes, int n_in,
                              void* d_out, int out_size, void* d_ws, size_t ws_size,
                              hipStream_t stream) {
    const float* q_embed = (const float*)d_in[0];
    const float* qa_embed = (const float*)d_in[1];
    const float* fr  = (const float*)d_in[2];
    const float* pe  = (const float*)d_in[3];
    const float* Wk  = (const float*)d_in[4];
    const float* bk  = (const float*)d_in[5];
    const float* Wv  = (const float*)d_in[6];
    const float* bv  = (const float*)d_in[7];
    const float* Wo  = (const float*)d_in[8];
    const float* bo  = (const float*)d_in[9];
    const float* g1  = (const float*)d_in[10];
    const float* be1 = (const float*)d_in[11];
    const float* W1  = (const float*)d_in[12];
    const float* bf1 = (const float*)d_in[13];
    const float* W2  = (const float*)d_in[14];
    const float* bf2 = (const float*)d_in[15];
    const float* g2  = (const float*)d_in[16];
    const float* be2 = (const float*)d_in[17];

    // workspace layout (~128 MB)
    char* ws = (char*)d_ws;
    __bf16* xbf   = (__bf16*)(ws + 0);           // 16 MB bf16 residual master
    __bf16* ybf   = (__bf16*)(ws + 16777216);    // 16 MB
    __bf16* pool  = (__bf16*)(ws + 33554432);    // 64 MB: k/v/vt/attn OR f1
    __bf16* preln = (__bf16*)(ws + 100663296);   // 16 MB
    __bf16* wts   = (__bf16*)(ws + 117440512);   // 11 MB bf16 transposed weights

    __bf16* kbuf  = pool;
    __bf16* vbuf  = pool + 8388608;
    __bf16* vtbuf = pool + 2 * 8388608;
    __bf16* abuf  = pool + 3 * 8388608;
    __bf16* f1buf = pool;  // 64 MB, aliases k/v/vt/attn (all dead by FFN1)

    __bf16* wkt = wts;
    __bf16* wvt = wts + 524288;
    __bf16* wot = wts + 1048576;
    __bf16* w1t = wts + 1572864;
    __bf16* w2t = wts + 3670016;

    transpose6 <<<dim3(16, 16, 6), 256, 0, stream>>>(Wk, Wv, Wo, wkt, wvt, wot);
    transposeW1<<<dim3(64, 16, 2), 256, 0, stream>>>(W1, w1t);
    transposeW2<<<dim3(16, 64, 2), 256, 0, stream>>>(W2, w2t);
    prep_kernel<<<2048, 256, 0, stream>>>(q_embed, qa_embed, pe, xbf, ybf);

    for (int i = 0; i < 2; ++i) {
        gemm_kernel<0, 0><<<dim3(4, 128), 256, 0, stream>>>(
            xbf, wkt + i * 262144, bk + i * 512, nullptr, kbuf, 16384, 512, 512);
        gemm_kernel<0, 0><<<dim3(4, 128), 256, 0, stream>>>(
            ybf, wvt + i * 262144, bv + i * 512, nullptr, vbuf, 16384, 512, 512);
        vtrans_kernel<<<dim3(8, 8, 32), 256, 0, stream>>>(vbuf, vtbuf);
        attn_kernel<<<dim3(8, 8, 32), 256, 0, stream>>>(kbuf, vtbuf, fr, abuf);
        gemm_kernel<0, 1><<<dim3(4, 128), 256, 0, stream>>>(
            abuf, wot + i * 262144, bo + i * 512, xbf, preln, 16384, 512, 512);
        ln_kernel<<<4096, 256, 0, stream>>>(preln, g1 + i * 512, be1 + i * 512,
                                            (float*)d_out, xbf, 0);
        gemm_kernel<1, 0><<<dim3(16, 128), 256, 0, stream>>>(
            xbf, w1t + i * 1048576, bf1 + i * 2048, nullptr, f1buf, 16384, 2048, 512);
        gemm_kernel<0, 1><<<dim3(4, 128), 256, 0, stream>>>(
            f1buf, w2t + i * 1048576, bf2 + i * 512, xbf, preln, 16384, 512, 2048);
        ln_kernel<<<4096, 256, 0, stream>>>(preln, g2 + i * 512, be2 + i * 512,
                                            (float*)d_out, xbf, i == 1 ? 1 : 0);
    }
}

// Round 8
// 447.861 us; speedup vs baseline: 1.6162x; 1.0967x over previous
//
#include <hip/hip_runtime.h>

#define B_ 32
#define S_ 512
#define D_ 512
#define H_ 8
#define DK_ 64
#define FF_ 2048

typedef float f32x4 __attribute__((ext_vector_type(4)));
typedef __bf16 bf16x8 __attribute__((ext_vector_type(8)));
typedef __bf16 bf16x4 __attribute__((ext_vector_type(4)));

// ---- async global->LDS, 16B per lane (dest must be wave-uniform base + lane*16) ----
__device__ __forceinline__ void gld_lds16(const void* gptr, void* lptr) {
    auto g = (__attribute__((address_space(1))) void*)(unsigned long long)gptr;
    auto l = (__attribute__((address_space(3))) void*)(unsigned)(unsigned long long)lptr;
    __builtin_amdgcn_global_load_lds(g, l, 16, 0, 0);
}

// ---- x = q+pe (bf16), y = qa+pe (bf16); bf16 master stream ----
__global__ __launch_bounds__(256) void prep_kernel(
    const float* __restrict__ q, const float* __restrict__ qa,
    const float* __restrict__ pe, __bf16* __restrict__ xbf,
    __bf16* __restrict__ ybf)
{
    const int n4 = B_ * S_ * D_ / 4;
    for (int i = blockIdx.x * blockDim.x + threadIdx.x; i < n4;
         i += gridDim.x * blockDim.x) {
        float4 pv = ((const float4*)pe)[i & (S_ * D_ / 4 - 1)];
        float4 qv = ((const float4*)q)[i];
        float4 av = ((const float4*)qa)[i];
        bf16x4 xb = {(__bf16)(qv.x + pv.x), (__bf16)(qv.y + pv.y),
                     (__bf16)(qv.z + pv.z), (__bf16)(qv.w + pv.w)};
        ((bf16x4*)xbf)[i] = xb;
        bf16x4 yb = {(__bf16)(av.x + pv.x), (__bf16)(av.y + pv.y),
                     (__bf16)(av.z + pv.z), (__bf16)(av.w + pv.w)};
        ((bf16x4*)ybf)[i] = yb;
    }
}

// ---- shared 32x32 transpose tile body: fp32 [R][C] -> bf16 [C][R] ----
__device__ __forceinline__ void ttile(
    const float* __restrict__ in, __bf16* __restrict__ out,
    int R, int C, int bx, int by, int t)
{
    __shared__ float tile[32][33];
    const int tc = bx * 32, tr = by * 32;
    const int lx = t & 31, ly = t >> 5;
    #pragma unroll
    for (int yy = ly; yy < 32; yy += 8)
        tile[yy][lx] = in[(long)(tr + yy) * C + tc + lx];
    __syncthreads();
    #pragma unroll
    for (int yy = ly; yy < 32; yy += 8)
        out[(long)(tc + yy) * R + tr + lx] = (__bf16)tile[lx][yy];
}

// six 512x512 weights (Wk,Wv,Wo x 2 blocks), z = mat*2 + i
__global__ __launch_bounds__(256) void transpose6(
    const float* __restrict__ Wk, const float* __restrict__ Wv,
    const float* __restrict__ Wo, __bf16* __restrict__ ok,
    __bf16* __restrict__ ov, __bf16* __restrict__ oo)
{
    const int z = blockIdx.z, sel = z >> 1, i = z & 1;
    const float* src = sel == 0 ? Wk : (sel == 1 ? Wv : Wo);
    __bf16* dst = sel == 0 ? ok : (sel == 1 ? ov : oo);
    ttile(src + (long)i * 262144, dst + (long)i * 262144, 512, 512,
          blockIdx.x, blockIdx.y, threadIdx.x);
}

// W1 [512,2048] x2, z = i
__global__ __launch_bounds__(256) void transposeW1(
    const float* __restrict__ W1, __bf16* __restrict__ o1)
{
    const int i = blockIdx.z;
    ttile(W1 + (long)i * 1048576, o1 + (long)i * 1048576, 512, 2048,
          blockIdx.x, blockIdx.y, threadIdx.x);
}

// W2 [2048,512] x2, z = i
__global__ __launch_bounds__(256) void transposeW2(
    const float* __restrict__ W2, __bf16* __restrict__ o2)
{
    const int i = blockIdx.z;
    ttile(W2 + (long)i * 1048576, o2 + (long)i * 1048576, 2048, 512,
          blockIdx.x, blockIdx.y, threadIdx.x);
}

// ---- GEMM v5: 128x128, BK=64, T2 LDS swizzle, T1 XCD swizzle, 2-deep counted-vmcnt
// pipeline (R6-proven form: mfma(af,bfr), scalar epilogue).
// MODE 0: bf16 out (+RELU). MODE 1: bf16 out = acc + bias + res(bf16).
// MODE 2: V-projection with fused transpose: out is Vt [B,H,DK,S]; thread's 4
//         consecutive m (= s within one b) at fixed n (= h*64+dk) -> packed bf16x4.
template <int RELU, int MODE>
__global__ __launch_bounds__(256) void gemm_kernel(
    const __bf16* __restrict__ A, const __bf16* __restrict__ Bt,
    const float* __restrict__ bias, const __bf16* __restrict__ res,
    __bf16* __restrict__ out, int M, int N, int K)
{
    __shared__ __bf16 As[2][128 * 64];
    __shared__ __bf16 Bs[2][128 * 64];
    const int t = threadIdx.x;
    const int lane = t & 63;
    const int wv = t >> 6, wr = wv >> 1, wc = wv & 1;
    const int lr = lane & 15, lk = lane >> 4;

    // XCD-aware bijective block swizzle
    const int nwg = gridDim.x * gridDim.y;
    const int lin = blockIdx.y * gridDim.x + blockIdx.x;
    const int swz = (lin & 7) * (nwg >> 3) + (lin >> 3);
    const int m0 = (swz / gridDim.x) * 128, n0 = (swz % gridDim.x) * 128;

    const int srow = t >> 3;
    const int sslot = (t & 7) ^ (srow & 7);
    const __bf16* gA = A + (long)(m0 + srow) * K + sslot * 8;
    const __bf16* gB = Bt + (long)(n0 + srow) * K + sslot * 8;
    const long rstep = (long)32 * K;

    auto STAGE = [&](int bsel, int k0) {
        char* ldsA = (char*)As[bsel] + t * 16;
        char* ldsB = (char*)Bs[bsel] + t * 16;
        #pragma unroll
        for (int u = 0; u < 4; ++u) {
            gld_lds16(gA + u * rstep + k0, ldsA + u * 4096);
            gld_lds16(gB + u * rstep + k0, ldsB + u * 4096);
        }
    };

    f32x4 acc[4][4] = {};
    auto COMPUTE = [&](int bsel) {
        #pragma unroll
        for (int kk = 0; kk < 2; ++kk) {
            bf16x8 af[4], bfr[4];
            #pragma unroll
            for (int i = 0; i < 4; ++i) {
                const int rr = wr * 64 + i * 16 + lr;
                af[i] = *(const bf16x8*)((const char*)As[bsel] +
                        (rr << 7) + (((kk * 4 + lk) ^ (rr & 7)) << 4));
            }
            #pragma unroll
            for (int j = 0; j < 4; ++j) {
                const int rr = wc * 64 + j * 16 + lr;
                bfr[j] = *(const bf16x8*)((const char*)Bs[bsel] +
                         (rr << 7) + (((kk * 4 + lk) ^ (rr & 7)) << 4));
            }
            #pragma unroll
            for (int i = 0; i < 4; ++i)
                #pragma unroll
                for (int j = 0; j < 4; ++j)
                    acc[i][j] = __builtin_amdgcn_mfma_f32_16x16x32_bf16(
                        af[i], bfr[j], acc[i][j], 0, 0, 0);
        }
    };

    const int NT = K >> 6;
    STAGE(0, 0);
    STAGE(1, 64);
    for (int kt = 0; kt < NT - 1; ++kt) {
        asm volatile("s_waitcnt vmcnt(8)" ::: "memory");
        __builtin_amdgcn_s_barrier();
        COMPUTE(kt & 1);
        __builtin_amdgcn_s_barrier();
        if (kt + 2 < NT) STAGE(kt & 1, (kt + 2) << 6);
    }
    asm volatile("s_waitcnt vmcnt(0)" ::: "memory");
    __builtin_amdgcn_s_barrier();
    COMPUTE((NT - 1) & 1);

    #pragma unroll
    for (int i = 0; i < 4; ++i) {
        #pragma unroll
        for (int j = 0; j < 4; ++j) {
            const int n = n0 + wc * 64 + j * 16 + lr;
            const float bv = bias[n];
            if (MODE == 2) {
                const int mb = m0 + wr * 64 + i * 16 + lk * 4;
                const int b = mb >> 9, s = mb & 511;
                bf16x4 ov = {(__bf16)(acc[i][j][0] + bv),
                             (__bf16)(acc[i][j][1] + bv),
                             (__bf16)(acc[i][j][2] + bv),
                             (__bf16)(acc[i][j][3] + bv)};
                *(bf16x4*)(out + (((long)(b * 8 + (n >> 6)) * 64 + (n & 63)) << 9) + s) = ov;
            } else {
                #pragma unroll
                for (int r = 0; r < 4; ++r) {
                    const int m = m0 + wr * 64 + i * 16 + lk * 4 + r;
                    const long off = (long)m * N + n;
                    float v = acc[i][j][r] + bv;
                    if (MODE == 1) v += (float)res[off];
                    if (RELU) v = v > 0.f ? v : 0.f;
                    out[off] = (__bf16)v;
                }
            }
        }
    }
}

// ---- attention v4: block-cooperative LDS staging of K and V tiles ----
__global__ __launch_bounds__(256) void attn_kernel(
    const __bf16* __restrict__ Q, const __bf16* __restrict__ Vt,
    const float* __restrict__ fr, __bf16* __restrict__ Out)
{
    __shared__ __bf16 Ks[64 * 64];
    __shared__ __bf16 Vs[64 * 64];
    __shared__ __bf16 Plds[4][16 * 64];
    const int t = threadIdx.x;
    const int lane = t & 63, wv = t >> 6;
    const int lr = lane & 15, lk = lane >> 4;
    const int qb = blockIdx.x, h = blockIdx.y, b = blockIdx.z;
    const int qT = qb * 64 + wv * 16;

    const __bf16* qp = Q + (long)(b * S_ + qT + lr) * D_ + h * DK_ + lk * 8;
    const bf16x8 qf0 = *(const bf16x8*)qp;
    const bf16x8 qf1 = *(const bf16x8*)(qp + 32);

    float frv[4], ls[4];
    #pragma unroll
    for (int r = 0; r < 4; ++r) {
        frv[r] = fr[b * S_ + qT + lk * 4 + r] * 0.125f;
        ls[r] = 0.f;
    }
    f32x4 o[4] = {};

    const int srow = t >> 3;
    const int sslot = (t & 7) ^ (srow & 7);
    const __bf16* kstage = Q + (long)(b * S_ + srow) * D_ + h * DK_ + sslot * 8;
    const __bf16* vstage = Vt + ((long)(b * H_ + h) * DK_ + srow) * S_ + sslot * 8;
    char* kd = (char*)Ks + t * 16;
    char* vd = (char*)Vs + t * 16;
    __bf16* pl = &Plds[wv][0];
    const int sw = (lr & 7);

    for (int ks = 0; ks <= qb * 64; ks += 64) {
        gld_lds16(kstage + (long)ks * D_, kd);
        gld_lds16(kstage + (long)(ks + 32) * D_, kd + 4096);
        gld_lds16(vstage + ks, vd);
        gld_lds16(vstage + ks + 32 * S_, vd + 4096);
        __syncthreads();

        f32x4 s[4] = {};
        #pragma unroll
        for (int j = 0; j < 4; ++j) {
            const char* kb = (const char*)Ks + ((j * 16 + lr) << 7);
            const bf16x8 kf0 = *(const bf16x8*)(kb + ((lk ^ sw) << 4));
            const bf16x8 kf1 = *(const bf16x8*)(kb + (((lk + 4) ^ sw) << 4));
            s[j] = __builtin_amdgcn_mfma_f32_16x16x32_bf16(qf0, kf0, s[j], 0, 0, 0);
            s[j] = __builtin_amdgcn_mfma_f32_16x16x32_bf16(qf1, kf1, s[j], 0, 0, 0);
        }
        #pragma unroll
        for (int j = 0; j < 4; ++j) {
            const int col = ks + j * 16 + lr;
            const int c8 = j * 2 + (lr >> 3), cb = lr & 7;
            #pragma unroll
            for (int r = 0; r < 4; ++r) {
                const int row = lk * 4 + r;
                const int sidx = row * 64 + ((c8 ^ (row & 7)) << 3) + cb;
                const float e = __expf(s[j][r] * frv[r]);
                const float p = (col < qT + row) ? e : 0.f;
                ls[r] += p;
                pl[sidx] = (__bf16)p;
            }
        }
        bf16x8 pf[2];
        #pragma unroll
        for (int kk = 0; kk < 2; ++kk) {
            const int ridx = lr * 64 + (((kk * 4 + lk) ^ sw) << 3);
            pf[kk] = *(const bf16x8*)&pl[ridx];
        }
        #pragma unroll
        for (int dt = 0; dt < 4; ++dt) {
            const char* vb = (const char*)Vs + ((dt * 16 + lr) << 7);
            #pragma unroll
            for (int kk = 0; kk < 2; ++kk) {
                const bf16x8 vf = *(const bf16x8*)(vb + (((kk * 4 + lk) ^ sw) << 4));
                o[dt] = __builtin_amdgcn_mfma_f32_16x16x32_bf16(pf[kk], vf, o[dt], 0, 0, 0);
            }
        }
        __syncthreads();
    }

    #pragma unroll
    for (int r = 0; r < 4; ++r) {
        #pragma unroll
        for (int d = 1; d < 16; d <<= 1)
            ls[r] += __shfl_xor(ls[r], d);
        const float inv = ls[r] > 0.f ? 1.f / ls[r] : 0.f;
        #pragma unroll
        for (int dt = 0; dt < 4; ++dt)
            Out[(long)(b * S_ + qT + lk * 4 + r) * D_ + h * DK_ + dt * 16 + lr] =
                (__bf16)(o[dt][r] * inv);
    }
}

// ---- LayerNorm: bf16 in, bf16 out (+fp32 out only when wf32 != 0) ----
__global__ __launch_bounds__(256) void ln_kernel(
    const __bf16* __restrict__ pre, const float* __restrict__ g,
    const float* __restrict__ be, float* __restrict__ xout,
    __bf16* __restrict__ xbf, int wf32)
{
    const int lane = threadIdx.x & 63, wv = threadIdx.x >> 6;
    const long row = (long)blockIdx.x * 4 + wv;
    const bf16x8 v = *(const bf16x8*)(pre + row * D_ + lane * 8);
    float f[8];
    #pragma unroll
    for (int k = 0; k < 8; ++k) f[k] = (float)v[k];
    float s = 0.f, ss = 0.f;
    #pragma unroll
    for (int k = 0; k < 8; ++k) { s += f[k]; ss += f[k] * f[k]; }
    #pragma unroll
    for (int d = 1; d < 64; d <<= 1) {
        s  += __shfl_xor(s, d);
        ss += __shfl_xor(ss, d);
    }
    const float mean = s * (1.f / 512.f);
    const float rstd = rsqrtf(ss * (1.f / 512.f) - mean * mean + 1e-5f);
    const float4 ga = ((const float4*)(g + lane * 8))[0];
    const float4 gc = ((const float4*)(g + lane * 8))[1];
    const float4 ba = ((const float4*)(be + lane * 8))[0];
    const float4 bc = ((const float4*)(be + lane * 8))[1];
    float o[8];
    o[0] = (f[0] - mean) * rstd * ga.x + ba.x;
    o[1] = (f[1] - mean) * rstd * ga.y + ba.y;
    o[2] = (f[2] - mean) * rstd * ga.z + ba.z;
    o[3] = (f[3] - mean) * rstd * ga.w + ba.w;
    o[4] = (f[4] - mean) * rstd * gc.x + bc.x;
    o[5] = (f[5] - mean) * rstd * gc.y + bc.y;
    o[6] = (f[6] - mean) * rstd * gc.z + bc.z;
    o[7] = (f[7] - mean) * rstd * gc.w + bc.w;
    bf16x8 xb = {(__bf16)o[0], (__bf16)o[1], (__bf16)o[2], (__bf16)o[3],
                 (__bf16)o[4], (__bf16)o[5], (__bf16)o[6], (__bf16)o[7]};
    *(bf16x8*)(xbf + row * D_ + lane * 8) = xb;
    if (wf32) {
        float* xo = xout + row * D_ + lane * 8;
        ((float4*)xo)[0] = make_float4(o[0], o[1], o[2], o[3]);
        ((float4*)xo)[1] = make_float4(o[4], o[5], o[6], o[7]);
    }
}

extern "C" void kernel_launch(void* const* d_in, const int* in_sizes, int n_in,
                              void* d_out, int out_size, void* d_ws, size_t ws_size,
                              hipStream_t stream) {
    const float* q_embed = (const float*)d_in[0];
    const float* qa_embed = (const float*)d_in[1];
    const float* fr  = (const float*)d_in[2];
    const float* pe  = (const float*)d_in[3];
    const float* Wk  = (const float*)d_in[4];
    const float* bk  = (const float*)d_in[5];
    const float* Wv  = (const float*)d_in[6];
    const float* bv  = (const float*)d_in[7];
    const float* Wo  = (const float*)d_in[8];
    const float* bo  = (const float*)d_in[9];
    const float* g1  = (const float*)d_in[10];
    const float* be1 = (const float*)d_in[11];
    const float* W1  = (const float*)d_in[12];
    const float* bf1 = (const float*)d_in[13];
    const float* W2  = (const float*)d_in[14];
    const float* bf2 = (const float*)d_in[15];
    const float* g2  = (const float*)d_in[16];
    const float* be2 = (const float*)d_in[17];

    // workspace layout (~128 MB)
    char* ws = (char*)d_ws;
    __bf16* xbf   = (__bf16*)(ws + 0);           // 16 MB bf16 residual master
    __bf16* ybf   = (__bf16*)(ws + 16777216);    // 16 MB
    __bf16* pool  = (__bf16*)(ws + 33554432);    // 64 MB: k/vt/attn OR f1
    __bf16* preln = (__bf16*)(ws + 100663296);   // 16 MB
    __bf16* wts   = (__bf16*)(ws + 117440512);   // 11 MB bf16 transposed weights

    __bf16* kbuf  = pool;
    __bf16* vtbuf = pool + 8388608;
    __bf16* abuf  = pool + 2 * 8388608;
    __bf16* f1buf = pool;  // 64 MB, aliases k/vt/attn (all dead by FFN1)

    __bf16* wkt = wts;
    __bf16* wvt = wts + 524288;
    __bf16* wot = wts + 1048576;
    __bf16* w1t = wts + 1572864;
    __bf16* w2t = wts + 3670016;

    transpose6 <<<dim3(16, 16, 6), 256, 0, stream>>>(Wk, Wv, Wo, wkt, wvt, wot);
    transposeW1<<<dim3(64, 16, 2), 256, 0, stream>>>(W1, w1t);
    transposeW2<<<dim3(16, 64, 2), 256, 0, stream>>>(W2, w2t);
    prep_kernel<<<2048, 256, 0, stream>>>(q_embed, qa_embed, pe, xbf, ybf);

    for (int i = 0; i < 2; ++i) {
        gemm_kernel<0, 0><<<dim3(4, 128), 256, 0, stream>>>(
            xbf, wkt + i * 262144, bk + i * 512, nullptr, kbuf, 16384, 512, 512);
        gemm_kernel<0, 2><<<dim3(4, 128), 256, 0, stream>>>(
            ybf, wvt + i * 262144, bv + i * 512, nullptr, vtbuf, 16384, 512, 512);
        attn_kernel<<<dim3(8, 8, 32), 256, 0, stream>>>(kbuf, vtbuf, fr, abuf);
        gemm_kernel<0, 1><<<dim3(4, 128), 256, 0, stream>>>(
            abuf, wot + i * 262144, bo + i * 512, xbf, preln, 16384, 512, 512);
        ln_kernel<<<4096, 256, 0, stream>>>(preln, g1 + i * 512, be1 + i * 512,
                                            (float*)d_out, xbf, 0);
        gemm_kernel<1, 0><<<dim3(16, 128), 256, 0, stream>>>(
            xbf, w1t + i * 1048576, bf1 + i * 2048, nullptr, f1buf, 16384, 2048, 512);
        gemm_kernel<0, 1><<<dim3(4, 128), 256, 0, stream>>>(
            f1buf, w2t + i * 1048576, bf2 + i * 512, xbf, preln, 16384, 512, 2048);
        ln_kernel<<<4096, 256, 0, stream>>>(preln, g2 + i * 512, be2 + i * 512,
                                            (float*)d_out, xbf, i == 1 ? 1 : 0);
    }
}

// Round 9
// 438.028 us; speedup vs baseline: 1.6525x; 1.0224x over previous
//
#include <hip/hip_runtime.h>

#define B_ 32
#define S_ 512
#define D_ 512
#define H_ 8
#define DK_ 64
#define FF_ 2048

typedef float f32x4 __attribute__((ext_vector_type(4)));
typedef __bf16 bf16x8 __attribute__((ext_vector_type(8)));
typedef __bf16 bf16x4 __attribute__((ext_vector_type(4)));

// ---- async global->LDS, 16B per lane (dest must be wave-uniform base + lane*16) ----
__device__ __forceinline__ void gld_lds16(const void* gptr, void* lptr) {
    auto g = (__attribute__((address_space(1))) void*)(unsigned long long)gptr;
    auto l = (__attribute__((address_space(3))) void*)(unsigned)(unsigned long long)lptr;
    __builtin_amdgcn_global_load_lds(g, l, 16, 0, 0);
}

// ---- x = q+pe (bf16), y = qa+pe (bf16); bf16 master stream ----
__global__ __launch_bounds__(256) void prep_kernel(
    const float* __restrict__ q, const float* __restrict__ qa,
    const float* __restrict__ pe, __bf16* __restrict__ xbf,
    __bf16* __restrict__ ybf)
{
    const int n4 = B_ * S_ * D_ / 4;
    for (int i = blockIdx.x * blockDim.x + threadIdx.x; i < n4;
         i += gridDim.x * blockDim.x) {
        float4 pv = ((const float4*)pe)[i & (S_ * D_ / 4 - 1)];
        float4 qv = ((const float4*)q)[i];
        float4 av = ((const float4*)qa)[i];
        bf16x4 xb = {(__bf16)(qv.x + pv.x), (__bf16)(qv.y + pv.y),
                     (__bf16)(qv.z + pv.z), (__bf16)(qv.w + pv.w)};
        ((bf16x4*)xbf)[i] = xb;
        bf16x4 yb = {(__bf16)(av.x + pv.x), (__bf16)(av.y + pv.y),
                     (__bf16)(av.z + pv.z), (__bf16)(av.w + pv.w)};
        ((bf16x4*)ybf)[i] = yb;
    }
}

// ---- shared 32x32 transpose tile body: fp32 [R][C] -> bf16 [C][R] ----
__device__ __forceinline__ void ttile(
    const float* __restrict__ in, __bf16* __restrict__ out,
    int R, int C, int bx, int by, int t)
{
    __shared__ float tile[32][33];
    const int tc = bx * 32, tr = by * 32;
    const int lx = t & 31, ly = t >> 5;
    #pragma unroll
    for (int yy = ly; yy < 32; yy += 8)
        tile[yy][lx] = in[(long)(tr + yy) * C + tc + lx];
    __syncthreads();
    #pragma unroll
    for (int yy = ly; yy < 32; yy += 8)
        out[(long)(tc + yy) * R + tr + lx] = (__bf16)tile[lx][yy];
}

// ---- all weight transposes in one flat-grid dispatch ----
// blocks 0..1535: Wk/Wv/Wo (6 x 256 tiles of 512x512)
// blocks 1536..3583: W1 (2 x 1024 tiles of [512,2048])
// blocks 3584..5631: W2 (2 x 1024 tiles of [2048,512])
__global__ __launch_bounds__(256) void transpose_all(
    const float* __restrict__ Wk, const float* __restrict__ Wv,
    const float* __restrict__ Wo, const float* __restrict__ W1,
    const float* __restrict__ W2, __bf16* __restrict__ ok,
    __bf16* __restrict__ ov, __bf16* __restrict__ oo,
    __bf16* __restrict__ o1, __bf16* __restrict__ o2)
{
    const int id = blockIdx.x, t = threadIdx.x;
    if (id < 1536) {
        const int z = id >> 8, r = id & 255;
        const int sel = z >> 1, i = z & 1;
        const float* src = sel == 0 ? Wk : (sel == 1 ? Wv : Wo);
        __bf16* dst = sel == 0 ? ok : (sel == 1 ? ov : oo);
        ttile(src + (long)i * 262144, dst + (long)i * 262144, 512, 512,
              r & 15, r >> 4, t);
    } else if (id < 3584) {
        int r = id - 1536; const int i = r >> 10; r &= 1023;
        ttile(W1 + (long)i * 1048576, o1 + (long)i * 1048576, 512, 2048,
              r & 63, r >> 6, t);
    } else {
        int r = id - 3584; const int i = r >> 10; r &= 1023;
        ttile(W2 + (long)i * 1048576, o2 + (long)i * 1048576, 2048, 512,
              r & 15, r >> 4, t);
    }
}

// ---- GEMM v5 (unchanged proven R8 form): 128x128, BK=64, T2 swizzle, T1 XCD
// swizzle, 2-deep counted-vmcnt pipeline.
// MODE 0: bf16 out (+RELU). MODE 1: bf16 out = acc + bias + res(bf16).
template <int RELU, int MODE>
__global__ __launch_bounds__(256) void gemm_kernel(
    const __bf16* __restrict__ A, const __bf16* __restrict__ Bt,
    const float* __restrict__ bias, const __bf16* __restrict__ res,
    __bf16* __restrict__ out, int M, int N, int K)
{
    __shared__ __bf16 As[2][128 * 64];
    __shared__ __bf16 Bs[2][128 * 64];
    const int t = threadIdx.x;
    const int lane = t & 63;
    const int wv = t >> 6, wr = wv >> 1, wc = wv & 1;
    const int lr = lane & 15, lk = lane >> 4;

    const int nwg = gridDim.x * gridDim.y;
    const int lin = blockIdx.y * gridDim.x + blockIdx.x;
    const int swz = (lin & 7) * (nwg >> 3) + (lin >> 3);
    const int m0 = (swz / gridDim.x) * 128, n0 = (swz % gridDim.x) * 128;

    const int srow = t >> 3;
    const int sslot = (t & 7) ^ (srow & 7);
    const __bf16* gA = A + (long)(m0 + srow) * K + sslot * 8;
    const __bf16* gB = Bt + (long)(n0 + srow) * K + sslot * 8;
    const long rstep = (long)32 * K;

    auto STAGE = [&](int bsel, int k0) {
        char* ldsA = (char*)As[bsel] + t * 16;
        char* ldsB = (char*)Bs[bsel] + t * 16;
        #pragma unroll
        for (int u = 0; u < 4; ++u) {
            gld_lds16(gA + u * rstep + k0, ldsA + u * 4096);
            gld_lds16(gB + u * rstep + k0, ldsB + u * 4096);
        }
    };

    f32x4 acc[4][4] = {};
    auto COMPUTE = [&](int bsel) {
        #pragma unroll
        for (int kk = 0; kk < 2; ++kk) {
            bf16x8 af[4], bfr[4];
            #pragma unroll
            for (int i = 0; i < 4; ++i) {
                const int rr = wr * 64 + i * 16 + lr;
                af[i] = *(const bf16x8*)((const char*)As[bsel] +
                        (rr << 7) + (((kk * 4 + lk) ^ (rr & 7)) << 4));
            }
            #pragma unroll
            for (int j = 0; j < 4; ++j) {
                const int rr = wc * 64 + j * 16 + lr;
                bfr[j] = *(const bf16x8*)((const char*)Bs[bsel] +
                         (rr << 7) + (((kk * 4 + lk) ^ (rr & 7)) << 4));
            }
            #pragma unroll
            for (int i = 0; i < 4; ++i)
                #pragma unroll
                for (int j = 0; j < 4; ++j)
                    acc[i][j] = __builtin_amdgcn_mfma_f32_16x16x32_bf16(
                        af[i], bfr[j], acc[i][j], 0, 0, 0);
        }
    };

    const int NT = K >> 6;
    STAGE(0, 0);
    STAGE(1, 64);
    for (int kt = 0; kt < NT - 1; ++kt) {
        asm volatile("s_waitcnt vmcnt(8)" ::: "memory");
        __builtin_amdgcn_s_barrier();
        COMPUTE(kt & 1);
        __builtin_amdgcn_s_barrier();
        if (kt + 2 < NT) STAGE(kt & 1, (kt + 2) << 6);
    }
    asm volatile("s_waitcnt vmcnt(0)" ::: "memory");
    __builtin_amdgcn_s_barrier();
    COMPUTE((NT - 1) & 1);

    #pragma unroll
    for (int i = 0; i < 4; ++i) {
        #pragma unroll
        for (int j = 0; j < 4; ++j) {
            const int n = n0 + wc * 64 + j * 16 + lr;
            const float bv = bias[n];
            #pragma unroll
            for (int r = 0; r < 4; ++r) {
                const int m = m0 + wr * 64 + i * 16 + lk * 4 + r;
                const long off = (long)m * N + n;
                float v = acc[i][j][r] + bv;
                if (MODE == 1) v += (float)res[off];
                if (RELU) v = v > 0.f ? v : 0.f;
                out[off] = (__bf16)v;
            }
        }
    }
}

// ---- merged K+V projection: z=0 -> K = xbf@WkT+bk (standard layout),
//      z=1 -> Vt = transpose-fused (ybf@WvT+bv) into [B,H,DK,S].
// K-loop identical to gemm_kernel. M=16384, N=512, K=512 hardcoded.
__global__ __launch_bounds__(256) void gemm_kv(
    const __bf16* __restrict__ xbf, const __bf16* __restrict__ ybf,
    const __bf16* __restrict__ wkt, const __bf16* __restrict__ wvt,
    const float* __restrict__ bk, const float* __restrict__ bv,
    __bf16* __restrict__ kout, __bf16* __restrict__ vtout)
{
    constexpr int N = 512, K = 512;
    __shared__ __bf16 As[2][128 * 64];
    __shared__ __bf16 Bs[2][128 * 64];
    const int t = threadIdx.x;
    const int lane = t & 63;
    const int wv = t >> 6, wr = wv >> 1, wc = wv & 1;
    const int lr = lane & 15, lk = lane >> 4;
    const int zv = blockIdx.z;

    const __bf16* A  = zv ? ybf : xbf;
    const __bf16* Bt = zv ? wvt : wkt;
    const float* bias = zv ? bv : bk;
    __bf16* out = zv ? vtout : kout;

    const int nwg = gridDim.x * gridDim.y;
    const int lin = blockIdx.y * gridDim.x + blockIdx.x;
    const int swz = (lin & 7) * (nwg >> 3) + (lin >> 3);
    const int m0 = (swz / gridDim.x) * 128, n0 = (swz % gridDim.x) * 128;

    const int srow = t >> 3;
    const int sslot = (t & 7) ^ (srow & 7);
    const __bf16* gA = A + (long)(m0 + srow) * K + sslot * 8;
    const __bf16* gB = Bt + (long)(n0 + srow) * K + sslot * 8;
    const long rstep = (long)32 * K;

    auto STAGE = [&](int bsel, int k0) {
        char* ldsA = (char*)As[bsel] + t * 16;
        char* ldsB = (char*)Bs[bsel] + t * 16;
        #pragma unroll
        for (int u = 0; u < 4; ++u) {
            gld_lds16(gA + u * rstep + k0, ldsA + u * 4096);
            gld_lds16(gB + u * rstep + k0, ldsB + u * 4096);
        }
    };

    f32x4 acc[4][4] = {};
    auto COMPUTE = [&](int bsel) {
        #pragma unroll
        for (int kk = 0; kk < 2; ++kk) {
            bf16x8 af[4], bfr[4];
            #pragma unroll
            for (int i = 0; i < 4; ++i) {
                const int rr = wr * 64 + i * 16 + lr;
                af[i] = *(const bf16x8*)((const char*)As[bsel] +
                        (rr << 7) + (((kk * 4 + lk) ^ (rr & 7)) << 4));
            }
            #pragma unroll
            for (int j = 0; j < 4; ++j) {
                const int rr = wc * 64 + j * 16 + lr;
                bfr[j] = *(const bf16x8*)((const char*)Bs[bsel] +
                         (rr << 7) + (((kk * 4 + lk) ^ (rr & 7)) << 4));
            }
            #pragma unroll
            for (int i = 0; i < 4; ++i)
                #pragma unroll
                for (int j = 0; j < 4; ++j)
                    acc[i][j] = __builtin_amdgcn_mfma_f32_16x16x32_bf16(
                        af[i], bfr[j], acc[i][j], 0, 0, 0);
        }
    };

    const int NT = K >> 6;
    STAGE(0, 0);
    STAGE(1, 64);
    for (int kt = 0; kt < NT - 1; ++kt) {
        asm volatile("s_waitcnt vmcnt(8)" ::: "memory");
        __builtin_amdgcn_s_barrier();
        COMPUTE(kt & 1);
        __builtin_amdgcn_s_barrier();
        if (kt + 2 < NT) STAGE(kt & 1, (kt + 2) << 6);
    }
    asm volatile("s_waitcnt vmcnt(0)" ::: "memory");
    __builtin_amdgcn_s_barrier();
    COMPUTE((NT - 1) & 1);

    #pragma unroll
    for (int i = 0; i < 4; ++i) {
        #pragma unroll
        for (int j = 0; j < 4; ++j) {
            const int n = n0 + wc * 64 + j * 16 + lr;
            const float bvl = bias[n];
            if (zv) {
                const int mb = m0 + wr * 64 + i * 16 + lk * 4;
                const int b = mb >> 9, s = mb & 511;
                bf16x4 ov = {(__bf16)(acc[i][j][0] + bvl),
                             (__bf16)(acc[i][j][1] + bvl),
                             (__bf16)(acc[i][j][2] + bvl),
                             (__bf16)(acc[i][j][3] + bvl)};
                *(bf16x4*)(out + (((long)(b * 8 + (n >> 6)) * 64 + (n & 63)) << 9) + s) = ov;
            } else {
                #pragma unroll
                for (int r = 0; r < 4; ++r) {
                    const int m = m0 + wr * 64 + i * 16 + lk * 4 + r;
                    out[(long)m * N + n] = (__bf16)(acc[i][j][r] + bvl);
                }
            }
        }
    }
}

// ---- attention v5: v4 + 2-deep double-buffered K/V staging with counted vmcnt
// (same pipeline skeleton as the proven GEMM). Plds stays wave-private. ----
__global__ __launch_bounds__(256) void attn_kernel(
    const __bf16* __restrict__ Q, const __bf16* __restrict__ Vt,
    const float* __restrict__ fr, __bf16* __restrict__ Out)
{
    __shared__ __bf16 Ks[2][64 * 64];
    __shared__ __bf16 Vs[2][64 * 64];
    __shared__ __bf16 Plds[4][16 * 64];
    const int t = threadIdx.x;
    const int lane = t & 63, wv = t >> 6;
    const int lr = lane & 15, lk = lane >> 4;
    const int qb = blockIdx.x, h = blockIdx.y, b = blockIdx.z;
    const int qT = qb * 64 + wv * 16;

    const __bf16* qp = Q + (long)(b * S_ + qT + lr) * D_ + h * DK_ + lk * 8;
    const bf16x8 qf0 = *(const bf16x8*)qp;
    const bf16x8 qf1 = *(const bf16x8*)(qp + 32);

    float frv[4], ls[4];
    #pragma unroll
    for (int r = 0; r < 4; ++r) {
        frv[r] = fr[b * S_ + qT + lk * 4 + r] * 0.125f;
        ls[r] = 0.f;
    }
    f32x4 o[4] = {};

    const int srow = t >> 3;
    const int sslot = (t & 7) ^ (srow & 7);
    const __bf16* kstage = Q + (long)(b * S_ + srow) * D_ + h * DK_ + sslot * 8;
    const __bf16* vstage = Vt + ((long)(b * H_ + h) * DK_ + srow) * S_ + sslot * 8;
    __bf16* pl = &Plds[wv][0];
    const int sw = (lr & 7);

    auto STAGE = [&](int bsel, int ks) {
        gld_lds16(kstage + (long)ks * D_, (char*)Ks[bsel] + t * 16);
        gld_lds16(kstage + (long)(ks + 32) * D_, (char*)Ks[bsel] + 4096 + t * 16);
        gld_lds16(vstage + ks, (char*)Vs[bsel] + t * 16);
        gld_lds16(vstage + ks + 32 * S_, (char*)Vs[bsel] + 4096 + t * 16);
    };

    auto COMPUTE = [&](int bsel, int ks) {
        f32x4 sc[4] = {};
        #pragma unroll
        for (int j = 0; j < 4; ++j) {
            const char* kb = (const char*)Ks[bsel] + ((j * 16 + lr) << 7);
            const bf16x8 kf0 = *(const bf16x8*)(kb + ((lk ^ sw) << 4));
            const bf16x8 kf1 = *(const bf16x8*)(kb + (((lk + 4) ^ sw) << 4));
            sc[j] = __builtin_amdgcn_mfma_f32_16x16x32_bf16(qf0, kf0, sc[j], 0, 0, 0);
            sc[j] = __builtin_amdgcn_mfma_f32_16x16x32_bf16(qf1, kf1, sc[j], 0, 0, 0);
        }
        #pragma unroll
        for (int j = 0; j < 4; ++j) {
            const int col = ks + j * 16 + lr;
            const int c8 = j * 2 + (lr >> 3), cb = lr & 7;
            #pragma unroll
            for (int r = 0; r < 4; ++r) {
                const int row = lk * 4 + r;
                const int sidx = row * 64 + ((c8 ^ (row & 7)) << 3) + cb;
                const float e = __expf(sc[j][r] * frv[r]);
                const float p = (col < qT + row) ? e : 0.f;
                ls[r] += p;
                pl[sidx] = (__bf16)p;
            }
        }
        bf16x8 pf[2];
        #pragma unroll
        for (int kk = 0; kk < 2; ++kk) {
            const int ridx = lr * 64 + (((kk * 4 + lk) ^ sw) << 3);
            pf[kk] = *(const bf16x8*)&pl[ridx];
        }
        #pragma unroll
        for (int dt = 0; dt < 4; ++dt) {
            const char* vb = (const char*)Vs[bsel] + ((dt * 16 + lr) << 7);
            #pragma unroll
            for (int kk = 0; kk < 2; ++kk) {
                const bf16x8 vf = *(const bf16x8*)(vb + (((kk * 4 + lk) ^ sw) << 4));
                o[dt] = __builtin_amdgcn_mfma_f32_16x16x32_bf16(pf[kk], vf, o[dt], 0, 0, 0);
            }
        }
    };

    const int nt = qb + 1;
    STAGE(0, 0);
    if (nt > 1) STAGE(1, 64);
    for (int tt = 0; tt < nt - 1; ++tt) {
        asm volatile("s_waitcnt vmcnt(4)" ::: "memory");
        __builtin_amdgcn_s_barrier();
        COMPUTE(tt & 1, tt * 64);
        __builtin_amdgcn_s_barrier();
        if (tt + 2 < nt) STAGE(tt & 1, (tt + 2) * 64);
    }
    asm volatile("s_waitcnt vmcnt(0)" ::: "memory");
    __builtin_amdgcn_s_barrier();
    COMPUTE((nt - 1) & 1, (nt - 1) * 64);

    #pragma unroll
    for (int r = 0; r < 4; ++r) {
        #pragma unroll
        for (int d = 1; d < 16; d <<= 1)
            ls[r] += __shfl_xor(ls[r], d);
        const float inv = ls[r] > 0.f ? 1.f / ls[r] : 0.f;  // row 0 -> zeros
        #pragma unroll
        for (int dt = 0; dt < 4; ++dt)
            Out[(long)(b * S_ + qT + lk * 4 + r) * D_ + h * DK_ + dt * 16 + lr] =
                (__bf16)(o[dt][r] * inv);
    }
}

// ---- LayerNorm: bf16 in, bf16 out (+fp32 out only when wf32 != 0) ----
__global__ __launch_bounds__(256) void ln_kernel(
    const __bf16* __restrict__ pre, const float* __restrict__ g,
    const float* __restrict__ be, float* __restrict__ xout,
    __bf16* __restrict__ xbf, int wf32)
{
    const int lane = threadIdx.x & 63, wv = threadIdx.x >> 6;
    const long row = (long)blockIdx.x * 4 + wv;
    const bf16x8 v = *(const bf16x8*)(pre + row * D_ + lane * 8);
    float f[8];
    #pragma unroll
    for (int k = 0; k < 8; ++k) f[k] = (float)v[k];
    float s = 0.f, ss = 0.f;
    #pragma unroll
    for (int k = 0; k < 8; ++k) { s += f[k]; ss += f[k] * f[k]; }
    #pragma unroll
    for (int d = 1; d < 64; d <<= 1) {
        s  += __shfl_xor(s, d);
        ss += __shfl_xor(ss, d);
    }
    const float mean = s * (1.f / 512.f);
    const float rstd = rsqrtf(ss * (1.f / 512.f) - mean * mean + 1e-5f);
    const float4 ga = ((const float4*)(g + lane * 8))[0];
    const float4 gc = ((const float4*)(g + lane * 8))[1];
    const float4 ba = ((const float4*)(be + lane * 8))[0];
    const float4 bc = ((const float4*)(be + lane * 8))[1];
    float o[8];
    o[0] = (f[0] - mean) * rstd * ga.x + ba.x;
    o[1] = (f[1] - mean) * rstd * ga.y + ba.y;
    o[2] = (f[2] - mean) * rstd * ga.z + ba.z;
    o[3] = (f[3] - mean) * rstd * ga.w + ba.w;
    o[4] = (f[4] - mean) * rstd * gc.x + bc.x;
    o[5] = (f[5] - mean) * rstd * gc.y + bc.y;
    o[6] = (f[6] - mean) * rstd * gc.z + bc.z;
    o[7] = (f[7] - mean) * rstd * gc.w + bc.w;
    bf16x8 xb = {(__bf16)o[0], (__bf16)o[1], (__bf16)o[2], (__bf16)o[3],
                 (__bf16)o[4], (__bf16)o[5], (__bf16)o[6], (__bf16)o[7]};
    *(bf16x8*)(xbf + row * D_ + lane * 8) = xb;
    if (wf32) {
        float* xo = xout + row * D_ + lane * 8;
        ((float4*)xo)[0] = make_float4(o[0], o[1], o[2], o[3]);
        ((float4*)xo)[1] = make_float4(o[4], o[5], o[6], o[7]);
    }
}

extern "C" void kernel_launch(void* const* d_in, const int* in_sizes, int n_in,
                              void* d_out, int out_size, void* d_ws, size_t ws_size,
                              hipStream_t stream) {
    const float* q_embed = (const float*)d_in[0];
    const float* qa_embed = (const float*)d_in[1];
    const float* fr  = (const float*)d_in[2];
    const float* pe  = (const float*)d_in[3];
    const float* Wk  = (const float*)d_in[4];
    const float* bk  = (const float*)d_in[5];
    const float* Wv  = (const float*)d_in[6];
    const float* bv  = (const float*)d_in[7];
    const float* Wo  = (const float*)d_in[8];
    const float* bo  = (const float*)d_in[9];
    const float* g1  = (const float*)d_in[10];
    const float* be1 = (const float*)d_in[11];
    const float* W1  = (const float*)d_in[12];
    const float* bf1 = (const float*)d_in[13];
    const float* W2  = (const float*)d_in[14];
    const float* bf2 = (const float*)d_in[15];
    const float* g2  = (const float*)d_in[16];
    const float* be2 = (const float*)d_in[17];

    // workspace layout (~128 MB)
    char* ws = (char*)d_ws;
    __bf16* xbf   = (__bf16*)(ws + 0);           // 16 MB bf16 residual master
    __bf16* ybf   = (__bf16*)(ws + 16777216);    // 16 MB
    __bf16* pool  = (__bf16*)(ws + 33554432);    // 64 MB: k/vt/attn OR f1
    __bf16* preln = (__bf16*)(ws + 100663296);   // 16 MB
    __bf16* wts   = (__bf16*)(ws + 117440512);   // 11 MB bf16 transposed weights

    __bf16* kbuf  = pool;
    __bf16* vtbuf = pool + 8388608;
    __bf16* abuf  = pool + 2 * 8388608;
    __bf16* f1buf = pool;  // 64 MB, aliases k/vt/attn (all dead by FFN1)

    __bf16* wkt = wts;
    __bf16* wvt = wts + 524288;
    __bf16* wot = wts + 1048576;
    __bf16* w1t = wts + 1572864;
    __bf16* w2t = wts + 3670016;

    transpose_all<<<5632, 256, 0, stream>>>(Wk, Wv, Wo, W1, W2,
                                            wkt, wvt, wot, w1t, w2t);
    prep_kernel<<<2048, 256, 0, stream>>>(q_embed, qa_embed, pe, xbf, ybf);

    for (int i = 0; i < 2; ++i) {
        gemm_kv<<<dim3(4, 128, 2), 256, 0, stream>>>(
            xbf, ybf, wkt + i * 262144, wvt + i * 262144,
            bk + i * 512, bv + i * 512, kbuf, vtbuf);
        attn_kernel<<<dim3(8, 8, 32), 256, 0, stream>>>(kbuf, vtbuf, fr, abuf);
        gemm_kernel<0, 1><<<dim3(4, 128), 256, 0, stream>>>(
            abuf, wot + i * 262144, bo + i * 512, xbf, preln, 16384, 512, 512);
        ln_kernel<<<4096, 256, 0, stream>>>(preln, g1 + i * 512, be1 + i * 512,
                                            (float*)d_out, xbf, 0);
        gemm_kernel<1, 0><<<dim3(16, 128), 256, 0, stream>>>(
            xbf, w1t + i * 1048576, bf1 + i * 2048, nullptr, f1buf, 16384, 2048, 512);
        gemm_kernel<0, 1><<<dim3(4, 128), 256, 0, stream>>>(
            f1buf, w2t + i * 1048576, bf2 + i * 512, xbf, preln, 16384, 512, 2048);
        ln_kernel<<<4096, 256, 0, stream>>>(preln, g2 + i * 512, be2 + i * 512,
                                            (float*)d_out, xbf, i == 1 ? 1 : 0);
    }
}

// Round 10
// 434.868 us; speedup vs baseline: 1.6645x; 1.0073x over previous
//
#include <hip/hip_runtime.h>

#define B_ 32
#define S_ 512
#define D_ 512
#define H_ 8
#define DK_ 64
#define FF_ 2048

typedef float f32x4 __attribute__((ext_vector_type(4)));
typedef __bf16 bf16x8 __attribute__((ext_vector_type(8)));
typedef __bf16 bf16x4 __attribute__((ext_vector_type(4)));

// ---- async global->LDS, 16B per lane (dest must be wave-uniform base + lane*16) ----
__device__ __forceinline__ void gld_lds16(const void* gptr, void* lptr) {
    auto g = (__attribute__((address_space(1))) void*)(unsigned long long)gptr;
    auto l = (__attribute__((address_space(3))) void*)(unsigned)(unsigned long long)lptr;
    __builtin_amdgcn_global_load_lds(g, l, 16, 0, 0);
}

// ---- x = q+pe (bf16), y = qa+pe (bf16); bf16 master stream ----
__global__ __launch_bounds__(256) void prep_kernel(
    const float* __restrict__ q, const float* __restrict__ qa,
    const float* __restrict__ pe, __bf16* __restrict__ xbf,
    __bf16* __restrict__ ybf)
{
    const int n4 = B_ * S_ * D_ / 4;
    for (int i = blockIdx.x * blockDim.x + threadIdx.x; i < n4;
         i += gridDim.x * blockDim.x) {
        float4 pv = ((const float4*)pe)[i & (S_ * D_ / 4 - 1)];
        float4 qv = ((const float4*)q)[i];
        float4 av = ((const float4*)qa)[i];
        bf16x4 xb = {(__bf16)(qv.x + pv.x), (__bf16)(qv.y + pv.y),
                     (__bf16)(qv.z + pv.z), (__bf16)(qv.w + pv.w)};
        ((bf16x4*)xbf)[i] = xb;
        bf16x4 yb = {(__bf16)(av.x + pv.x), (__bf16)(av.y + pv.y),
                     (__bf16)(av.z + pv.z), (__bf16)(av.w + pv.w)};
        ((bf16x4*)ybf)[i] = yb;
    }
}

// ---- shared 32x32 transpose tile body: fp32 [R][C] -> bf16 [C][R] ----
__device__ __forceinline__ void ttile(
    const float* __restrict__ in, __bf16* __restrict__ out,
    int R, int C, int bx, int by, int t)
{
    __shared__ float tile[32][33];
    const int tc = bx * 32, tr = by * 32;
    const int lx = t & 31, ly = t >> 5;
    #pragma unroll
    for (int yy = ly; yy < 32; yy += 8)
        tile[yy][lx] = in[(long)(tr + yy) * C + tc + lx];
    __syncthreads();
    #pragma unroll
    for (int yy = ly; yy < 32; yy += 8)
        out[(long)(tc + yy) * R + tr + lx] = (__bf16)tile[lx][yy];
}

// ---- all weight transposes in one flat-grid dispatch ----
__global__ __launch_bounds__(256) void transpose_all(
    const float* __restrict__ Wk, const float* __restrict__ Wv,
    const float* __restrict__ Wo, const float* __restrict__ W1,
    const float* __restrict__ W2, __bf16* __restrict__ ok,
    __bf16* __restrict__ ov, __bf16* __restrict__ oo,
    __bf16* __restrict__ o1, __bf16* __restrict__ o2)
{
    const int id = blockIdx.x, t = threadIdx.x;
    if (id < 1536) {
        const int z = id >> 8, r = id & 255;
        const int sel = z >> 1, i = z & 1;
        const float* src = sel == 0 ? Wk : (sel == 1 ? Wv : Wo);
        __bf16* dst = sel == 0 ? ok : (sel == 1 ? ov : oo);
        ttile(src + (long)i * 262144, dst + (long)i * 262144, 512, 512,
              r & 15, r >> 4, t);
    } else if (id < 3584) {
        int r = id - 1536; const int i = r >> 10; r &= 1023;
        ttile(W1 + (long)i * 1048576, o1 + (long)i * 1048576, 512, 2048,
              r & 63, r >> 6, t);
    } else {
        int r = id - 3584; const int i = r >> 10; r &= 1023;
        ttile(W2 + (long)i * 1048576, o2 + (long)i * 1048576, 2048, 512,
              r & 15, r >> 4, t);
    }
}

// ---- GEMM v5 (proven): 128x128, BK=64, T2 swizzle, T1 XCD swizzle,
// 2-deep counted-vmcnt pipeline. MODE 0: bf16 out (+RELU). MODE 1: +res. ----
template <int RELU, int MODE>
__global__ __launch_bounds__(256) void gemm_kernel(
    const __bf16* __restrict__ A, const __bf16* __restrict__ Bt,
    const float* __restrict__ bias, const __bf16* __restrict__ res,
    __bf16* __restrict__ out, int M, int N, int K)
{
    __shared__ __bf16 As[2][128 * 64];
    __shared__ __bf16 Bs[2][128 * 64];
    const int t = threadIdx.x;
    const int lane = t & 63;
    const int wv = t >> 6, wr = wv >> 1, wc = wv & 1;
    const int lr = lane & 15, lk = lane >> 4;

    const int nwg = gridDim.x * gridDim.y;
    const int lin = blockIdx.y * gridDim.x + blockIdx.x;
    const int swz = (lin & 7) * (nwg >> 3) + (lin >> 3);
    const int m0 = (swz / gridDim.x) * 128, n0 = (swz % gridDim.x) * 128;

    const int srow = t >> 3;
    const int sslot = (t & 7) ^ (srow & 7);
    const __bf16* gA = A + (long)(m0 + srow) * K + sslot * 8;
    const __bf16* gB = Bt + (long)(n0 + srow) * K + sslot * 8;
    const long rstep = (long)32 * K;

    auto STAGE = [&](int bsel, int k0) {
        char* ldsA = (char*)As[bsel] + t * 16;
        char* ldsB = (char*)Bs[bsel] + t * 16;
        #pragma unroll
        for (int u = 0; u < 4; ++u) {
            gld_lds16(gA + u * rstep + k0, ldsA + u * 4096);
            gld_lds16(gB + u * rstep + k0, ldsB + u * 4096);
        }
    };

    f32x4 acc[4][4] = {};
    auto COMPUTE = [&](int bsel) {
        #pragma unroll
        for (int kk = 0; kk < 2; ++kk) {
            bf16x8 af[4], bfr[4];
            #pragma unroll
            for (int i = 0; i < 4; ++i) {
                const int rr = wr * 64 + i * 16 + lr;
                af[i] = *(const bf16x8*)((const char*)As[bsel] +
                        (rr << 7) + (((kk * 4 + lk) ^ (rr & 7)) << 4));
            }
            #pragma unroll
            for (int j = 0; j < 4; ++j) {
                const int rr = wc * 64 + j * 16 + lr;
                bfr[j] = *(const bf16x8*)((const char*)Bs[bsel] +
                         (rr << 7) + (((kk * 4 + lk) ^ (rr & 7)) << 4));
            }
            #pragma unroll
            for (int i = 0; i < 4; ++i)
                #pragma unroll
                for (int j = 0; j < 4; ++j)
                    acc[i][j] = __builtin_amdgcn_mfma_f32_16x16x32_bf16(
                        af[i], bfr[j], acc[i][j], 0, 0, 0);
        }
    };

    const int NT = K >> 6;
    STAGE(0, 0);
    STAGE(1, 64);
    for (int kt = 0; kt < NT - 1; ++kt) {
        asm volatile("s_waitcnt vmcnt(8)" ::: "memory");
        __builtin_amdgcn_s_barrier();
        COMPUTE(kt & 1);
        __builtin_amdgcn_s_barrier();
        if (kt + 2 < NT) STAGE(kt & 1, (kt + 2) << 6);
    }
    asm volatile("s_waitcnt vmcnt(0)" ::: "memory");
    __builtin_amdgcn_s_barrier();
    COMPUTE((NT - 1) & 1);

    #pragma unroll
    for (int i = 0; i < 4; ++i) {
        #pragma unroll
        for (int j = 0; j < 4; ++j) {
            const int n = n0 + wc * 64 + j * 16 + lr;
            const float bv = bias[n];
            #pragma unroll
            for (int r = 0; r < 4; ++r) {
                const int m = m0 + wr * 64 + i * 16 + lk * 4 + r;
                const long off = (long)m * N + n;
                float v = acc[i][j][r] + bv;
                if (MODE == 1) v += (float)res[off];
                if (RELU) v = v > 0.f ? v : 0.f;
                out[off] = (__bf16)v;
            }
        }
    }
}

// ---- GEMM8: 256x256 tile, 8 waves, BK=64, 8-phase interleave (T3+T4+T5).
// Subtiled LDS [buf][A|B][sr*2+kk] of 1KB linear subtiles; wave-granular staging
// (one wave stages one subtile per issue). Phase = (kk, mh) quadrant, 16 MFMA.
// Stagger: tile T's k0 staged at (T-2).ph2/3, k1 at (T-1).ph0/1 (race-audited).
// vmcnt(8) twice per K-tile in steady state; peeled last tile 4/0.
template <int RELU, int MODE>
__global__ __launch_bounds__(512, 2) void gemm8_kernel(
    const __bf16* __restrict__ A, const __bf16* __restrict__ Bt,
    const float* __restrict__ bias, const __bf16* __restrict__ res,
    __bf16* __restrict__ out, int M, int N, int K)
{
    __shared__ __bf16 lds[65536];  // 128 KB
    const int t = threadIdx.x;
    const int lane = t & 63, wv = t >> 6;
    const int wr = wv >> 2, wc = wv & 3;
    const int lr = lane & 15, lk = lane >> 4;

    const int nwg = gridDim.x * gridDim.y;
    const int lin = blockIdx.y * gridDim.x + blockIdx.x;
    const int swz = (lin & 7) * (nwg >> 3) + (lin >> 3);
    const int m0 = (swz / gridDim.x) * 256, n0 = (swz % gridDim.x) * 256;

    const int srcrow = lane >> 2, srccol = (lane & 3) * 8;
    // stage one K-half region (16 subtiles) of A (isB=0) or B (isB=1), tile kt2, buffer pb
    auto STG = [&](int isB, int kt2, int kk2, int pb) {
        const __bf16* src = isB ? Bt : A;
        const int base = isB ? n0 : m0;
        #pragma unroll
        for (int u = 0; u < 2; ++u) {
            const int sr = u * 8 + wv;
            const long g = (long)(base + sr * 16 + srcrow) * K + kt2 * 64 + kk2 * 32 + srccol;
            char* d = (char*)lds + pb * 65536 + isB * 32768 + ((sr * 2 + kk2) << 10) + lane * 16;
            gld_lds16(src + g, d);
        }
    };

    f32x4 acc[8][4] = {};
    bf16x8 af[4], bfr[4];
    auto RDA = [&](int p, int kk, int mh) {
        #pragma unroll
        for (int i = 0; i < 4; ++i) {
            const int sr = wr * 8 + mh * 4 + i;
            af[i] = *(const bf16x8*)((const char*)lds + p * 65536 +
                    ((sr * 2 + kk) << 10) + lr * 64 + lk * 16);
        }
    };
    auto RDB = [&](int p, int kk) {
        #pragma unroll
        for (int j = 0; j < 4; ++j) {
            const int sr = wc * 4 + j;
            bfr[j] = *(const bf16x8*)((const char*)lds + p * 65536 + 32768 +
                     ((sr * 2 + kk) << 10) + lr * 64 + lk * 16);
        }
    };
    auto MM = [&](int mh) {
        __builtin_amdgcn_s_setprio(1);
        #pragma unroll
        for (int i = 0; i < 4; ++i)
            #pragma unroll
            for (int j = 0; j < 4; ++j)
                acc[mh * 4 + i][j] = __builtin_amdgcn_mfma_f32_16x16x32_bf16(
                    af[i], bfr[j], acc[mh * 4 + i][j], 0, 0, 0);
        __builtin_amdgcn_s_setprio(0);
    };

    const int NT = K >> 6;
    // prologue: t0 Ak0,Bk0,Ak1,Bk1; t1 Ak0,Bk0  (6 regions = 12 loads/thread)
    STG(0, 0, 0, 0); STG(1, 0, 0, 0); STG(0, 0, 1, 0); STG(1, 0, 1, 0);
    STG(0, 1, 0, 1); STG(1, 1, 0, 1);

    for (int kt = 0; kt < NT - 1; ++kt) {
        const int p = kt & 1;
        asm volatile("s_waitcnt vmcnt(8)" ::: "memory");   // tile kt k0 landed
        __builtin_amdgcn_s_barrier();
        RDA(p, 0, 0); RDB(p, 0); STG(0, kt + 1, 1, p ^ 1);
        MM(0);
        __builtin_amdgcn_s_barrier();
        RDA(p, 0, 1); STG(1, kt + 1, 1, p ^ 1);
        MM(1);
        asm volatile("s_waitcnt vmcnt(8)" ::: "memory");   // tile kt k1 landed
        __builtin_amdgcn_s_barrier();
        RDA(p, 1, 0); RDB(p, 1); if (kt + 2 < NT) STG(0, kt + 2, 0, p);
        MM(0);
        __builtin_amdgcn_s_barrier();
        RDA(p, 1, 1); if (kt + 2 < NT) STG(1, kt + 2, 0, p);
        MM(1);
    }
    {   // peeled last tile: no stages; drain exactly
        const int p = (NT - 1) & 1;
        asm volatile("s_waitcnt vmcnt(4)" ::: "memory");
        __builtin_amdgcn_s_barrier();
        RDA(p, 0, 0); RDB(p, 0); MM(0);
        __builtin_amdgcn_s_barrier();
        RDA(p, 0, 1); MM(1);
        asm volatile("s_waitcnt vmcnt(0)" ::: "memory");
        __builtin_amdgcn_s_barrier();
        RDA(p, 1, 0); RDB(p, 1); MM(0);
        __builtin_amdgcn_s_barrier();
        RDA(p, 1, 1); MM(1);
    }

    #pragma unroll
    for (int i = 0; i < 8; ++i) {
        #pragma unroll
        for (int j = 0; j < 4; ++j) {
            const int n = n0 + wc * 64 + j * 16 + lr;
            const float bv = bias[n];
            #pragma unroll
            for (int r = 0; r < 4; ++r) {
                const int m = m0 + wr * 128 + i * 16 + lk * 4 + r;
                const long off = (long)m * N + n;
                float v = acc[i][j][r] + bv;
                if (MODE == 1) v += (float)res[off];
                if (RELU) v = v > 0.f ? v : 0.f;
                out[off] = (__bf16)v;
            }
        }
    }
}

// ---- merged K+V projection (proven v5 pipeline) ----
__global__ __launch_bounds__(256) void gemm_kv(
    const __bf16* __restrict__ xbf, const __bf16* __restrict__ ybf,
    const __bf16* __restrict__ wkt, const __bf16* __restrict__ wvt,
    const float* __restrict__ bk, const float* __restrict__ bv,
    __bf16* __restrict__ kout, __bf16* __restrict__ vtout)
{
    constexpr int N = 512, K = 512;
    __shared__ __bf16 As[2][128 * 64];
    __shared__ __bf16 Bs[2][128 * 64];
    const int t = threadIdx.x;
    const int lane = t & 63;
    const int wv = t >> 6, wr = wv >> 1, wc = wv & 1;
    const int lr = lane & 15, lk = lane >> 4;
    const int zv = blockIdx.z;

    const __bf16* A  = zv ? ybf : xbf;
    const __bf16* Bt = zv ? wvt : wkt;
    const float* bias = zv ? bv : bk;
    __bf16* out = zv ? vtout : kout;

    const int nwg = gridDim.x * gridDim.y;
    const int lin = blockIdx.y * gridDim.x + blockIdx.x;
    const int swz = (lin & 7) * (nwg >> 3) + (lin >> 3);
    const int m0 = (swz / gridDim.x) * 128, n0 = (swz % gridDim.x) * 128;

    const int srow = t >> 3;
    const int sslot = (t & 7) ^ (srow & 7);
    const __bf16* gA = A + (long)(m0 + srow) * K + sslot * 8;
    const __bf16* gB = Bt + (long)(n0 + srow) * K + sslot * 8;
    const long rstep = (long)32 * K;

    auto STAGE = [&](int bsel, int k0) {
        char* ldsA = (char*)As[bsel] + t * 16;
        char* ldsB = (char*)Bs[bsel] + t * 16;
        #pragma unroll
        for (int u = 0; u < 4; ++u) {
            gld_lds16(gA + u * rstep + k0, ldsA + u * 4096);
            gld_lds16(gB + u * rstep + k0, ldsB + u * 4096);
        }
    };

    f32x4 acc[4][4] = {};
    auto COMPUTE = [&](int bsel) {
        #pragma unroll
        for (int kk = 0; kk < 2; ++kk) {
            bf16x8 af[4], bfr[4];
            #pragma unroll
            for (int i = 0; i < 4; ++i) {
                const int rr = wr * 64 + i * 16 + lr;
                af[i] = *(const bf16x8*)((const char*)As[bsel] +
                        (rr << 7) + (((kk * 4 + lk) ^ (rr & 7)) << 4));
            }
            #pragma unroll
            for (int j = 0; j < 4; ++j) {
                const int rr = wc * 64 + j * 16 + lr;
                bfr[j] = *(const bf16x8*)((const char*)Bs[bsel] +
                         (rr << 7) + (((kk * 4 + lk) ^ (rr & 7)) << 4));
            }
            #pragma unroll
            for (int i = 0; i < 4; ++i)
                #pragma unroll
                for (int j = 0; j < 4; ++j)
                    acc[i][j] = __builtin_amdgcn_mfma_f32_16x16x32_bf16(
                        af[i], bfr[j], acc[i][j], 0, 0, 0);
        }
    };

    const int NT = K >> 6;
    STAGE(0, 0);
    STAGE(1, 64);
    for (int kt = 0; kt < NT - 1; ++kt) {
        asm volatile("s_waitcnt vmcnt(8)" ::: "memory");
        __builtin_amdgcn_s_barrier();
        COMPUTE(kt & 1);
        __builtin_amdgcn_s_barrier();
        if (kt + 2 < NT) STAGE(kt & 1, (kt + 2) << 6);
    }
    asm volatile("s_waitcnt vmcnt(0)" ::: "memory");
    __builtin_amdgcn_s_barrier();
    COMPUTE((NT - 1) & 1);

    #pragma unroll
    for (int i = 0; i < 4; ++i) {
        #pragma unroll
        for (int j = 0; j < 4; ++j) {
            const int n = n0 + wc * 64 + j * 16 + lr;
            const float bvl = bias[n];
            if (zv) {
                const int mb = m0 + wr * 64 + i * 16 + lk * 4;
                const int b = mb >> 9, s = mb & 511;
                bf16x4 ov = {(__bf16)(acc[i][j][0] + bvl),
                             (__bf16)(acc[i][j][1] + bvl),
                             (__bf16)(acc[i][j][2] + bvl),
                             (__bf16)(acc[i][j][3] + bvl)};
                *(bf16x4*)(out + (((long)(b * 8 + (n >> 6)) * 64 + (n & 63)) << 9) + s) = ov;
            } else {
                #pragma unroll
                for (int r = 0; r < 4; ++r) {
                    const int m = m0 + wr * 64 + i * 16 + lk * 4 + r;
                    out[(long)m * N + n] = (__bf16)(acc[i][j][r] + bvl);
                }
            }
        }
    }
}

// ---- attention v5 (proven): 2-deep double-buffered K/V staging, counted vmcnt ----
__global__ __launch_bounds__(256) void attn_kernel(
    const __bf16* __restrict__ Q, const __bf16* __restrict__ Vt,
    const float* __restrict__ fr, __bf16* __restrict__ Out)
{
    __shared__ __bf16 Ks[2][64 * 64];
    __shared__ __bf16 Vs[2][64 * 64];
    __shared__ __bf16 Plds[4][16 * 64];
    const int t = threadIdx.x;
    const int lane = t & 63, wv = t >> 6;
    const int lr = lane & 15, lk = lane >> 4;
    const int qb = blockIdx.x, h = blockIdx.y, b = blockIdx.z;
    const int qT = qb * 64 + wv * 16;

    const __bf16* qp = Q + (long)(b * S_ + qT + lr) * D_ + h * DK_ + lk * 8;
    const bf16x8 qf0 = *(const bf16x8*)qp;
    const bf16x8 qf1 = *(const bf16x8*)(qp + 32);

    float frv[4], ls[4];
    #pragma unroll
    for (int r = 0; r < 4; ++r) {
        frv[r] = fr[b * S_ + qT + lk * 4 + r] * 0.125f;
        ls[r] = 0.f;
    }
    f32x4 o[4] = {};

    const int srow = t >> 3;
    const int sslot = (t & 7) ^ (srow & 7);
    const __bf16* kstage = Q + (long)(b * S_ + srow) * D_ + h * DK_ + sslot * 8;
    const __bf16* vstage = Vt + ((long)(b * H_ + h) * DK_ + srow) * S_ + sslot * 8;
    __bf16* pl = &Plds[wv][0];
    const int sw = (lr & 7);

    auto STAGE = [&](int bsel, int ks) {
        gld_lds16(kstage + (long)ks * D_, (char*)Ks[bsel] + t * 16);
        gld_lds16(kstage + (long)(ks + 32) * D_, (char*)Ks[bsel] + 4096 + t * 16);
        gld_lds16(vstage + ks, (char*)Vs[bsel] + t * 16);
        gld_lds16(vstage + ks + 32 * S_, (char*)Vs[bsel] + 4096 + t * 16);
    };

    auto COMPUTE = [&](int bsel, int ks) {
        f32x4 sc[4] = {};
        #pragma unroll
        for (int j = 0; j < 4; ++j) {
            const char* kb = (const char*)Ks[bsel] + ((j * 16 + lr) << 7);
            const bf16x8 kf0 = *(const bf16x8*)(kb + ((lk ^ sw) << 4));
            const bf16x8 kf1 = *(const bf16x8*)(kb + (((lk + 4) ^ sw) << 4));
            sc[j] = __builtin_amdgcn_mfma_f32_16x16x32_bf16(qf0, kf0, sc[j], 0, 0, 0);
            sc[j] = __builtin_amdgcn_mfma_f32_16x16x32_bf16(qf1, kf1, sc[j], 0, 0, 0);
        }
        #pragma unroll
        for (int j = 0; j < 4; ++j) {
            const int col = ks + j * 16 + lr;
            const int c8 = j * 2 + (lr >> 3), cb = lr & 7;
            #pragma unroll
            for (int r = 0; r < 4; ++r) {
                const int row = lk * 4 + r;
                const int sidx = row * 64 + ((c8 ^ (row & 7)) << 3) + cb;
                const float e = __expf(sc[j][r] * frv[r]);
                const float p = (col < qT + row) ? e : 0.f;
                ls[r] += p;
                pl[sidx] = (__bf16)p;
            }
        }
        bf16x8 pf[2];
        #pragma unroll
        for (int kk = 0; kk < 2; ++kk) {
            const int ridx = lr * 64 + (((kk * 4 + lk) ^ sw) << 3);
            pf[kk] = *(const bf16x8*)&pl[ridx];
        }
        #pragma unroll
        for (int dt = 0; dt < 4; ++dt) {
            const char* vb = (const char*)Vs[bsel] + ((dt * 16 + lr) << 7);
            #pragma unroll
            for (int kk = 0; kk < 2; ++kk) {
                const bf16x8 vf = *(const bf16x8*)(vb + (((kk * 4 + lk) ^ sw) << 4));
                o[dt] = __builtin_amdgcn_mfma_f32_16x16x32_bf16(pf[kk], vf, o[dt], 0, 0, 0);
            }
        }
    };

    const int nt = qb + 1;
    STAGE(0, 0);
    if (nt > 1) STAGE(1, 64);
    for (int tt = 0; tt < nt - 1; ++tt) {
        asm volatile("s_waitcnt vmcnt(4)" ::: "memory");
        __builtin_amdgcn_s_barrier();
        COMPUTE(tt & 1, tt * 64);
        __builtin_amdgcn_s_barrier();
        if (tt + 2 < nt) STAGE(tt & 1, (tt + 2) * 64);
    }
    asm volatile("s_waitcnt vmcnt(0)" ::: "memory");
    __builtin_amdgcn_s_barrier();
    COMPUTE((nt - 1) & 1, (nt - 1) * 64);

    #pragma unroll
    for (int r = 0; r < 4; ++r) {
        #pragma unroll
        for (int d = 1; d < 16; d <<= 1)
            ls[r] += __shfl_xor(ls[r], d);
        const float inv = ls[r] > 0.f ? 1.f / ls[r] : 0.f;  // row 0 -> zeros
        #pragma unroll
        for (int dt = 0; dt < 4; ++dt)
            Out[(long)(b * S_ + qT + lk * 4 + r) * D_ + h * DK_ + dt * 16 + lr] =
                (__bf16)(o[dt][r] * inv);
    }
}

// ---- LayerNorm: bf16 in, bf16 out (+fp32 out only when wf32 != 0) ----
__global__ __launch_bounds__(256) void ln_kernel(
    const __bf16* __restrict__ pre, const float* __restrict__ g,
    const float* __restrict__ be, float* __restrict__ xout,
    __bf16* __restrict__ xbf, int wf32)
{
    const int lane = threadIdx.x & 63, wv = threadIdx.x >> 6;
    const long row = (long)blockIdx.x * 4 + wv;
    const bf16x8 v = *(const bf16x8*)(pre + row * D_ + lane * 8);
    float f[8];
    #pragma unroll
    for (int k = 0; k < 8; ++k) f[k] = (float)v[k];
    float s = 0.f, ss = 0.f;
    #pragma unroll
    for (int k = 0; k < 8; ++k) { s += f[k]; ss += f[k] * f[k]; }
    #pragma unroll
    for (int d = 1; d < 64; d <<= 1) {
        s  += __shfl_xor(s, d);
        ss += __shfl_xor(ss, d);
    }
    const float mean = s * (1.f / 512.f);
    const float rstd = rsqrtf(ss * (1.f / 512.f) - mean * mean + 1e-5f);
    const float4 ga = ((const float4*)(g + lane * 8))[0];
    const float4 gc = ((const float4*)(g + lane * 8))[1];
    const float4 ba = ((const float4*)(be + lane * 8))[0];
    const float4 bc = ((const float4*)(be + lane * 8))[1];
    float o[8];
    o[0] = (f[0] - mean) * rstd * ga.x + ba.x;
    o[1] = (f[1] - mean) * rstd * ga.y + ba.y;
    o[2] = (f[2] - mean) * rstd * ga.z + ba.z;
    o[3] = (f[3] - mean) * rstd * ga.w + ba.w;
    o[4] = (f[4] - mean) * rstd * gc.x + bc.x;
    o[5] = (f[5] - mean) * rstd * gc.y + bc.y;
    o[6] = (f[6] - mean) * rstd * gc.z + bc.z;
    o[7] = (f[7] - mean) * rstd * gc.w + bc.w;
    bf16x8 xb = {(__bf16)o[0], (__bf16)o[1], (__bf16)o[2], (__bf16)o[3],
                 (__bf16)o[4], (__bf16)o[5], (__bf16)o[6], (__bf16)o[7]};
    *(bf16x8*)(xbf + row * D_ + lane * 8) = xb;
    if (wf32) {
        float* xo = xout + row * D_ + lane * 8;
        ((float4*)xo)[0] = make_float4(o[0], o[1], o[2], o[3]);
        ((float4*)xo)[1] = make_float4(o[4], o[5], o[6], o[7]);
    }
}

extern "C" void kernel_launch(void* const* d_in, const int* in_sizes, int n_in,
                              void* d_out, int out_size, void* d_ws, size_t ws_size,
                              hipStream_t stream) {
    const float* q_embed = (const float*)d_in[0];
    const float* qa_embed = (const float*)d_in[1];
    const float* fr  = (const float*)d_in[2];
    const float* pe  = (const float*)d_in[3];
    const float* Wk  = (const float*)d_in[4];
    const float* bk  = (const float*)d_in[5];
    const float* Wv  = (const float*)d_in[6];
    const float* bv  = (const float*)d_in[7];
    const float* Wo  = (const float*)d_in[8];
    const float* bo  = (const float*)d_in[9];
    const float* g1  = (const float*)d_in[10];
    const float* be1 = (const float*)d_in[11];
    const float* W1  = (const float*)d_in[12];
    const float* bf1 = (const float*)d_in[13];
    const float* W2  = (const float*)d_in[14];
    const float* bf2 = (const float*)d_in[15];
    const float* g2  = (const float*)d_in[16];
    const float* be2 = (const float*)d_in[17];

    // workspace layout (~128 MB)
    char* ws = (char*)d_ws;
    __bf16* xbf   = (__bf16*)(ws + 0);           // 16 MB bf16 residual master
    __bf16* ybf   = (__bf16*)(ws + 16777216);    // 16 MB
    __bf16* pool  = (__bf16*)(ws + 33554432);    // 64 MB: k/vt/attn OR f1
    __bf16* preln = (__bf16*)(ws + 100663296);   // 16 MB
    __bf16* wts   = (__bf16*)(ws + 117440512);   // 11 MB bf16 transposed weights

    __bf16* kbuf  = pool;
    __bf16* vtbuf = pool + 8388608;
    __bf16* abuf  = pool + 2 * 8388608;
    __bf16* f1buf = pool;  // 64 MB, aliases k/vt/attn (all dead by FFN1)

    __bf16* wkt = wts;
    __bf16* wvt = wts + 524288;
    __bf16* wot = wts + 1048576;
    __bf16* w1t = wts + 1572864;
    __bf16* w2t = wts + 3670016;

    transpose_all<<<5632, 256, 0, stream>>>(Wk, Wv, Wo, W1, W2,
                                            wkt, wvt, wot, w1t, w2t);
    prep_kernel<<<2048, 256, 0, stream>>>(q_embed, qa_embed, pe, xbf, ybf);

    for (int i = 0; i < 2; ++i) {
        gemm_kv<<<dim3(4, 128, 2), 256, 0, stream>>>(
            xbf, ybf, wkt + i * 262144, wvt + i * 262144,
            bk + i * 512, bv + i * 512, kbuf, vtbuf);
        attn_kernel<<<dim3(8, 8, 32), 256, 0, stream>>>(kbuf, vtbuf, fr, abuf);
        gemm_kernel<0, 1><<<dim3(4, 128), 256, 0, stream>>>(
            abuf, wot + i * 262144, bo + i * 512, xbf, preln, 16384, 512, 512);
        ln_kernel<<<4096, 256, 0, stream>>>(preln, g1 + i * 512, be1 + i * 512,
                                            (float*)d_out, xbf, 0);
        gemm8_kernel<1, 0><<<dim3(8, 64), 512, 0, stream>>>(
            xbf, w1t + i * 1048576, bf1 + i * 2048, nullptr, f1buf, 16384, 2048, 512);
        gemm_kernel<0, 1><<<dim3(4, 128), 256, 0, stream>>>(
            f1buf, w2t + i * 1048576, bf2 + i * 512, xbf, preln, 16384, 512, 2048);
        ln_kernel<<<4096, 256, 0, stream>>>(preln, g2 + i * 512, be2 + i * 512,
                                            (float*)d_out, xbf, i == 1 ? 1 : 0);
    }
}

// Round 11
// 432.213 us; speedup vs baseline: 1.6747x; 1.0061x over previous
//
#include <hip/hip_runtime.h>

#define B_ 32
#define S_ 512
#define D_ 512
#define H_ 8
#define DK_ 64
#define FF_ 2048

typedef float f32x4 __attribute__((ext_vector_type(4)));
typedef __bf16 bf16x8 __attribute__((ext_vector_type(8)));
typedef __bf16 bf16x4 __attribute__((ext_vector_type(4)));

// ---- async global->LDS, 16B per lane (dest must be wave-uniform base + lane*16) ----
__device__ __forceinline__ void gld_lds16(const void* gptr, void* lptr) {
    auto g = (__attribute__((address_space(1))) void*)(unsigned long long)gptr;
    auto l = (__attribute__((address_space(3))) void*)(unsigned)(unsigned long long)lptr;
    __builtin_amdgcn_global_load_lds(g, l, 16, 0, 0);
}

// ---- x = q+pe (bf16), y = qa+pe (bf16); bf16 master stream ----
__global__ __launch_bounds__(256) void prep_kernel(
    const float* __restrict__ q, const float* __restrict__ qa,
    const float* __restrict__ pe, __bf16* __restrict__ xbf,
    __bf16* __restrict__ ybf)
{
    const int n4 = B_ * S_ * D_ / 4;
    for (int i = blockIdx.x * blockDim.x + threadIdx.x; i < n4;
         i += gridDim.x * blockDim.x) {
        float4 pv = ((const float4*)pe)[i & (S_ * D_ / 4 - 1)];
        float4 qv = ((const float4*)q)[i];
        float4 av = ((const float4*)qa)[i];
        bf16x4 xb = {(__bf16)(qv.x + pv.x), (__bf16)(qv.y + pv.y),
                     (__bf16)(qv.z + pv.z), (__bf16)(qv.w + pv.w)};
        ((bf16x4*)xbf)[i] = xb;
        bf16x4 yb = {(__bf16)(av.x + pv.x), (__bf16)(av.y + pv.y),
                     (__bf16)(av.z + pv.z), (__bf16)(av.w + pv.w)};
        ((bf16x4*)ybf)[i] = yb;
    }
}

// ---- shared 32x32 transpose tile body: fp32 [R][C] -> bf16 [C][R] ----
__device__ __forceinline__ void ttile(
    const float* __restrict__ in, __bf16* __restrict__ out,
    int R, int C, int bx, int by, int t)
{
    __shared__ float tile[32][33];
    const int tc = bx * 32, tr = by * 32;
    const int lx = t & 31, ly = t >> 5;
    #pragma unroll
    for (int yy = ly; yy < 32; yy += 8)
        tile[yy][lx] = in[(long)(tr + yy) * C + tc + lx];
    __syncthreads();
    #pragma unroll
    for (int yy = ly; yy < 32; yy += 8)
        out[(long)(tc + yy) * R + tr + lx] = (__bf16)tile[lx][yy];
}

// ---- all weight transposes in one flat-grid dispatch ----
__global__ __launch_bounds__(256) void transpose_all(
    const float* __restrict__ Wk, const float* __restrict__ Wv,
    const float* __restrict__ Wo, const float* __restrict__ W1,
    const float* __restrict__ W2, __bf16* __restrict__ ok,
    __bf16* __restrict__ ov, __bf16* __restrict__ oo,
    __bf16* __restrict__ o1, __bf16* __restrict__ o2)
{
    const int id = blockIdx.x, t = threadIdx.x;
    if (id < 1536) {
        const int z = id >> 8, r = id & 255;
        const int sel = z >> 1, i = z & 1;
        const float* src = sel == 0 ? Wk : (sel == 1 ? Wv : Wo);
        __bf16* dst = sel == 0 ? ok : (sel == 1 ? ov : oo);
        ttile(src + (long)i * 262144, dst + (long)i * 262144, 512, 512,
              r & 15, r >> 4, t);
    } else if (id < 3584) {
        int r = id - 1536; const int i = r >> 10; r &= 1023;
        ttile(W1 + (long)i * 1048576, o1 + (long)i * 1048576, 512, 2048,
              r & 63, r >> 6, t);
    } else {
        int r = id - 3584; const int i = r >> 10; r &= 1023;
        ttile(W2 + (long)i * 1048576, o2 + (long)i * 1048576, 2048, 512,
              r & 15, r >> 4, t);
    }
}

// ---- GEMM v5 (proven): 128x128, BK=64, T2 swizzle, T1 XCD swizzle,
// 2-deep counted-vmcnt pipeline. MODE 0: bf16 out (+RELU). MODE 1: +res. ----
template <int RELU, int MODE>
__global__ __launch_bounds__(256) void gemm_kernel(
    const __bf16* __restrict__ A, const __bf16* __restrict__ Bt,
    const float* __restrict__ bias, const __bf16* __restrict__ res,
    __bf16* __restrict__ out, int M, int N, int K)
{
    __shared__ __bf16 As[2][128 * 64];
    __shared__ __bf16 Bs[2][128 * 64];
    const int t = threadIdx.x;
    const int lane = t & 63;
    const int wv = t >> 6, wr = wv >> 1, wc = wv & 1;
    const int lr = lane & 15, lk = lane >> 4;

    const int nwg = gridDim.x * gridDim.y;
    const int lin = blockIdx.y * gridDim.x + blockIdx.x;
    const int swz = (lin & 7) * (nwg >> 3) + (lin >> 3);
    const int m0 = (swz / gridDim.x) * 128, n0 = (swz % gridDim.x) * 128;

    const int srow = t >> 3;
    const int sslot = (t & 7) ^ (srow & 7);
    const __bf16* gA = A + (long)(m0 + srow) * K + sslot * 8;
    const __bf16* gB = Bt + (long)(n0 + srow) * K + sslot * 8;
    const long rstep = (long)32 * K;

    auto STAGE = [&](int bsel, int k0) {
        char* ldsA = (char*)As[bsel] + t * 16;
        char* ldsB = (char*)Bs[bsel] + t * 16;
        #pragma unroll
        for (int u = 0; u < 4; ++u) {
            gld_lds16(gA + u * rstep + k0, ldsA + u * 4096);
            gld_lds16(gB + u * rstep + k0, ldsB + u * 4096);
        }
    };

    f32x4 acc[4][4] = {};
    auto COMPUTE = [&](int bsel) {
        #pragma unroll
        for (int kk = 0; kk < 2; ++kk) {
            bf16x8 af[4], bfr[4];
            #pragma unroll
            for (int i = 0; i < 4; ++i) {
                const int rr = wr * 64 + i * 16 + lr;
                af[i] = *(const bf16x8*)((const char*)As[bsel] +
                        (rr << 7) + (((kk * 4 + lk) ^ (rr & 7)) << 4));
            }
            #pragma unroll
            for (int j = 0; j < 4; ++j) {
                const int rr = wc * 64 + j * 16 + lr;
                bfr[j] = *(const bf16x8*)((const char*)Bs[bsel] +
                         (rr << 7) + (((kk * 4 + lk) ^ (rr & 7)) << 4));
            }
            #pragma unroll
            for (int i = 0; i < 4; ++i)
                #pragma unroll
                for (int j = 0; j < 4; ++j)
                    acc[i][j] = __builtin_amdgcn_mfma_f32_16x16x32_bf16(
                        af[i], bfr[j], acc[i][j], 0, 0, 0);
        }
    };

    const int NT = K >> 6;
    STAGE(0, 0);
    STAGE(1, 64);
    for (int kt = 0; kt < NT - 1; ++kt) {
        asm volatile("s_waitcnt vmcnt(8)" ::: "memory");
        __builtin_amdgcn_s_barrier();
        COMPUTE(kt & 1);
        __builtin_amdgcn_s_barrier();
        if (kt + 2 < NT) STAGE(kt & 1, (kt + 2) << 6);
    }
    asm volatile("s_waitcnt vmcnt(0)" ::: "memory");
    __builtin_amdgcn_s_barrier();
    COMPUTE((NT - 1) & 1);

    #pragma unroll
    for (int i = 0; i < 4; ++i) {
        #pragma unroll
        for (int j = 0; j < 4; ++j) {
            const int n = n0 + wc * 64 + j * 16 + lr;
            const float bv = bias[n];
            #pragma unroll
            for (int r = 0; r < 4; ++r) {
                const int m = m0 + wr * 64 + i * 16 + lk * 4 + r;
                const long off = (long)m * N + n;
                float v = acc[i][j][r] + bv;
                if (MODE == 1) v += (float)res[off];
                if (RELU) v = v > 0.f ? v : 0.f;
                out[off] = (__bf16)v;
            }
        }
    }
}

// ---- GEMM8: 256x256 tile, 8 waves, BK=64, 8-phase interleave (T3+T4+T5).
// Subtiled LDS with intra-subtile XOR swizzle (slot ^= (row>>2)&3) applied on
// BOTH sides: pre-swizzled global source (linear LDS dest) + swizzled read.
// Banks: 16(lr&1)+4(lk^(lr>>2)) -> 2 lanes/bank = free (was 8-way, 3.15M).
template <int RELU, int MODE>
__global__ __launch_bounds__(512, 2) void gemm8_kernel(
    const __bf16* __restrict__ A, const __bf16* __restrict__ Bt,
    const float* __restrict__ bias, const __bf16* __restrict__ res,
    __bf16* __restrict__ out, int M, int N, int K)
{
    __shared__ __bf16 lds[65536];  // 128 KB
    const int t = threadIdx.x;
    const int lane = t & 63, wv = t >> 6;
    const int wr = wv >> 2, wc = wv & 3;
    const int lr = lane & 15, lk = lane >> 4;

    const int nwg = gridDim.x * gridDim.y;
    const int lin = blockIdx.y * gridDim.x + blockIdx.x;
    const int swz = (lin & 7) * (nwg >> 3) + (lin >> 3);
    const int m0 = (swz / gridDim.x) * 256, n0 = (swz % gridDim.x) * 256;

    const int srcrow = lane >> 2;
    const int srccol = ((lane & 3) ^ ((lane >> 4) & 3)) * 8;  // pre-swizzled source slot
    // stage one K-half region (16 subtiles) of A (isB=0) or B (isB=1), tile kt2, buffer pb
    auto STG = [&](int isB, int kt2, int kk2, int pb) {
        const __bf16* src = isB ? Bt : A;
        const int base = isB ? n0 : m0;
        #pragma unroll
        for (int u = 0; u < 2; ++u) {
            const int sr = u * 8 + wv;
            const long g = (long)(base + sr * 16 + srcrow) * K + kt2 * 64 + kk2 * 32 + srccol;
            char* d = (char*)lds + pb * 65536 + isB * 32768 + ((sr * 2 + kk2) << 10) + lane * 16;
            gld_lds16(src + g, d);
        }
    };

    f32x4 acc[8][4] = {};
    bf16x8 af[4], bfr[4];
    auto RDA = [&](int p, int kk, int mh) {
        #pragma unroll
        for (int i = 0; i < 4; ++i) {
            const int sr = wr * 8 + mh * 4 + i;
            af[i] = *(const bf16x8*)((const char*)lds + p * 65536 +
                    ((sr * 2 + kk) << 10) + lr * 64 + ((lk ^ ((lr >> 2) & 3)) << 4));
        }
    };
    auto RDB = [&](int p, int kk) {
        #pragma unroll
        for (int j = 0; j < 4; ++j) {
            const int sr = wc * 4 + j;
            bfr[j] = *(const bf16x8*)((const char*)lds + p * 65536 + 32768 +
                     ((sr * 2 + kk) << 10) + lr * 64 + ((lk ^ ((lr >> 2) & 3)) << 4));
        }
    };
    auto MM = [&](int mh) {
        __builtin_amdgcn_s_setprio(1);
        #pragma unroll
        for (int i = 0; i < 4; ++i)
            #pragma unroll
            for (int j = 0; j < 4; ++j)
                acc[mh * 4 + i][j] = __builtin_amdgcn_mfma_f32_16x16x32_bf16(
                    af[i], bfr[j], acc[mh * 4 + i][j], 0, 0, 0);
        __builtin_amdgcn_s_setprio(0);
    };

    const int NT = K >> 6;
    // prologue: t0 Ak0,Bk0,Ak1,Bk1; t1 Ak0,Bk0  (6 regions = 12 loads/thread)
    STG(0, 0, 0, 0); STG(1, 0, 0, 0); STG(0, 0, 1, 0); STG(1, 0, 1, 0);
    STG(0, 1, 0, 1); STG(1, 1, 0, 1);

    for (int kt = 0; kt < NT - 1; ++kt) {
        const int p = kt & 1;
        asm volatile("s_waitcnt vmcnt(8)" ::: "memory");   // tile kt k0 landed
        __builtin_amdgcn_s_barrier();
        RDA(p, 0, 0); RDB(p, 0); STG(0, kt + 1, 1, p ^ 1);
        MM(0);
        __builtin_amdgcn_s_barrier();
        RDA(p, 0, 1); STG(1, kt + 1, 1, p ^ 1);
        MM(1);
        asm volatile("s_waitcnt vmcnt(8)" ::: "memory");   // tile kt k1 landed
        __builtin_amdgcn_s_barrier();
        RDA(p, 1, 0); RDB(p, 1); if (kt + 2 < NT) STG(0, kt + 2, 0, p);
        MM(0);
        __builtin_amdgcn_s_barrier();
        RDA(p, 1, 1); if (kt + 2 < NT) STG(1, kt + 2, 0, p);
        MM(1);
    }
    {   // peeled last tile: no stages; drain exactly
        const int p = (NT - 1) & 1;
        asm volatile("s_waitcnt vmcnt(4)" ::: "memory");
        __builtin_amdgcn_s_barrier();
        RDA(p, 0, 0); RDB(p, 0); MM(0);
        __builtin_amdgcn_s_barrier();
        RDA(p, 0, 1); MM(1);
        asm volatile("s_waitcnt vmcnt(0)" ::: "memory");
        __builtin_amdgcn_s_barrier();
        RDA(p, 1, 0); RDB(p, 1); MM(0);
        __builtin_amdgcn_s_barrier();
        RDA(p, 1, 1); MM(1);
    }

    #pragma unroll
    for (int i = 0; i < 8; ++i) {
        #pragma unroll
        for (int j = 0; j < 4; ++j) {
            const int n = n0 + wc * 64 + j * 16 + lr;
            const float bv = bias[n];
            #pragma unroll
            for (int r = 0; r < 4; ++r) {
                const int m = m0 + wr * 128 + i * 16 + lk * 4 + r;
                const long off = (long)m * N + n;
                float v = acc[i][j][r] + bv;
                if (MODE == 1) v += (float)res[off];
                if (RELU) v = v > 0.f ? v : 0.f;
                out[off] = (__bf16)v;
            }
        }
    }
}

// ---- merged K+V projection (proven v5 pipeline) ----
__global__ __launch_bounds__(256) void gemm_kv(
    const __bf16* __restrict__ xbf, const __bf16* __restrict__ ybf,
    const __bf16* __restrict__ wkt, const __bf16* __restrict__ wvt,
    const float* __restrict__ bk, const float* __restrict__ bv,
    __bf16* __restrict__ kout, __bf16* __restrict__ vtout)
{
    constexpr int N = 512, K = 512;
    __shared__ __bf16 As[2][128 * 64];
    __shared__ __bf16 Bs[2][128 * 64];
    const int t = threadIdx.x;
    const int lane = t & 63;
    const int wv = t >> 6, wr = wv >> 1, wc = wv & 1;
    const int lr = lane & 15, lk = lane >> 4;
    const int zv = blockIdx.z;

    const __bf16* A  = zv ? ybf : xbf;
    const __bf16* Bt = zv ? wvt : wkt;
    const float* bias = zv ? bv : bk;
    __bf16* out = zv ? vtout : kout;

    const int nwg = gridDim.x * gridDim.y;
    const int lin = blockIdx.y * gridDim.x + blockIdx.x;
    const int swz = (lin & 7) * (nwg >> 3) + (lin >> 3);
    const int m0 = (swz / gridDim.x) * 128, n0 = (swz % gridDim.x) * 128;

    const int srow = t >> 3;
    const int sslot = (t & 7) ^ (srow & 7);
    const __bf16* gA = A + (long)(m0 + srow) * K + sslot * 8;
    const __bf16* gB = Bt + (long)(n0 + srow) * K + sslot * 8;
    const long rstep = (long)32 * K;

    auto STAGE = [&](int bsel, int k0) {
        char* ldsA = (char*)As[bsel] + t * 16;
        char* ldsB = (char*)Bs[bsel] + t * 16;
        #pragma unroll
        for (int u = 0; u < 4; ++u) {
            gld_lds16(gA + u * rstep + k0, ldsA + u * 4096);
            gld_lds16(gB + u * rstep + k0, ldsB + u * 4096);
        }
    };

    f32x4 acc[4][4] = {};
    auto COMPUTE = [&](int bsel) {
        #pragma unroll
        for (int kk = 0; kk < 2; ++kk) {
            bf16x8 af[4], bfr[4];
            #pragma unroll
            for (int i = 0; i < 4; ++i) {
                const int rr = wr * 64 + i * 16 + lr;
                af[i] = *(const bf16x8*)((const char*)As[bsel] +
                        (rr << 7) + (((kk * 4 + lk) ^ (rr & 7)) << 4));
            }
            #pragma unroll
            for (int j = 0; j < 4; ++j) {
                const int rr = wc * 64 + j * 16 + lr;
                bfr[j] = *(const bf16x8*)((const char*)Bs[bsel] +
                         (rr << 7) + (((kk * 4 + lk) ^ (rr & 7)) << 4));
            }
            #pragma unroll
            for (int i = 0; i < 4; ++i)
                #pragma unroll
                for (int j = 0; j < 4; ++j)
                    acc[i][j] = __builtin_amdgcn_mfma_f32_16x16x32_bf16(
                        af[i], bfr[j], acc[i][j], 0, 0, 0);
        }
    };

    const int NT = K >> 6;
    STAGE(0, 0);
    STAGE(1, 64);
    for (int kt = 0; kt < NT - 1; ++kt) {
        asm volatile("s_waitcnt vmcnt(8)" ::: "memory");
        __builtin_amdgcn_s_barrier();
        COMPUTE(kt & 1);
        __builtin_amdgcn_s_barrier();
        if (kt + 2 < NT) STAGE(kt & 1, (kt + 2) << 6);
    }
    asm volatile("s_waitcnt vmcnt(0)" ::: "memory");
    __builtin_amdgcn_s_barrier();
    COMPUTE((NT - 1) & 1);

    #pragma unroll
    for (int i = 0; i < 4; ++i) {
        #pragma unroll
        for (int j = 0; j < 4; ++j) {
            const int n = n0 + wc * 64 + j * 16 + lr;
            const float bvl = bias[n];
            if (zv) {
                const int mb = m0 + wr * 64 + i * 16 + lk * 4;
                const int b = mb >> 9, s = mb & 511;
                bf16x4 ov = {(__bf16)(acc[i][j][0] + bvl),
                             (__bf16)(acc[i][j][1] + bvl),
                             (__bf16)(acc[i][j][2] + bvl),
                             (__bf16)(acc[i][j][3] + bvl)};
                *(bf16x4*)(out + (((long)(b * 8 + (n >> 6)) * 64 + (n & 63)) << 9) + s) = ov;
            } else {
                #pragma unroll
                for (int r = 0; r < 4; ++r) {
                    const int m = m0 + wr * 64 + i * 16 + lk * 4 + r;
                    out[(long)m * N + n] = (__bf16)(acc[i][j][r] + bvl);
                }
            }
        }
    }
}

// ---- attention v5 (proven): 2-deep double-buffered K/V staging, counted vmcnt ----
__global__ __launch_bounds__(256) void attn_kernel(
    const __bf16* __restrict__ Q, const __bf16* __restrict__ Vt,
    const float* __restrict__ fr, __bf16* __restrict__ Out)
{
    __shared__ __bf16 Ks[2][64 * 64];
    __shared__ __bf16 Vs[2][64 * 64];
    __shared__ __bf16 Plds[4][16 * 64];
    const int t = threadIdx.x;
    const int lane = t & 63, wv = t >> 6;
    const int lr = lane & 15, lk = lane >> 4;
    const int qb = blockIdx.x, h = blockIdx.y, b = blockIdx.z;
    const int qT = qb * 64 + wv * 16;

    const __bf16* qp = Q + (long)(b * S_ + qT + lr) * D_ + h * DK_ + lk * 8;
    const bf16x8 qf0 = *(const bf16x8*)qp;
    const bf16x8 qf1 = *(const bf16x8*)(qp + 32);

    float frv[4], ls[4];
    #pragma unroll
    for (int r = 0; r < 4; ++r) {
        frv[r] = fr[b * S_ + qT + lk * 4 + r] * 0.125f;
        ls[r] = 0.f;
    }
    f32x4 o[4] = {};

    const int srow = t >> 3;
    const int sslot = (t & 7) ^ (srow & 7);
    const __bf16* kstage = Q + (long)(b * S_ + srow) * D_ + h * DK_ + sslot * 8;
    const __bf16* vstage = Vt + ((long)(b * H_ + h) * DK_ + srow) * S_ + sslot * 8;
    __bf16* pl = &Plds[wv][0];
    const int sw = (lr & 7);

    auto STAGE = [&](int bsel, int ks) {
        gld_lds16(kstage + (long)ks * D_, (char*)Ks[bsel] + t * 16);
        gld_lds16(kstage + (long)(ks + 32) * D_, (char*)Ks[bsel] + 4096 + t * 16);
        gld_lds16(vstage + ks, (char*)Vs[bsel] + t * 16);
        gld_lds16(vstage + ks + 32 * S_, (char*)Vs[bsel] + 4096 + t * 16);
    };

    auto COMPUTE = [&](int bsel, int ks) {
        f32x4 sc[4] = {};
        #pragma unroll
        for (int j = 0; j < 4; ++j) {
            const char* kb = (const char*)Ks[bsel] + ((j * 16 + lr) << 7);
            const bf16x8 kf0 = *(const bf16x8*)(kb + ((lk ^ sw) << 4));
            const bf16x8 kf1 = *(const bf16x8*)(kb + (((lk + 4) ^ sw) << 4));
            sc[j] = __builtin_amdgcn_mfma_f32_16x16x32_bf16(qf0, kf0, sc[j], 0, 0, 0);
            sc[j] = __builtin_amdgcn_mfma_f32_16x16x32_bf16(qf1, kf1, sc[j], 0, 0, 0);
        }
        #pragma unroll
        for (int j = 0; j < 4; ++j) {
            const int col = ks + j * 16 + lr;
            const int c8 = j * 2 + (lr >> 3), cb = lr & 7;
            #pragma unroll
            for (int r = 0; r < 4; ++r) {
                const int row = lk * 4 + r;
                const int sidx = row * 64 + ((c8 ^ (row & 7)) << 3) + cb;
                const float e = __expf(sc[j][r] * frv[r]);
                const float p = (col < qT + row) ? e : 0.f;
                ls[r] += p;
                pl[sidx] = (__bf16)p;
            }
        }
        bf16x8 pf[2];
        #pragma unroll
        for (int kk = 0; kk < 2; ++kk) {
            const int ridx = lr * 64 + (((kk * 4 + lk) ^ sw) << 3);
            pf[kk] = *(const bf16x8*)&pl[ridx];
        }
        #pragma unroll
        for (int dt = 0; dt < 4; ++dt) {
            const char* vb = (const char*)Vs[bsel] + ((dt * 16 + lr) << 7);
            #pragma unroll
            for (int kk = 0; kk < 2; ++kk) {
                const bf16x8 vf = *(const bf16x8*)(vb + (((kk * 4 + lk) ^ sw) << 4));
                o[dt] = __builtin_amdgcn_mfma_f32_16x16x32_bf16(pf[kk], vf, o[dt], 0, 0, 0);
            }
        }
    };

    const int nt = qb + 1;
    STAGE(0, 0);
    if (nt > 1) STAGE(1, 64);
    for (int tt = 0; tt < nt - 1; ++tt) {
        asm volatile("s_waitcnt vmcnt(4)" ::: "memory");
        __builtin_amdgcn_s_barrier();
        COMPUTE(tt & 1, tt * 64);
        __builtin_amdgcn_s_barrier();
        if (tt + 2 < nt) STAGE(tt & 1, (tt + 2) * 64);
    }
    asm volatile("s_waitcnt vmcnt(0)" ::: "memory");
    __builtin_amdgcn_s_barrier();
    COMPUTE((nt - 1) & 1, (nt - 1) * 64);

    #pragma unroll
    for (int r = 0; r < 4; ++r) {
        #pragma unroll
        for (int d = 1; d < 16; d <<= 1)
            ls[r] += __shfl_xor(ls[r], d);
        const float inv = ls[r] > 0.f ? 1.f / ls[r] : 0.f;  // row 0 -> zeros
        #pragma unroll
        for (int dt = 0; dt < 4; ++dt)
            Out[(long)(b * S_ + qT + lk * 4 + r) * D_ + h * DK_ + dt * 16 + lr] =
                (__bf16)(o[dt][r] * inv);
    }
}

// ---- LayerNorm: bf16 in, bf16 out (+fp32 out only when wf32 != 0) ----
__global__ __launch_bounds__(256) void ln_kernel(
    const __bf16* __restrict__ pre, const float* __restrict__ g,
    const float* __restrict__ be, float* __restrict__ xout,
    __bf16* __restrict__ xbf, int wf32)
{
    const int lane = threadIdx.x & 63, wv = threadIdx.x >> 6;
    const long row = (long)blockIdx.x * 4 + wv;
    const bf16x8 v = *(const bf16x8*)(pre + row * D_ + lane * 8);
    float f[8];
    #pragma unroll
    for (int k = 0; k < 8; ++k) f[k] = (float)v[k];
    float s = 0.f, ss = 0.f;
    #pragma unroll
    for (int k = 0; k < 8; ++k) { s += f[k]; ss += f[k] * f[k]; }
    #pragma unroll
    for (int d = 1; d < 64; d <<= 1) {
        s  += __shfl_xor(s, d);
        ss += __shfl_xor(ss, d);
    }
    const float mean = s * (1.f / 512.f);
    const float rstd = rsqrtf(ss * (1.f / 512.f) - mean * mean + 1e-5f);
    const float4 ga = ((const float4*)(g + lane * 8))[0];
    const float4 gc = ((const float4*)(g + lane * 8))[1];
    const float4 ba = ((const float4*)(be + lane * 8))[0];
    const float4 bc = ((const float4*)(be + lane * 8))[1];
    float o[8];
    o[0] = (f[0] - mean) * rstd * ga.x + ba.x;
    o[1] = (f[1] - mean) * rstd * ga.y + ba.y;
    o[2] = (f[2] - mean) * rstd * ga.z + ba.z;
    o[3] = (f[3] - mean) * rstd * ga.w + ba.w;
    o[4] = (f[4] - mean) * rstd * gc.x + bc.x;
    o[5] = (f[5] - mean) * rstd * gc.y + bc.y;
    o[6] = (f[6] - mean) * rstd * gc.z + bc.z;
    o[7] = (f[7] - mean) * rstd * gc.w + bc.w;
    bf16x8 xb = {(__bf16)o[0], (__bf16)o[1], (__bf16)o[2], (__bf16)o[3],
                 (__bf16)o[4], (__bf16)o[5], (__bf16)o[6], (__bf16)o[7]};
    *(bf16x8*)(xbf + row * D_ + lane * 8) = xb;
    if (wf32) {
        float* xo = xout + row * D_ + lane * 8;
        ((float4*)xo)[0] = make_float4(o[0], o[1], o[2], o[3]);
        ((float4*)xo)[1] = make_float4(o[4], o[5], o[6], o[7]);
    }
}

extern "C" void kernel_launch(void* const* d_in, const int* in_sizes, int n_in,
                              void* d_out, int out_size, void* d_ws, size_t ws_size,
                              hipStream_t stream) {
    const float* q_embed = (const float*)d_in[0];
    const float* qa_embed = (const float*)d_in[1];
    const float* fr  = (const float*)d_in[2];
    const float* pe  = (const float*)d_in[3];
    const float* Wk  = (const float*)d_in[4];
    const float* bk  = (const float*)d_in[5];
    const float* Wv  = (const float*)d_in[6];
    const float* bv  = (const float*)d_in[7];
    const float* Wo  = (const float*)d_in[8];
    const float* bo  = (const float*)d_in[9];
    const float* g1  = (const float*)d_in[10];
    const float* be1 = (const float*)d_in[11];
    const float* W1  = (const float*)d_in[12];
    const float* bf1 = (const float*)d_in[13];
    const float* W2  = (const float*)d_in[14];
    const float* bf2 = (const float*)d_in[15];
    const float* g2  = (const float*)d_in[16];
    const float* be2 = (const float*)d_in[17];

    // workspace layout (~128 MB)
    char* ws = (char*)d_ws;
    __bf16* xbf   = (__bf16*)(ws + 0);           // 16 MB bf16 residual master
    __bf16* ybf   = (__bf16*)(ws + 16777216);    // 16 MB
    __bf16* pool  = (__bf16*)(ws + 33554432);    // 64 MB: k/vt/attn OR f1
    __bf16* preln = (__bf16*)(ws + 100663296);   // 16 MB
    __bf16* wts   = (__bf16*)(ws + 117440512);   // 11 MB bf16 transposed weights

    __bf16* kbuf  = pool;
    __bf16* vtbuf = pool + 8388608;
    __bf16* abuf  = pool + 2 * 8388608;
    __bf16* f1buf = pool;  // 64 MB, aliases k/vt/attn (all dead by FFN1)

    __bf16* wkt = wts;
    __bf16* wvt = wts + 524288;
    __bf16* wot = wts + 1048576;
    __bf16* w1t = wts + 1572864;
    __bf16* w2t = wts + 3670016;

    transpose_all<<<5632, 256, 0, stream>>>(Wk, Wv, Wo, W1, W2,
                                            wkt, wvt, wot, w1t, w2t);
    prep_kernel<<<2048, 256, 0, stream>>>(q_embed, qa_embed, pe, xbf, ybf);

    for (int i = 0; i < 2; ++i) {
        gemm_kv<<<dim3(4, 128, 2), 256, 0, stream>>>(
            xbf, ybf, wkt + i * 262144, wvt + i * 262144,
            bk + i * 512, bv + i * 512, kbuf, vtbuf);
        attn_kernel<<<dim3(8, 8, 32), 256, 0, stream>>>(kbuf, vtbuf, fr, abuf);
        gemm_kernel<0, 1><<<dim3(4, 128), 256, 0, stream>>>(
            abuf, wot + i * 262144, bo + i * 512, xbf, preln, 16384, 512, 512);
        ln_kernel<<<4096, 256, 0, stream>>>(preln, g1 + i * 512, be1 + i * 512,
                                            (float*)d_out, xbf, 0);
        gemm8_kernel<1, 0><<<dim3(8, 64), 512, 0, stream>>>(
            xbf, w1t + i * 1048576, bf1 + i * 2048, nullptr, f1buf, 16384, 2048, 512);
        gemm_kernel<0, 1><<<dim3(4, 128), 256, 0, stream>>>(
            f1buf, w2t + i * 1048576, bf2 + i * 512, xbf, preln, 16384, 512, 2048);
        ln_kernel<<<4096, 256, 0, stream>>>(preln, g2 + i * 512, be2 + i * 512,
                                            (float*)d_out, xbf, i == 1 ? 1 : 0);
    }
}

// Round 12
// 428.800 us; speedup vs baseline: 1.6880x; 1.0080x over previous
//
#include <hip/hip_runtime.h>

#define B_ 32
#define S_ 512
#define D_ 512
#define H_ 8
#define DK_ 64
#define FF_ 2048

typedef float f32x4 __attribute__((ext_vector_type(4)));
typedef __bf16 bf16x8 __attribute__((ext_vector_type(8)));
typedef __bf16 bf16x4 __attribute__((ext_vector_type(4)));

// ---- async global->LDS, 16B per lane (dest must be wave-uniform base + lane*16) ----
__device__ __forceinline__ void gld_lds16(const void* gptr, void* lptr) {
    auto g = (__attribute__((address_space(1))) void*)(unsigned long long)gptr;
    auto l = (__attribute__((address_space(3))) void*)(unsigned)(unsigned long long)lptr;
    __builtin_amdgcn_global_load_lds(g, l, 16, 0, 0);
}

// ---- shared 32x32 transpose tile body: fp32 [R][C] -> bf16 [C][R] ----
__device__ __forceinline__ void ttile(
    const float* __restrict__ in, __bf16* __restrict__ out,
    int R, int C, int bx, int by, int t)
{
    __shared__ float tile[32][33];
    const int tc = bx * 32, tr = by * 32;
    const int lx = t & 31, ly = t >> 5;
    #pragma unroll
    for (int yy = ly; yy < 32; yy += 8)
        tile[yy][lx] = in[(long)(tr + yy) * C + tc + lx];
    __syncthreads();
    #pragma unroll
    for (int yy = ly; yy < 32; yy += 8)
        out[(long)(tc + yy) * R + tr + lx] = (__bf16)tile[lx][yy];
}

// ---- weight transposes + x/y prep fused into one flat-grid dispatch ----
// blocks 0..1535: Wk/Wv/Wo; 1536..3583: W1; 3584..5631: W2; 5632..7679: prep.
__global__ __launch_bounds__(256) void pre_all(
    const float* __restrict__ Wk, const float* __restrict__ Wv,
    const float* __restrict__ Wo, const float* __restrict__ W1,
    const float* __restrict__ W2, const float* __restrict__ q,
    const float* __restrict__ qa, const float* __restrict__ pe,
    __bf16* __restrict__ ok, __bf16* __restrict__ ov,
    __bf16* __restrict__ oo, __bf16* __restrict__ o1,
    __bf16* __restrict__ o2, __bf16* __restrict__ xbf,
    __bf16* __restrict__ ybf)
{
    const int id = blockIdx.x, t = threadIdx.x;
    if (id < 1536) {
        const int z = id >> 8, r = id & 255;
        const int sel = z >> 1, i = z & 1;
        const float* src = sel == 0 ? Wk : (sel == 1 ? Wv : Wo);
        __bf16* dst = sel == 0 ? ok : (sel == 1 ? ov : oo);
        ttile(src + (long)i * 262144, dst + (long)i * 262144, 512, 512,
              r & 15, r >> 4, t);
    } else if (id < 3584) {
        int r = id - 1536; const int i = r >> 10; r &= 1023;
        ttile(W1 + (long)i * 1048576, o1 + (long)i * 1048576, 512, 2048,
              r & 63, r >> 6, t);
    } else if (id < 5632) {
        int r = id - 3584; const int i = r >> 10; r &= 1023;
        ttile(W2 + (long)i * 1048576, o2 + (long)i * 1048576, 2048, 512,
              r & 15, r >> 4, t);
    } else {
        const int n4 = B_ * S_ * D_ / 4;
        for (int i = (id - 5632) * 256 + t; i < n4; i += 2048 * 256) {
            float4 pv = ((const float4*)pe)[i & (S_ * D_ / 4 - 1)];
            float4 qv = ((const float4*)q)[i];
            float4 av = ((const float4*)qa)[i];
            bf16x4 xb = {(__bf16)(qv.x + pv.x), (__bf16)(qv.y + pv.y),
                         (__bf16)(qv.z + pv.z), (__bf16)(qv.w + pv.w)};
            ((bf16x4*)xbf)[i] = xb;
            bf16x4 yb = {(__bf16)(av.x + pv.x), (__bf16)(av.y + pv.y),
                         (__bf16)(av.z + pv.z), (__bf16)(av.w + pv.w)};
            ((bf16x4*)ybf)[i] = yb;
        }
    }
}

// ---- GEMM v5 (proven): 128x128, BK=64, T2 swizzle, T1 XCD swizzle,
// 2-deep counted-vmcnt pipeline. MODE 0: bf16 out (+RELU). MODE 1: +res. ----
template <int RELU, int MODE>
__global__ __launch_bounds__(256) void gemm_kernel(
    const __bf16* __restrict__ A, const __bf16* __restrict__ Bt,
    const float* __restrict__ bias, const __bf16* __restrict__ res,
    __bf16* __restrict__ out, int M, int N, int K)
{
    __shared__ __bf16 As[2][128 * 64];
    __shared__ __bf16 Bs[2][128 * 64];
    const int t = threadIdx.x;
    const int lane = t & 63;
    const int wv = t >> 6, wr = wv >> 1, wc = wv & 1;
    const int lr = lane & 15, lk = lane >> 4;

    const int nwg = gridDim.x * gridDim.y;
    const int lin = blockIdx.y * gridDim.x + blockIdx.x;
    const int swz = (lin & 7) * (nwg >> 3) + (lin >> 3);
    const int m0 = (swz / gridDim.x) * 128, n0 = (swz % gridDim.x) * 128;

    const int srow = t >> 3;
    const int sslot = (t & 7) ^ (srow & 7);
    const __bf16* gA = A + (long)(m0 + srow) * K + sslot * 8;
    const __bf16* gB = Bt + (long)(n0 + srow) * K + sslot * 8;
    const long rstep = (long)32 * K;

    auto STAGE = [&](int bsel, int k0) {
        char* ldsA = (char*)As[bsel] + t * 16;
        char* ldsB = (char*)Bs[bsel] + t * 16;
        #pragma unroll
        for (int u = 0; u < 4; ++u) {
            gld_lds16(gA + u * rstep + k0, ldsA + u * 4096);
            gld_lds16(gB + u * rstep + k0, ldsB + u * 4096);
        }
    };

    f32x4 acc[4][4] = {};
    auto COMPUTE = [&](int bsel) {
        #pragma unroll
        for (int kk = 0; kk < 2; ++kk) {
            bf16x8 af[4], bfr[4];
            #pragma unroll
            for (int i = 0; i < 4; ++i) {
                const int rr = wr * 64 + i * 16 + lr;
                af[i] = *(const bf16x8*)((const char*)As[bsel] +
                        (rr << 7) + (((kk * 4 + lk) ^ (rr & 7)) << 4));
            }
            #pragma unroll
            for (int j = 0; j < 4; ++j) {
                const int rr = wc * 64 + j * 16 + lr;
                bfr[j] = *(const bf16x8*)((const char*)Bs[bsel] +
                         (rr << 7) + (((kk * 4 + lk) ^ (rr & 7)) << 4));
            }
            #pragma unroll
            for (int i = 0; i < 4; ++i)
                #pragma unroll
                for (int j = 0; j < 4; ++j)
                    acc[i][j] = __builtin_amdgcn_mfma_f32_16x16x32_bf16(
                        af[i], bfr[j], acc[i][j], 0, 0, 0);
        }
    };

    const int NT = K >> 6;
    STAGE(0, 0);
    STAGE(1, 64);
    for (int kt = 0; kt < NT - 1; ++kt) {
        asm volatile("s_waitcnt vmcnt(8)" ::: "memory");
        __builtin_amdgcn_s_barrier();
        COMPUTE(kt & 1);
        __builtin_amdgcn_s_barrier();
        if (kt + 2 < NT) STAGE(kt & 1, (kt + 2) << 6);
    }
    asm volatile("s_waitcnt vmcnt(0)" ::: "memory");
    __builtin_amdgcn_s_barrier();
    COMPUTE((NT - 1) & 1);

    #pragma unroll
    for (int i = 0; i < 4; ++i) {
        #pragma unroll
        for (int j = 0; j < 4; ++j) {
            const int n = n0 + wc * 64 + j * 16 + lr;
            const float bv = bias[n];
            #pragma unroll
            for (int r = 0; r < 4; ++r) {
                const int m = m0 + wr * 64 + i * 16 + lk * 4 + r;
                const long off = (long)m * N + n;
                float v = acc[i][j][r] + bv;
                if (MODE == 1) v += (float)res[off];
                if (RELU) v = v > 0.f ? v : 0.f;
                out[off] = (__bf16)v;
            }
        }
    }
}

// ---- GEMM8: 256x256 tile, 8 waves, BK=64, 8-phase interleave (T3+T4+T5).
// R12: single vmcnt(4) per K-tile (never 0 mid-loop); k1-regions staged one
// phase-pair earlier (race-audited: lgkmcnt-before-MFMA retires all buffer
// reads before the tile-end barrier; vmcnt(4) retires through the tile's k1).
template <int RELU, int MODE>
__global__ __launch_bounds__(512, 2) void gemm8_kernel(
    const __bf16* __restrict__ A, const __bf16* __restrict__ Bt,
    const float* __restrict__ bias, const __bf16* __restrict__ res,
    __bf16* __restrict__ out, int M, int N, int K)
{
    __shared__ __bf16 lds[65536];  // 128 KB
    const int t = threadIdx.x;
    const int lane = t & 63, wv = t >> 6;
    const int wr = wv >> 2, wc = wv & 3;
    const int lr = lane & 15, lk = lane >> 4;

    const int nwg = gridDim.x * gridDim.y;
    const int lin = blockIdx.y * gridDim.x + blockIdx.x;
    const int swz = (lin & 7) * (nwg >> 3) + (lin >> 3);
    const int m0 = (swz / gridDim.x) * 256, n0 = (swz % gridDim.x) * 256;

    const int srcrow = lane >> 2;
    const int srccol = ((lane & 3) ^ ((lane >> 4) & 3)) * 8;
    auto STG = [&](int isB, int kt2, int kk2, int pb) {
        const __bf16* src = isB ? Bt : A;
        const int base = isB ? n0 : m0;
        #pragma unroll
        for (int u = 0; u < 2; ++u) {
            const int sr = u * 8 + wv;
            const long g = (long)(base + sr * 16 + srcrow) * K + kt2 * 64 + kk2 * 32 + srccol;
            char* d = (char*)lds + pb * 65536 + isB * 32768 + ((sr * 2 + kk2) << 10) + lane * 16;
            gld_lds16(src + g, d);
        }
    };

    f32x4 acc[8][4] = {};
    bf16x8 af[4], bfr[4];
    auto RDA = [&](int p, int kk, int mh) {
        #pragma unroll
        for (int i = 0; i < 4; ++i) {
            const int sr = wr * 8 + mh * 4 + i;
            af[i] = *(const bf16x8*)((const char*)lds + p * 65536 +
                    ((sr * 2 + kk) << 10) + lr * 64 + ((lk ^ ((lr >> 2) & 3)) << 4));
        }
    };
    auto RDB = [&](int p, int kk) {
        #pragma unroll
        for (int j = 0; j < 4; ++j) {
            const int sr = wc * 4 + j;
            bfr[j] = *(const bf16x8*)((const char*)lds + p * 65536 + 32768 +
                     ((sr * 2 + kk) << 10) + lr * 64 + ((lk ^ ((lr >> 2) & 3)) << 4));
        }
    };
    auto MM = [&](int mh) {
        __builtin_amdgcn_s_setprio(1);
        #pragma unroll
        for (int i = 0; i < 4; ++i)
            #pragma unroll
            for (int j = 0; j < 4; ++j)
                acc[mh * 4 + i][j] = __builtin_amdgcn_mfma_f32_16x16x32_bf16(
                    af[i], bfr[j], acc[mh * 4 + i][j], 0, 0, 0);
        __builtin_amdgcn_s_setprio(0);
    };

    const int NT = K >> 6;
    // prologue: A0B0(0), A1B1(0), A0B0(1) = 12 loads in flight
    STG(0, 0, 0, 0); STG(1, 0, 0, 0); STG(0, 0, 1, 0); STG(1, 0, 1, 0);
    STG(0, 1, 0, 1); STG(1, 1, 0, 1);

    for (int kt = 0; kt < NT; ++kt) {
        const int p = kt & 1;
        if (kt == NT - 1) asm volatile("s_waitcnt vmcnt(0)" ::: "memory");
        else              asm volatile("s_waitcnt vmcnt(4)" ::: "memory");
        __builtin_amdgcn_s_barrier();
        RDA(p, 0, 0); RDB(p, 0); if (kt + 1 < NT) STG(0, kt + 1, 1, p ^ 1);
        MM(0);
        __builtin_amdgcn_s_barrier();
        RDA(p, 0, 1); if (kt + 1 < NT) STG(1, kt + 1, 1, p ^ 1);
        MM(1);
        __builtin_amdgcn_s_barrier();
        RDA(p, 1, 0); RDB(p, 1); if (kt + 2 < NT) STG(0, kt + 2, 0, p);
        MM(0);
        __builtin_amdgcn_s_barrier();
        RDA(p, 1, 1); if (kt + 2 < NT) STG(1, kt + 2, 0, p);
        MM(1);
    }

    #pragma unroll
    for (int i = 0; i < 8; ++i) {
        #pragma unroll
        for (int j = 0; j < 4; ++j) {
            const int n = n0 + wc * 64 + j * 16 + lr;
            const float bv = bias[n];
            #pragma unroll
            for (int r = 0; r < 4; ++r) {
                const int m = m0 + wr * 128 + i * 16 + lk * 4 + r;
                const long off = (long)m * N + n;
                float v = acc[i][j][r] + bv;
                if (MODE == 1) v += (float)res[off];
                if (RELU) v = v > 0.f ? v : 0.f;
                out[off] = (__bf16)v;
            }
        }
    }
}

// ---- merged K+V projection; R12: z=1 (Vt) epilogue via LDS-staged coalesced
// stores — 4-lane groups fill complete 64B lines (was 8B @1KB-stride scatter).
__global__ __launch_bounds__(256) void gemm_kv(
    const __bf16* __restrict__ xbf, const __bf16* __restrict__ ybf,
    const __bf16* __restrict__ wkt, const __bf16* __restrict__ wvt,
    const float* __restrict__ bk, const float* __restrict__ bv,
    __bf16* __restrict__ kout, __bf16* __restrict__ vtout)
{
    constexpr int N = 512, K = 512;
    __shared__ __bf16 As[2][128 * 64];
    __shared__ __bf16 Bs[2][128 * 64];
    const int t = threadIdx.x;
    const int lane = t & 63;
    const int wv = t >> 6, wr = wv >> 1, wc = wv & 1;
    const int lr = lane & 15, lk = lane >> 4;
    const int zv = blockIdx.z;

    const __bf16* A  = zv ? ybf : xbf;
    const __bf16* Bt = zv ? wvt : wkt;
    const float* bias = zv ? bv : bk;
    __bf16* out = zv ? vtout : kout;

    const int nwg = gridDim.x * gridDim.y;
    const int lin = blockIdx.y * gridDim.x + blockIdx.x;
    const int swz = (lin & 7) * (nwg >> 3) + (lin >> 3);
    const int m0 = (swz / gridDim.x) * 128, n0 = (swz % gridDim.x) * 128;

    const int srow = t >> 3;
    const int sslot = (t & 7) ^ (srow & 7);
    const __bf16* gA = A + (long)(m0 + srow) * K + sslot * 8;
    const __bf16* gB = Bt + (long)(n0 + srow) * K + sslot * 8;
    const long rstep = (long)32 * K;

    auto STAGE = [&](int bsel, int k0) {
        char* ldsA = (char*)As[bsel] + t * 16;
        char* ldsB = (char*)Bs[bsel] + t * 16;
        #pragma unroll
        for (int u = 0; u < 4; ++u) {
            gld_lds16(gA + u * rstep + k0, ldsA + u * 4096);
            gld_lds16(gB + u * rstep + k0, ldsB + u * 4096);
        }
    };

    f32x4 acc[4][4] = {};
    auto COMPUTE = [&](int bsel) {
        #pragma unroll
        for (int kk = 0; kk < 2; ++kk) {
            bf16x8 af[4], bfr[4];
            #pragma unroll
            for (int i = 0; i < 4; ++i) {
                const int rr = wr * 64 + i * 16 + lr;
                af[i] = *(const bf16x8*)((const char*)As[bsel] +
                        (rr << 7) + (((kk * 4 + lk) ^ (rr & 7)) << 4));
            }
            #pragma unroll
            for (int j = 0; j < 4; ++j) {
                const int rr = wc * 64 + j * 16 + lr;
                bfr[j] = *(const bf16x8*)((const char*)Bs[bsel] +
                         (rr << 7) + (((kk * 4 + lk) ^ (rr & 7)) << 4));
            }
            #pragma unroll
            for (int i = 0; i < 4; ++i)
                #pragma unroll
                for (int j = 0; j < 4; ++j)
                    acc[i][j] = __builtin_amdgcn_mfma_f32_16x16x32_bf16(
                        af[i], bfr[j], acc[i][j], 0, 0, 0);
        }
    };

    const int NT = K >> 6;
    STAGE(0, 0);
    STAGE(1, 64);
    for (int kt = 0; kt < NT - 1; ++kt) {
        asm volatile("s_waitcnt vmcnt(8)" ::: "memory");
        __builtin_amdgcn_s_barrier();
        COMPUTE(kt & 1);
        __builtin_amdgcn_s_barrier();
        if (kt + 2 < NT) STAGE(kt & 1, (kt + 2) << 6);
    }
    asm volatile("s_waitcnt vmcnt(0)" ::: "memory");
    __builtin_amdgcn_s_barrier();
    COMPUTE((NT - 1) & 1);

    if (zv) {
        // stage the 128(n) x 128(m) tile into As (dead now) with 16B-chunk XOR
        __syncthreads();                       // all waves done reading As
        __bf16* st = (__bf16*)As;              // 32 KB exactly
        #pragma unroll
        for (int i = 0; i < 4; ++i) {
            #pragma unroll
            for (int j = 0; j < 4; ++j) {
                const int nl = wc * 64 + j * 16 + lr;
                const float bvl = bias[n0 + nl];
                #pragma unroll
                for (int r = 0; r < 4; ++r) {
                    const int ml = wr * 64 + i * 16 + lk * 4 + r;
                    const int m16 = ml >> 3;
                    st[nl * 128 + (((m16 ^ (nl & 15)) << 3) | (ml & 7))] =
                        (__bf16)(acc[i][j][r] + bvl);
                }
            }
        }
        __syncthreads();
        // coalesced store: 4 lanes (c4) fill one full 64B line per instruction
        const int rowh = t >> 2, c4 = t & 3;
        const int b = m0 >> 9;
        #pragma unroll
        for (int pass = 0; pass < 2; ++pass) {
            const int row = pass * 64 + rowh;
            const int n = n0 + row;
            __bf16* dst = out + (((long)((b * 8 + (n >> 6)) * 64 + (n & 63))) << 9)
                          + (m0 & 511);
            #pragma unroll
            for (int seg = 0; seg < 4; ++seg) {
                const int m16 = seg * 4 + c4;
                const bf16x8 vv =
                    *(const bf16x8*)&st[row * 128 + ((m16 ^ (row & 15)) << 3)];
                *(bf16x8*)(dst + m16 * 8) = vv;
            }
        }
    } else {
        #pragma unroll
        for (int i = 0; i < 4; ++i) {
            #pragma unroll
            for (int j = 0; j < 4; ++j) {
                const int n = n0 + wc * 64 + j * 16 + lr;
                const float bvl = bias[n];
                #pragma unroll
                for (int r = 0; r < 4; ++r) {
                    const int m = m0 + wr * 64 + i * 16 + lk * 4 + r;
                    out[(long)m * N + n] = (__bf16)(acc[i][j][r] + bvl);
                }
            }
        }
    }
}

// ---- attention v5 (proven): 2-deep double-buffered K/V staging, counted vmcnt ----
__global__ __launch_bounds__(256) void attn_kernel(
    const __bf16* __restrict__ Q, const __bf16* __restrict__ Vt,
    const float* __restrict__ fr, __bf16* __restrict__ Out)
{
    __shared__ __bf16 Ks[2][64 * 64];
    __shared__ __bf16 Vs[2][64 * 64];
    __shared__ __bf16 Plds[4][16 * 64];
    const int t = threadIdx.x;
    const int lane = t & 63, wv = t >> 6;
    const int lr = lane & 15, lk = lane >> 4;
    const int qb = blockIdx.x, h = blockIdx.y, b = blockIdx.z;
    const int qT = qb * 64 + wv * 16;

    const __bf16* qp = Q + (long)(b * S_ + qT + lr) * D_ + h * DK_ + lk * 8;
    const bf16x8 qf0 = *(const bf16x8*)qp;
    const bf16x8 qf1 = *(const bf16x8*)(qp + 32);

    float frv[4], ls[4];
    #pragma unroll
    for (int r = 0; r < 4; ++r) {
        frv[r] = fr[b * S_ + qT + lk * 4 + r] * 0.125f;
        ls[r] = 0.f;
    }
    f32x4 o[4] = {};

    const int srow = t >> 3;
    const int sslot = (t & 7) ^ (srow & 7);
    const __bf16* kstage = Q + (long)(b * S_ + srow) * D_ + h * DK_ + sslot * 8;
    const __bf16* vstage = Vt + ((long)(b * H_ + h) * DK_ + srow) * S_ + sslot * 8;
    __bf16* pl = &Plds[wv][0];
    const int sw = (lr & 7);

    auto STAGE = [&](int bsel, int ks) {
        gld_lds16(kstage + (long)ks * D_, (char*)Ks[bsel] + t * 16);
        gld_lds16(kstage + (long)(ks + 32) * D_, (char*)Ks[bsel] + 4096 + t * 16);
        gld_lds16(vstage + ks, (char*)Vs[bsel] + t * 16);
        gld_lds16(vstage + ks + 32 * S_, (char*)Vs[bsel] + 4096 + t * 16);
    };

    auto COMPUTE = [&](int bsel, int ks) {
        f32x4 sc[4] = {};
        #pragma unroll
        for (int j = 0; j < 4; ++j) {
            const char* kb = (const char*)Ks[bsel] + ((j * 16 + lr) << 7);
            const bf16x8 kf0 = *(const bf16x8*)(kb + ((lk ^ sw) << 4));
            const bf16x8 kf1 = *(const bf16x8*)(kb + (((lk + 4) ^ sw) << 4));
            sc[j] = __builtin_amdgcn_mfma_f32_16x16x32_bf16(qf0, kf0, sc[j], 0, 0, 0);
            sc[j] = __builtin_amdgcn_mfma_f32_16x16x32_bf16(qf1, kf1, sc[j], 0, 0, 0);
        }
        #pragma unroll
        for (int j = 0; j < 4; ++j) {
            const int col = ks + j * 16 + lr;
            const int c8 = j * 2 + (lr >> 3), cb = lr & 7;
            #pragma unroll
            for (int r = 0; r < 4; ++r) {
                const int row = lk * 4 + r;
                const int sidx = row * 64 + ((c8 ^ (row & 7)) << 3) + cb;
                const float e = __expf(sc[j][r] * frv[r]);
                const float p = (col < qT + row) ? e : 0.f;
                ls[r] += p;
                pl[sidx] = (__bf16)p;
            }
        }
        bf16x8 pf[2];
        #pragma unroll
        for (int kk = 0; kk < 2; ++kk) {
            const int ridx = lr * 64 + (((kk * 4 + lk) ^ sw) << 3);
            pf[kk] = *(const bf16x8*)&pl[ridx];
        }
        #pragma unroll
        for (int dt = 0; dt < 4; ++dt) {
            const char* vb = (const char*)Vs[bsel] + ((dt * 16 + lr) << 7);
            #pragma unroll
            for (int kk = 0; kk < 2; ++kk) {
                const bf16x8 vf = *(const bf16x8*)(vb + (((kk * 4 + lk) ^ sw) << 4));
                o[dt] = __builtin_amdgcn_mfma_f32_16x16x32_bf16(pf[kk], vf, o[dt], 0, 0, 0);
            }
        }
    };

    const int nt = qb + 1;
    STAGE(0, 0);
    if (nt > 1) STAGE(1, 64);
    for (int tt = 0; tt < nt - 1; ++tt) {
        asm volatile("s_waitcnt vmcnt(4)" ::: "memory");
        __builtin_amdgcn_s_barrier();
        COMPUTE(tt & 1, tt * 64);
        __builtin_amdgcn_s_barrier();
        if (tt + 2 < nt) STAGE(tt & 1, (tt + 2) * 64);
    }
    asm volatile("s_waitcnt vmcnt(0)" ::: "memory");
    __builtin_amdgcn_s_barrier();
    COMPUTE((nt - 1) & 1, (nt - 1) * 64);

    #pragma unroll
    for (int r = 0; r < 4; ++r) {
        #pragma unroll
        for (int d = 1; d < 16; d <<= 1)
            ls[r] += __shfl_xor(ls[r], d);
        const float inv = ls[r] > 0.f ? 1.f / ls[r] : 0.f;  // row 0 -> zeros
        #pragma unroll
        for (int dt = 0; dt < 4; ++dt)
            Out[(long)(b * S_ + qT + lk * 4 + r) * D_ + h * DK_ + dt * 16 + lr] =
                (__bf16)(o[dt][r] * inv);
    }
}

// ---- LayerNorm: bf16 in, bf16 out (+fp32 out only when wf32 != 0) ----
__global__ __launch_bounds__(256) void ln_kernel(
    const __bf16* __restrict__ pre, const float* __restrict__ g,
    const float* __restrict__ be, float* __restrict__ xout,
    __bf16* __restrict__ xbf, int wf32)
{
    const int lane = threadIdx.x & 63, wv = threadIdx.x >> 6;
    const long row = (long)blockIdx.x * 4 + wv;
    const bf16x8 v = *(const bf16x8*)(pre + row * D_ + lane * 8);
    float f[8];
    #pragma unroll
    for (int k = 0; k < 8; ++k) f[k] = (float)v[k];
    float s = 0.f, ss = 0.f;
    #pragma unroll
    for (int k = 0; k < 8; ++k) { s += f[k]; ss += f[k] * f[k]; }
    #pragma unroll
    for (int d = 1; d < 64; d <<= 1) {
        s  += __shfl_xor(s, d);
        ss += __shfl_xor(ss, d);
    }
    const float mean = s * (1.f / 512.f);
    const float rstd = rsqrtf(ss * (1.f / 512.f) - mean * mean + 1e-5f);
    const float4 ga = ((const float4*)(g + lane * 8))[0];
    const float4 gc = ((const float4*)(g + lane * 8))[1];
    const float4 ba = ((const float4*)(be + lane * 8))[0];
    const float4 bc = ((const float4*)(be + lane * 8))[1];
    float o[8];
    o[0] = (f[0] - mean) * rstd * ga.x + ba.x;
    o[1] = (f[1] - mean) * rstd * ga.y + ba.y;
    o[2] = (f[2] - mean) * rstd * ga.z + ba.z;
    o[3] = (f[3] - mean) * rstd * ga.w + ba.w;
    o[4] = (f[4] - mean) * rstd * gc.x + bc.x;
    o[5] = (f[5] - mean) * rstd * gc.y + bc.y;
    o[6] = (f[6] - mean) * rstd * gc.z + bc.z;
    o[7] = (f[7] - mean) * rstd * gc.w + bc.w;
    bf16x8 xb = {(__bf16)o[0], (__bf16)o[1], (__bf16)o[2], (__bf16)o[3],
                 (__bf16)o[4], (__bf16)o[5], (__bf16)o[6], (__bf16)o[7]};
    *(bf16x8*)(xbf + row * D_ + lane * 8) = xb;
    if (wf32) {
        float* xo = xout + row * D_ + lane * 8;
        ((float4*)xo)[0] = make_float4(o[0], o[1], o[2], o[3]);
        ((float4*)xo)[1] = make_float4(o[4], o[5], o[6], o[7]);
    }
}

extern "C" void kernel_launch(void* const* d_in, const int* in_sizes, int n_in,
                              void* d_out, int out_size, void* d_ws, size_t ws_size,
                              hipStream_t stream) {
    const float* q_embed = (const float*)d_in[0];
    const float* qa_embed = (const float*)d_in[1];
    const float* fr  = (const float*)d_in[2];
    const float* pe  = (const float*)d_in[3];
    const float* Wk  = (const float*)d_in[4];
    const float* bk  = (const float*)d_in[5];
    const float* Wv  = (const float*)d_in[6];
    const float* bv  = (const float*)d_in[7];
    const float* Wo  = (const float*)d_in[8];
    const float* bo  = (const float*)d_in[9];
    const float* g1  = (const float*)d_in[10];
    const float* be1 = (const float*)d_in[11];
    const float* W1  = (const float*)d_in[12];
    const float* bf1 = (const float*)d_in[13];
    const float* W2  = (const float*)d_in[14];
    const float* bf2 = (const float*)d_in[15];
    const float* g2  = (const float*)d_in[16];
    const float* be2 = (const float*)d_in[17];

    // workspace layout (~128 MB)
    char* ws = (char*)d_ws;
    __bf16* xbf   = (__bf16*)(ws + 0);           // 16 MB bf16 residual master
    __bf16* ybf   = (__bf16*)(ws + 16777216);    // 16 MB
    __bf16* pool  = (__bf16*)(ws + 33554432);    // 64 MB: k/vt/attn OR f1
    __bf16* preln = (__bf16*)(ws + 100663296);   // 16 MB
    __bf16* wts   = (__bf16*)(ws + 117440512);   // 11 MB bf16 transposed weights

    __bf16* kbuf  = pool;
    __bf16* vtbuf = pool + 8388608;
    __bf16* abuf  = pool + 2 * 8388608;
    __bf16* f1buf = pool;  // 64 MB, aliases k/vt/attn (all dead by FFN1)

    __bf16* wkt = wts;
    __bf16* wvt = wts + 524288;
    __bf16* wot = wts + 1048576;
    __bf16* w1t = wts + 1572864;
    __bf16* w2t = wts + 3670016;

    pre_all<<<7680, 256, 0, stream>>>(Wk, Wv, Wo, W1, W2, q_embed, qa_embed, pe,
                                      wkt, wvt, wot, w1t, w2t, xbf, ybf);

    for (int i = 0; i < 2; ++i) {
        gemm_kv<<<dim3(4, 128, 2), 256, 0, stream>>>(
            xbf, ybf, wkt + i * 262144, wvt + i * 262144,
            bk + i * 512, bv + i * 512, kbuf, vtbuf);
        attn_kernel<<<dim3(8, 8, 32), 256, 0, stream>>>(kbuf, vtbuf, fr, abuf);
        gemm_kernel<0, 1><<<dim3(4, 128), 256, 0, stream>>>(
            abuf, wot + i * 262144, bo + i * 512, xbf, preln, 16384, 512, 512);
        ln_kernel<<<4096, 256, 0, stream>>>(preln, g1 + i * 512, be1 + i * 512,
                                            (float*)d_out, xbf, 0);
        gemm8_kernel<1, 0><<<dim3(8, 64), 512, 0, stream>>>(
            xbf, w1t + i * 1048576, bf1 + i * 2048, nullptr, f1buf, 16384, 2048, 512);
        gemm_kernel<0, 1><<<dim3(4, 128), 256, 0, stream>>>(
            f1buf, w2t + i * 1048576, bf2 + i * 512, xbf, preln, 16384, 512, 2048);
        ln_kernel<<<4096, 256, 0, stream>>>(preln, g2 + i * 512, be2 + i * 512,
                                            (float*)d_out, xbf, i == 1 ? 1 : 0);
    }
}

// Round 13
// 406.161 us; speedup vs baseline: 1.7821x; 1.0557x over previous
//
#include <hip/hip_runtime.h>

#define B_ 32
#define S_ 512
#define D_ 512
#define H_ 8
#define DK_ 64
#define FF_ 2048

typedef float f32x4 __attribute__((ext_vector_type(4)));
typedef __bf16 bf16x8 __attribute__((ext_vector_type(8)));
typedef __bf16 bf16x4 __attribute__((ext_vector_type(4)));

// ---- async global->LDS, 16B per lane (dest must be wave-uniform base + lane*16) ----
__device__ __forceinline__ void gld_lds16(const void* gptr, void* lptr) {
    auto g = (__attribute__((address_space(1))) void*)(unsigned long long)gptr;
    auto l = (__attribute__((address_space(3))) void*)(unsigned)(unsigned long long)lptr;
    __builtin_amdgcn_global_load_lds(g, l, 16, 0, 0);
}

// ---- shared 32x32 transpose tile body: fp32 [R][C] -> bf16 [C][R] ----
__device__ __forceinline__ void ttile(
    const float* __restrict__ in, __bf16* __restrict__ out,
    int R, int C, int bx, int by, int t)
{
    __shared__ float tile[32][33];
    const int tc = bx * 32, tr = by * 32;
    const int lx = t & 31, ly = t >> 5;
    #pragma unroll
    for (int yy = ly; yy < 32; yy += 8)
        tile[yy][lx] = in[(long)(tr + yy) * C + tc + lx];
    __syncthreads();
    #pragma unroll
    for (int yy = ly; yy < 32; yy += 8)
        out[(long)(tc + yy) * R + tr + lx] = (__bf16)tile[lx][yy];
}

// ---- weight transposes + x/y prep fused into one flat-grid dispatch ----
__global__ __launch_bounds__(256) void pre_all(
    const float* __restrict__ Wk, const float* __restrict__ Wv,
    const float* __restrict__ Wo, const float* __restrict__ W1,
    const float* __restrict__ W2, const float* __restrict__ q,
    const float* __restrict__ qa, const float* __restrict__ pe,
    __bf16* __restrict__ ok, __bf16* __restrict__ ov,
    __bf16* __restrict__ oo, __bf16* __restrict__ o1,
    __bf16* __restrict__ o2, __bf16* __restrict__ xbf,
    __bf16* __restrict__ ybf)
{
    const int id = blockIdx.x, t = threadIdx.x;
    if (id < 1536) {
        const int z = id >> 8, r = id & 255;
        const int sel = z >> 1, i = z & 1;
        const float* src = sel == 0 ? Wk : (sel == 1 ? Wv : Wo);
        __bf16* dst = sel == 0 ? ok : (sel == 1 ? ov : oo);
        ttile(src + (long)i * 262144, dst + (long)i * 262144, 512, 512,
              r & 15, r >> 4, t);
    } else if (id < 3584) {
        int r = id - 1536; const int i = r >> 10; r &= 1023;
        ttile(W1 + (long)i * 1048576, o1 + (long)i * 1048576, 512, 2048,
              r & 63, r >> 6, t);
    } else if (id < 5632) {
        int r = id - 3584; const int i = r >> 10; r &= 1023;
        ttile(W2 + (long)i * 1048576, o2 + (long)i * 1048576, 2048, 512,
              r & 15, r >> 4, t);
    } else {
        const int n4 = B_ * S_ * D_ / 4;
        for (int i = (id - 5632) * 256 + t; i < n4; i += 2048 * 256) {
            float4 pv = ((const float4*)pe)[i & (S_ * D_ / 4 - 1)];
            float4 qv = ((const float4*)q)[i];
            float4 av = ((const float4*)qa)[i];
            bf16x4 xb = {(__bf16)(qv.x + pv.x), (__bf16)(qv.y + pv.y),
                         (__bf16)(qv.z + pv.z), (__bf16)(qv.w + pv.w)};
            ((bf16x4*)xbf)[i] = xb;
            bf16x4 yb = {(__bf16)(av.x + pv.x), (__bf16)(av.y + pv.y),
                         (__bf16)(av.z + pv.z), (__bf16)(av.w + pv.w)};
            ((bf16x4*)ybf)[i] = yb;
        }
    }
}

// ---- GEMM v5 (proven, frozen): 128x128, BK=64, T2 swizzle, T1 XCD swizzle ----
template <int RELU, int MODE>
__global__ __launch_bounds__(256) void gemm_kernel(
    const __bf16* __restrict__ A, const __bf16* __restrict__ Bt,
    const float* __restrict__ bias, const __bf16* __restrict__ res,
    __bf16* __restrict__ out, int M, int N, int K)
{
    __shared__ __bf16 As[2][128 * 64];
    __shared__ __bf16 Bs[2][128 * 64];
    const int t = threadIdx.x;
    const int lane = t & 63;
    const int wv = t >> 6, wr = wv >> 1, wc = wv & 1;
    const int lr = lane & 15, lk = lane >> 4;

    const int nwg = gridDim.x * gridDim.y;
    const int lin = blockIdx.y * gridDim.x + blockIdx.x;
    const int swz = (lin & 7) * (nwg >> 3) + (lin >> 3);
    const int m0 = (swz / gridDim.x) * 128, n0 = (swz % gridDim.x) * 128;

    const int srow = t >> 3;
    const int sslot = (t & 7) ^ (srow & 7);
    const __bf16* gA = A + (long)(m0 + srow) * K + sslot * 8;
    const __bf16* gB = Bt + (long)(n0 + srow) * K + sslot * 8;
    const long rstep = (long)32 * K;

    auto STAGE = [&](int bsel, int k0) {
        char* ldsA = (char*)As[bsel] + t * 16;
        char* ldsB = (char*)Bs[bsel] + t * 16;
        #pragma unroll
        for (int u = 0; u < 4; ++u) {
            gld_lds16(gA + u * rstep + k0, ldsA + u * 4096);
            gld_lds16(gB + u * rstep + k0, ldsB + u * 4096);
        }
    };

    f32x4 acc[4][4] = {};
    auto COMPUTE = [&](int bsel) {
        #pragma unroll
        for (int kk = 0; kk < 2; ++kk) {
            bf16x8 af[4], bfr[4];
            #pragma unroll
            for (int i = 0; i < 4; ++i) {
                const int rr = wr * 64 + i * 16 + lr;
                af[i] = *(const bf16x8*)((const char*)As[bsel] +
                        (rr << 7) + (((kk * 4 + lk) ^ (rr & 7)) << 4));
            }
            #pragma unroll
            for (int j = 0; j < 4; ++j) {
                const int rr = wc * 64 + j * 16 + lr;
                bfr[j] = *(const bf16x8*)((const char*)Bs[bsel] +
                         (rr << 7) + (((kk * 4 + lk) ^ (rr & 7)) << 4));
            }
            #pragma unroll
            for (int i = 0; i < 4; ++i)
                #pragma unroll
                for (int j = 0; j < 4; ++j)
                    acc[i][j] = __builtin_amdgcn_mfma_f32_16x16x32_bf16(
                        af[i], bfr[j], acc[i][j], 0, 0, 0);
        }
    };

    const int NT = K >> 6;
    STAGE(0, 0);
    STAGE(1, 64);
    for (int kt = 0; kt < NT - 1; ++kt) {
        asm volatile("s_waitcnt vmcnt(8)" ::: "memory");
        __builtin_amdgcn_s_barrier();
        COMPUTE(kt & 1);
        __builtin_amdgcn_s_barrier();
        if (kt + 2 < NT) STAGE(kt & 1, (kt + 2) << 6);
    }
    asm volatile("s_waitcnt vmcnt(0)" ::: "memory");
    __builtin_amdgcn_s_barrier();
    COMPUTE((NT - 1) & 1);

    #pragma unroll
    for (int i = 0; i < 4; ++i) {
        #pragma unroll
        for (int j = 0; j < 4; ++j) {
            const int n = n0 + wc * 64 + j * 16 + lr;
            const float bv = bias[n];
            #pragma unroll
            for (int r = 0; r < 4; ++r) {
                const int m = m0 + wr * 64 + i * 16 + lk * 4 + r;
                const long off = (long)m * N + n;
                float v = acc[i][j][r] + bv;
                if (MODE == 1) v += (float)res[off];
                if (RELU) v = v > 0.f ? v : 0.f;
                out[off] = (__bf16)v;
            }
        }
    }
}

// ---- GEMM8 (frozen): 256x256, 8 waves, 8-phase interleave ----
template <int RELU, int MODE>
__global__ __launch_bounds__(512, 2) void gemm8_kernel(
    const __bf16* __restrict__ A, const __bf16* __restrict__ Bt,
    const float* __restrict__ bias, const __bf16* __restrict__ res,
    __bf16* __restrict__ out, int M, int N, int K)
{
    __shared__ __bf16 lds[65536];  // 128 KB
    const int t = threadIdx.x;
    const int lane = t & 63, wv = t >> 6;
    const int wr = wv >> 2, wc = wv & 3;
    const int lr = lane & 15, lk = lane >> 4;

    const int nwg = gridDim.x * gridDim.y;
    const int lin = blockIdx.y * gridDim.x + blockIdx.x;
    const int swz = (lin & 7) * (nwg >> 3) + (lin >> 3);
    const int m0 = (swz / gridDim.x) * 256, n0 = (swz % gridDim.x) * 256;

    const int srcrow = lane >> 2;
    const int srccol = ((lane & 3) ^ ((lane >> 4) & 3)) * 8;
    auto STG = [&](int isB, int kt2, int kk2, int pb) {
        const __bf16* src = isB ? Bt : A;
        const int base = isB ? n0 : m0;
        #pragma unroll
        for (int u = 0; u < 2; ++u) {
            const int sr = u * 8 + wv;
            const long g = (long)(base + sr * 16 + srcrow) * K + kt2 * 64 + kk2 * 32 + srccol;
            char* d = (char*)lds + pb * 65536 + isB * 32768 + ((sr * 2 + kk2) << 10) + lane * 16;
            gld_lds16(src + g, d);
        }
    };

    f32x4 acc[8][4] = {};
    bf16x8 af[4], bfr[4];
    auto RDA = [&](int p, int kk, int mh) {
        #pragma unroll
        for (int i = 0; i < 4; ++i) {
            const int sr = wr * 8 + mh * 4 + i;
            af[i] = *(const bf16x8*)((const char*)lds + p * 65536 +
                    ((sr * 2 + kk) << 10) + lr * 64 + ((lk ^ ((lr >> 2) & 3)) << 4));
        }
    };
    auto RDB = [&](int p, int kk) {
        #pragma unroll
        for (int j = 0; j < 4; ++j) {
            const int sr = wc * 4 + j;
            bfr[j] = *(const bf16x8*)((const char*)lds + p * 65536 + 32768 +
                     ((sr * 2 + kk) << 10) + lr * 64 + ((lk ^ ((lr >> 2) & 3)) << 4));
        }
    };
    auto MM = [&](int mh) {
        __builtin_amdgcn_s_setprio(1);
        #pragma unroll
        for (int i = 0; i < 4; ++i)
            #pragma unroll
            for (int j = 0; j < 4; ++j)
                acc[mh * 4 + i][j] = __builtin_amdgcn_mfma_f32_16x16x32_bf16(
                    af[i], bfr[j], acc[mh * 4 + i][j], 0, 0, 0);
        __builtin_amdgcn_s_setprio(0);
    };

    const int NT = K >> 6;
    STG(0, 0, 0, 0); STG(1, 0, 0, 0); STG(0, 0, 1, 0); STG(1, 0, 1, 0);
    STG(0, 1, 0, 1); STG(1, 1, 0, 1);

    for (int kt = 0; kt < NT; ++kt) {
        const int p = kt & 1;
        if (kt == NT - 1) asm volatile("s_waitcnt vmcnt(0)" ::: "memory");
        else              asm volatile("s_waitcnt vmcnt(4)" ::: "memory");
        __builtin_amdgcn_s_barrier();
        RDA(p, 0, 0); RDB(p, 0); if (kt + 1 < NT) STG(0, kt + 1, 1, p ^ 1);
        MM(0);
        __builtin_amdgcn_s_barrier();
        RDA(p, 0, 1); if (kt + 1 < NT) STG(1, kt + 1, 1, p ^ 1);
        MM(1);
        __builtin_amdgcn_s_barrier();
        RDA(p, 1, 0); RDB(p, 1); if (kt + 2 < NT) STG(0, kt + 2, 0, p);
        MM(0);
        __builtin_amdgcn_s_barrier();
        RDA(p, 1, 1); if (kt + 2 < NT) STG(1, kt + 2, 0, p);
        MM(1);
    }

    #pragma unroll
    for (int i = 0; i < 8; ++i) {
        #pragma unroll
        for (int j = 0; j < 4; ++j) {
            const int n = n0 + wc * 64 + j * 16 + lr;
            const float bv = bias[n];
            #pragma unroll
            for (int r = 0; r < 4; ++r) {
                const int m = m0 + wr * 128 + i * 16 + lk * 4 + r;
                const long off = (long)m * N + n;
                float v = acc[i][j][r] + bv;
                if (MODE == 1) v += (float)res[off];
                if (RELU) v = v > 0.f ? v : 0.f;
                out[off] = (__bf16)v;
            }
        }
    }
}

// ---- merged K+V projection (frozen) ----
__global__ __launch_bounds__(256) void gemm_kv(
    const __bf16* __restrict__ xbf, const __bf16* __restrict__ ybf,
    const __bf16* __restrict__ wkt, const __bf16* __restrict__ wvt,
    const float* __restrict__ bk, const float* __restrict__ bv,
    __bf16* __restrict__ kout, __bf16* __restrict__ vtout)
{
    constexpr int N = 512, K = 512;
    __shared__ __bf16 As[2][128 * 64];
    __shared__ __bf16 Bs[2][128 * 64];
    const int t = threadIdx.x;
    const int lane = t & 63;
    const int wv = t >> 6, wr = wv >> 1, wc = wv & 1;
    const int lr = lane & 15, lk = lane >> 4;
    const int zv = blockIdx.z;

    const __bf16* A  = zv ? ybf : xbf;
    const __bf16* Bt = zv ? wvt : wkt;
    const float* bias = zv ? bv : bk;
    __bf16* out = zv ? vtout : kout;

    const int nwg = gridDim.x * gridDim.y;
    const int lin = blockIdx.y * gridDim.x + blockIdx.x;
    const int swz = (lin & 7) * (nwg >> 3) + (lin >> 3);
    const int m0 = (swz / gridDim.x) * 128, n0 = (swz % gridDim.x) * 128;

    const int srow = t >> 3;
    const int sslot = (t & 7) ^ (srow & 7);
    const __bf16* gA = A + (long)(m0 + srow) * K + sslot * 8;
    const __bf16* gB = Bt + (long)(n0 + srow) * K + sslot * 8;
    const long rstep = (long)32 * K;

    auto STAGE = [&](int bsel, int k0) {
        char* ldsA = (char*)As[bsel] + t * 16;
        char* ldsB = (char*)Bs[bsel] + t * 16;
        #pragma unroll
        for (int u = 0; u < 4; ++u) {
            gld_lds16(gA + u * rstep + k0, ldsA + u * 4096);
            gld_lds16(gB + u * rstep + k0, ldsB + u * 4096);
        }
    };

    f32x4 acc[4][4] = {};
    auto COMPUTE = [&](int bsel) {
        #pragma unroll
        for (int kk = 0; kk < 2; ++kk) {
            bf16x8 af[4], bfr[4];
            #pragma unroll
            for (int i = 0; i < 4; ++i) {
                const int rr = wr * 64 + i * 16 + lr;
                af[i] = *(const bf16x8*)((const char*)As[bsel] +
                        (rr << 7) + (((kk * 4 + lk) ^ (rr & 7)) << 4));
            }
            #pragma unroll
            for (int j = 0; j < 4; ++j) {
                const int rr = wc * 64 + j * 16 + lr;
                bfr[j] = *(const bf16x8*)((const char*)Bs[bsel] +
                         (rr << 7) + (((kk * 4 + lk) ^ (rr & 7)) << 4));
            }
            #pragma unroll
            for (int i = 0; i < 4; ++i)
                #pragma unroll
                for (int j = 0; j < 4; ++j)
                    acc[i][j] = __builtin_amdgcn_mfma_f32_16x16x32_bf16(
                        af[i], bfr[j], acc[i][j], 0, 0, 0);
        }
    };

    const int NT = K >> 6;
    STAGE(0, 0);
    STAGE(1, 64);
    for (int kt = 0; kt < NT - 1; ++kt) {
        asm volatile("s_waitcnt vmcnt(8)" ::: "memory");
        __builtin_amdgcn_s_barrier();
        COMPUTE(kt & 1);
        __builtin_amdgcn_s_barrier();
        if (kt + 2 < NT) STAGE(kt & 1, (kt + 2) << 6);
    }
    asm volatile("s_waitcnt vmcnt(0)" ::: "memory");
    __builtin_amdgcn_s_barrier();
    COMPUTE((NT - 1) & 1);

    if (zv) {
        __syncthreads();
        __bf16* st = (__bf16*)As;
        #pragma unroll
        for (int i = 0; i < 4; ++i) {
            #pragma unroll
            for (int j = 0; j < 4; ++j) {
                const int nl = wc * 64 + j * 16 + lr;
                const float bvl = bias[n0 + nl];
                #pragma unroll
                for (int r = 0; r < 4; ++r) {
                    const int ml = wr * 64 + i * 16 + lk * 4 + r;
                    const int m16 = ml >> 3;
                    st[nl * 128 + (((m16 ^ (nl & 15)) << 3) | (ml & 7))] =
                        (__bf16)(acc[i][j][r] + bvl);
                }
            }
        }
        __syncthreads();
        const int rowh = t >> 2, c4 = t & 3;
        const int b = m0 >> 9;
        #pragma unroll
        for (int pass = 0; pass < 2; ++pass) {
            const int row = pass * 64 + rowh;
            const int n = n0 + row;
            __bf16* dst = out + (((long)((b * 8 + (n >> 6)) * 64 + (n & 63))) << 9)
                          + (m0 & 511);
            #pragma unroll
            for (int seg = 0; seg < 4; ++seg) {
                const int m16 = seg * 4 + c4;
                const bf16x8 vv =
                    *(const bf16x8*)&st[row * 128 + ((m16 ^ (row & 15)) << 3)];
                *(bf16x8*)(dst + m16 * 8) = vv;
            }
        }
    } else {
        #pragma unroll
        for (int i = 0; i < 4; ++i) {
            #pragma unroll
            for (int j = 0; j < 4; ++j) {
                const int n = n0 + wc * 64 + j * 16 + lr;
                const float bvl = bias[n];
                #pragma unroll
                for (int r = 0; r < 4; ++r) {
                    const int m = m0 + wr * 64 + i * 16 + lk * 4 + r;
                    out[(long)m * N + n] = (__bf16)(acc[i][j][r] + bvl);
                }
            }
        }
    }
}

// ---- attention v6: 8-wave / 128-row blocks. Per-wave code identical to the
// proven v5 (one 16-row q-tile per wave); only block geometry changes.
// Staging: 512 threads stage a whole 64x64 K (and V) tile in ONE gld_lds16.
// Fully-masked tiles skipped by a wave-uniform guard. Grid (4, H, B). ----
__global__ __launch_bounds__(512) void attn_kernel(
    const __bf16* __restrict__ Q, const __bf16* __restrict__ Vt,
    const float* __restrict__ fr, __bf16* __restrict__ Out)
{
    __shared__ __bf16 Ks[2][64 * 64];
    __shared__ __bf16 Vs[2][64 * 64];
    __shared__ __bf16 Plds[8][16 * 64];
    const int t = threadIdx.x;
    const int lane = t & 63, wv = t >> 6;          // wv 0..7
    const int lr = lane & 15, lk = lane >> 4;
    const int qb = blockIdx.x, h = blockIdx.y, b = blockIdx.z;
    const int qT = qb * 128 + wv * 16;

    const __bf16* qp = Q + (long)(b * S_ + qT + lr) * D_ + h * DK_ + lk * 8;
    const bf16x8 qf0 = *(const bf16x8*)qp;
    const bf16x8 qf1 = *(const bf16x8*)(qp + 32);

    float frv[4], ls[4];
    #pragma unroll
    for (int r = 0; r < 4; ++r) {
        frv[r] = fr[b * S_ + qT + lk * 4 + r] * 0.125f;
        ls[r] = 0.f;
    }
    f32x4 o[4] = {};

    const int srow = t >> 3;                        // 0..63 (full tile rows)
    const int sslot = (t & 7) ^ (srow & 7);         // XOR-swizzled 16B slot
    const __bf16* kstage = Q + (long)(b * S_ + srow) * D_ + h * DK_ + sslot * 8;
    const __bf16* vstage = Vt + ((long)(b * H_ + h) * DK_ + srow) * S_ + sslot * 8;
    __bf16* pl = &Plds[wv][0];
    const int sw = (lr & 7);

    auto STAGE = [&](int bsel, int ks) {            // 2 loads: whole K + whole V tile
        gld_lds16(kstage + (long)ks * D_, (char*)Ks[bsel] + t * 16);
        gld_lds16(vstage + ks, (char*)Vs[bsel] + t * 16);
    };

    auto COMPUTE = [&](int bsel, int ks) {
        if (ks >= qT + 16) return;                  // wave-uniform: fully masked
        f32x4 sc[4] = {};
        #pragma unroll
        for (int j = 0; j < 4; ++j) {
            const char* kb = (const char*)Ks[bsel] + ((j * 16 + lr) << 7);
            const bf16x8 kf0 = *(const bf16x8*)(kb + ((lk ^ sw) << 4));
            const bf16x8 kf1 = *(const bf16x8*)(kb + (((lk + 4) ^ sw) << 4));
            sc[j] = __builtin_amdgcn_mfma_f32_16x16x32_bf16(qf0, kf0, sc[j], 0, 0, 0);
            sc[j] = __builtin_amdgcn_mfma_f32_16x16x32_bf16(qf1, kf1, sc[j], 0, 0, 0);
        }
        #pragma unroll
        for (int j = 0; j < 4; ++j) {
            const int col = ks + j * 16 + lr;
            const int c8 = j * 2 + (lr >> 3), cb = lr & 7;
            #pragma unroll
            for (int r = 0; r < 4; ++r) {
                const int row = lk * 4 + r;
                const int sidx = row * 64 + ((c8 ^ (row & 7)) << 3) + cb;
                const float e = __expf(sc[j][r] * frv[r]);
                const float p = (col < qT + row) ? e : 0.f;
                ls[r] += p;
                pl[sidx] = (__bf16)p;
            }
        }
        bf16x8 pf[2];
        #pragma unroll
        for (int kk = 0; kk < 2; ++kk) {
            const int ridx = lr * 64 + (((kk * 4 + lk) ^ sw) << 3);
            pf[kk] = *(const bf16x8*)&pl[ridx];
        }
        #pragma unroll
        for (int dt = 0; dt < 4; ++dt) {
            const char* vb = (const char*)Vs[bsel] + ((dt * 16 + lr) << 7);
            #pragma unroll
            for (int kk = 0; kk < 2; ++kk) {
                const bf16x8 vf = *(const bf16x8*)(vb + (((kk * 4 + lk) ^ sw) << 4));
                o[dt] = __builtin_amdgcn_mfma_f32_16x16x32_bf16(pf[kk], vf, o[dt], 0, 0, 0);
            }
        }
    };

    const int nt = 2 * qb + 2;                      // tiles covering 128 q-rows
    STAGE(0, 0);
    STAGE(1, 64);
    for (int tt = 0; tt < nt - 1; ++tt) {
        asm volatile("s_waitcnt vmcnt(2)" ::: "memory");
        __builtin_amdgcn_s_barrier();
        COMPUTE(tt & 1, tt * 64);
        __builtin_amdgcn_s_barrier();
        if (tt + 2 < nt) STAGE(tt & 1, (tt + 2) * 64);
    }
    asm volatile("s_waitcnt vmcnt(0)" ::: "memory");
    __builtin_amdgcn_s_barrier();
    COMPUTE((nt - 1) & 1, (nt - 1) * 64);

    #pragma unroll
    for (int r = 0; r < 4; ++r) {
        #pragma unroll
        for (int d = 1; d < 16; d <<= 1)
            ls[r] += __shfl_xor(ls[r], d);
        const float inv = ls[r] > 0.f ? 1.f / ls[r] : 0.f;  // row 0 -> zeros
        #pragma unroll
        for (int dt = 0; dt < 4; ++dt)
            Out[(long)(b * S_ + qT + lk * 4 + r) * D_ + h * DK_ + dt * 16 + lr] =
                (__bf16)(o[dt][r] * inv);
    }
}

// ---- LayerNorm: bf16 in, bf16 out (+fp32 out only when wf32 != 0) ----
__global__ __launch_bounds__(256) void ln_kernel(
    const __bf16* __restrict__ pre, const float* __restrict__ g,
    const float* __restrict__ be, float* __restrict__ xout,
    __bf16* __restrict__ xbf, int wf32)
{
    const int lane = threadIdx.x & 63, wv = threadIdx.x >> 6;
    const long row = (long)blockIdx.x * 4 + wv;
    const bf16x8 v = *(const bf16x8*)(pre + row * D_ + lane * 8);
    float f[8];
    #pragma unroll
    for (int k = 0; k < 8; ++k) f[k] = (float)v[k];
    float s = 0.f, ss = 0.f;
    #pragma unroll
    for (int k = 0; k < 8; ++k) { s += f[k]; ss += f[k] * f[k]; }
    #pragma unroll
    for (int d = 1; d < 64; d <<= 1) {
        s  += __shfl_xor(s, d);
        ss += __shfl_xor(ss, d);
    }
    const float mean = s * (1.f / 512.f);
    const float rstd = rsqrtf(ss * (1.f / 512.f) - mean * mean + 1e-5f);
    const float4 ga = ((const float4*)(g + lane * 8))[0];
    const float4 gc = ((const float4*)(g + lane * 8))[1];
    const float4 ba = ((const float4*)(be + lane * 8))[0];
    const float4 bc = ((const float4*)(be + lane * 8))[1];
    float o[8];
    o[0] = (f[0] - mean) * rstd * ga.x + ba.x;
    o[1] = (f[1] - mean) * rstd * ga.y + ba.y;
    o[2] = (f[2] - mean) * rstd * ga.z + ba.z;
    o[3] = (f[3] - mean) * rstd * ga.w + ba.w;
    o[4] = (f[4] - mean) * rstd * gc.x + bc.x;
    o[5] = (f[5] - mean) * rstd * gc.y + bc.y;
    o[6] = (f[6] - mean) * rstd * gc.z + bc.z;
    o[7] = (f[7] - mean) * rstd * gc.w + bc.w;
    bf16x8 xb = {(__bf16)o[0], (__bf16)o[1], (__bf16)o[2], (__bf16)o[3],
                 (__bf16)o[4], (__bf16)o[5], (__bf16)o[6], (__bf16)o[7]};
    *(bf16x8*)(xbf + row * D_ + lane * 8) = xb;
    if (wf32) {
        float* xo = xout + row * D_ + lane * 8;
        ((float4*)xo)[0] = make_float4(o[0], o[1], o[2], o[3]);
        ((float4*)xo)[1] = make_float4(o[4], o[5], o[6], o[7]);
    }
}

extern "C" void kernel_launch(void* const* d_in, const int* in_sizes, int n_in,
                              void* d_out, int out_size, void* d_ws, size_t ws_size,
                              hipStream_t stream) {
    const float* q_embed = (const float*)d_in[0];
    const float* qa_embed = (const float*)d_in[1];
    const float* fr  = (const float*)d_in[2];
    const float* pe  = (const float*)d_in[3];
    const float* Wk  = (const float*)d_in[4];
    const float* bk  = (const float*)d_in[5];
    const float* Wv  = (const float*)d_in[6];
    const float* bv  = (const float*)d_in[7];
    const float* Wo  = (const float*)d_in[8];
    const float* bo  = (const float*)d_in[9];
    const float* g1  = (const float*)d_in[10];
    const float* be1 = (const float*)d_in[11];
    const float* W1  = (const float*)d_in[12];
    const float* bf1 = (const float*)d_in[13];
    const float* W2  = (const float*)d_in[14];
    const float* bf2 = (const float*)d_in[15];
    const float* g2  = (const float*)d_in[16];
    const float* be2 = (const float*)d_in[17];

    // workspace layout (~128 MB)
    char* ws = (char*)d_ws;
    __bf16* xbf   = (__bf16*)(ws + 0);           // 16 MB bf16 residual master
    __bf16* ybf   = (__bf16*)(ws + 16777216);    // 16 MB
    __bf16* pool  = (__bf16*)(ws + 33554432);    // 64 MB: k/vt/attn OR f1
    __bf16* preln = (__bf16*)(ws + 100663296);   // 16 MB
    __bf16* wts   = (__bf16*)(ws + 117440512);   // 11 MB bf16 transposed weights

    __bf16* kbuf  = pool;
    __bf16* vtbuf = pool + 8388608;
    __bf16* abuf  = pool + 2 * 8388608;
    __bf16* f1buf = pool;  // 64 MB, aliases k/vt/attn (all dead by FFN1)

    __bf16* wkt = wts;
    __bf16* wvt = wts + 524288;
    __bf16* wot = wts + 1048576;
    __bf16* w1t = wts + 1572864;
    __bf16* w2t = wts + 3670016;

    pre_all<<<7680, 256, 0, stream>>>(Wk, Wv, Wo, W1, W2, q_embed, qa_embed, pe,
                                      wkt, wvt, wot, w1t, w2t, xbf, ybf);

    for (int i = 0; i < 2; ++i) {
        gemm_kv<<<dim3(4, 128, 2), 256, 0, stream>>>(
            xbf, ybf, wkt + i * 262144, wvt + i * 262144,
            bk + i * 512, bv + i * 512, kbuf, vtbuf);
        attn_kernel<<<dim3(4, 8, 32), 512, 0, stream>>>(kbuf, vtbuf, fr, abuf);
        gemm_kernel<0, 1><<<dim3(4, 128), 256, 0, stream>>>(
            abuf, wot + i * 262144, bo + i * 512, xbf, preln, 16384, 512, 512);
        ln_kernel<<<4096, 256, 0, stream>>>(preln, g1 + i * 512, be1 + i * 512,
                                            (float*)d_out, xbf, 0);
        gemm8_kernel<1, 0><<<dim3(8, 64), 512, 0, stream>>>(
            xbf, w1t + i * 1048576, bf1 + i * 2048, nullptr, f1buf, 16384, 2048, 512);
        gemm_kernel<0, 1><<<dim3(4, 128), 256, 0, stream>>>(
            f1buf, w2t + i * 1048576, bf2 + i * 512, xbf, preln, 16384, 512, 2048);
        ln_kernel<<<4096, 256, 0, stream>>>(preln, g2 + i * 512, be2 + i * 512,
                                            (float*)d_out, xbf, i == 1 ? 1 : 0);
    }
}